// Round 4
// baseline (1581.573 us; speedup 1.0000x reference)
//
#include <hip/hip_runtime.h>
#include <math.h>
#include <stdint.h>

#define ROWS 8192   // B*S
#define DIM  1024
#define NH   8
#define DFF_ 4096
#define EPSF 1e-6f

typedef __attribute__((ext_vector_type(8))) short short8;
typedef __attribute__((ext_vector_type(4))) float f32x4;

__device__ __forceinline__ float siluf(float x) {
    return x / (1.0f + expf(-x));
}
__device__ __forceinline__ unsigned short f2bf(float f) {
    uint32_t u = __float_as_uint(f);
    uint32_t r = (u + 0x7FFFu + ((u >> 16) & 1u)) >> 16;
    return (unsigned short)r;
}
__device__ __forceinline__ float bf2f(unsigned short u) {
    return __uint_as_float(((uint32_t)u) << 16);
}

// async global->LDS 16B (wave-uniform LDS base + lane*16)
__device__ __forceinline__ void async16(const void* g, void* l) {
    __builtin_amdgcn_global_load_lds(
        (const __attribute__((address_space(1))) uint32_t*)g,
        (__attribute__((address_space(3))) uint32_t*)l, 16, 0, 0);
}

// DPP adds: xor1 = quad_perm 0xB1, xor2 = quad_perm 0x4E,
// 8-mirror = row_half_mirror 0x141, 16-mirror = row_mirror 0x140. All VALU.
template <int C>
__device__ __forceinline__ float dpp_add(float x) {
    int y = __builtin_amdgcn_update_dpp(0, __float_as_int(x), C, 0xF, 0xF, true);
    return x + __int_as_float(y);
}
__device__ __forceinline__ float red16(float x) {
    x = dpp_add<0xB1>(x);
    x = dpp_add<0x4E>(x);
    x = dpp_add<0x141>(x);
    x = dpp_add<0x140>(x);
    return x;
}

// ---------------- RMSNorm -> bf16 out ----------------
__global__ void rmsnorm_bf16_kernel(const float* __restrict__ x, unsigned short* __restrict__ y) {
    int row = blockIdx.x;
    int tid = threadIdx.x;  // 256 threads, one float4 each
    const float4* x4 = (const float4*)(x + (size_t)row * DIM);
    float4 v = x4[tid];
    float ss = v.x * v.x + v.y * v.y + v.z * v.z + v.w * v.w;
#pragma unroll
    for (int m = 1; m < 64; m <<= 1) ss += __shfl_xor(ss, m, 64);
    __shared__ float wss[4];
    if ((tid & 63) == 0) wss[tid >> 6] = ss;
    __syncthreads();
    float tot = wss[0] + wss[1] + wss[2] + wss[3];
    float r = rsqrtf(tot * (1.0f / 1024.0f) + EPSF);
    ushort4 o;
    o.x = f2bf(v.x * r); o.y = f2bf(v.y * r); o.z = f2bf(v.z * r); o.w = f2bf(v.w * r);
    ((ushort4*)(y + (size_t)row * DIM))[tid] = o;
}

// ---------------- fp32 -> bf16 transpose: W[K,N] -> WT[N,K] ----------------
__global__ void transpose_bf16_kernel(const float* __restrict__ W, unsigned short* __restrict__ WT,
                                      int K, int N) {
    __shared__ float tile[32][33];
    int n0 = blockIdx.x * 32, k0 = blockIdx.y * 32;
    int tx = threadIdx.x & 31, ty = threadIdx.x >> 5;  // 256 threads: 32 x 8
#pragma unroll
    for (int r = 0; r < 32; r += 8)
        tile[ty + r][tx] = W[(size_t)(k0 + ty + r) * N + n0 + tx];
    __syncthreads();
#pragma unroll
    for (int r = 0; r < 32; r += 8)
        WT[(size_t)(n0 + ty + r) * K + k0 + tx] = f2bf(tile[tx][ty + r]);
}

// ---------------- bf16 MFMA GEMM: C[M,N] = A[M,K] @ BT[N,K]^T ----------------
// EPI: 0 none(f32), 1 silu(f32), 2 res+acc(f32), 3 relu^2 -> bf16
template <int EPI, typename CT>
__global__ __launch_bounds__(256) void mfma_gemm(
    const unsigned short* __restrict__ A, const unsigned short* __restrict__ BT,
    CT* __restrict__ C, const float* __restrict__ res, int M, int N, int K) {
    __shared__ __align__(16) unsigned short As[128 * 32];
    __shared__ __align__(16) unsigned short Bs[128 * 32];
    int tid = threadIdx.x;
    int w = tid >> 6, lane = tid & 63;

    // XCD-aware swizzle (T1): nwg % 8 == 0 for all our launches.
    int nwgx = gridDim.x;
    int nwg = nwgx * gridDim.y;
    int id = blockIdx.y * nwgx + blockIdx.x;
    int cpx = nwg >> 3;
    int nid = (id & 7) * cpx + (id >> 3);
    int bxs = nid % nwgx, bys = nid / nwgx;

    int bm = bys * 128, bn = bxs * 128;
    int wm = (w >> 1) * 64, wn = (w & 1) * 64;

    int srow = tid >> 2;           // 0..63
    int skb = (tid & 3) * 8;       // ushort offset in row (16B chunks)
    const unsigned short* Ag = A + (size_t)(bm + srow) * K + skb;
    const unsigned short* Bg = BT + (size_t)(bn + srow) * K + skb;

    f32x4 acc[4][4] = {};

    int lr = lane & 15;
    int lk = (lane >> 4) * 8;

    for (int kt = 0; kt < K; kt += 32) {
        async16(Ag + kt, As + w * 512);
        async16(Ag + kt + (size_t)64 * K, As + 2048 + w * 512);
        async16(Bg + kt, Bs + w * 512);
        async16(Bg + kt + (size_t)64 * K, Bs + 2048 + w * 512);
        __syncthreads();  // drains vmcnt+lgkmcnt
        short8 af[4], bf[4];
#pragma unroll
        for (int i = 0; i < 4; i++) {
            af[i] = *(const short8*)&As[(wm + i * 16 + lr) * 32 + lk];
            bf[i] = *(const short8*)&Bs[(wn + i * 16 + lr) * 32 + lk];
        }
#pragma unroll
        for (int i = 0; i < 4; i++)
#pragma unroll
            for (int j = 0; j < 4; j++)
                acc[i][j] = __builtin_amdgcn_mfma_f32_16x16x32_bf16(af[i], bf[j], acc[i][j], 0, 0, 0);
        __syncthreads();
    }

#pragma unroll
    for (int i = 0; i < 4; i++) {
        int gr0 = bm + wm + i * 16 + (lane >> 4) * 4;
#pragma unroll
        for (int j = 0; j < 4; j++) {
            int gc = bn + wn + j * 16 + lr;
#pragma unroll
            for (int r = 0; r < 4; r++) {
                float v = acc[i][j][r];
                size_t idx = (size_t)(gr0 + r) * N + gc;
                if (EPI == 1) v = siluf(v);
                else if (EPI == 2) v += res[idx];
                else if (EPI == 3) { float t = fmaxf(v, 0.0f); v = t * t; }
                if constexpr (sizeof(CT) == 2) C[idx] = (CT)f2bf(v);
                else C[idx] = v;
            }
        }
    }
}

// ---------------- l2norm over 128-chunks (in-place fp32) ----------------
__global__ void l2norm_kernel(float* __restrict__ x) {
    int row = blockIdx.x;
    int tid = threadIdx.x;  // 256
    float4* p = (float4*)(x + (size_t)row * DIM);
    float4 v = p[tid];
    float ss = v.x * v.x + v.y * v.y + v.z * v.z + v.w * v.w;
#pragma unroll
    for (int m = 1; m < 32; m <<= 1) ss += __shfl_xor(ss, m, 32);
    float r = rsqrtf(ss + EPSF);
    v.x *= r; v.y *= r; v.z *= r; v.w *= r;
    p[tid] = v;
}

// ---------------- gated RMSNorm -> bf16: ob = rms128(o)*w*silu(gate) ----------------
__global__ void gating_kernel(const float* __restrict__ o, const float* __restrict__ gate,
                              const float* __restrict__ w, unsigned short* __restrict__ ob) {
    int row = blockIdx.x;
    int tid = threadIdx.x;  // 256
    const float4* op = (const float4*)(o + (size_t)row * DIM);
    const float4* gp = (const float4*)(gate + (size_t)row * DIM);
    float4 v = op[tid];
    float ss = v.x * v.x + v.y * v.y + v.z * v.z + v.w * v.w;
#pragma unroll
    for (int m = 1; m < 32; m <<= 1) ss += __shfl_xor(ss, m, 32);
    float r = rsqrtf(ss * (1.0f / 128.0f) + EPSF);
    float4 g = gp[tid];
    float4 wv = ((const float4*)w)[tid & 31];
    ushort4 out;
    out.x = f2bf(v.x * r * wv.x * siluf(g.x));
    out.y = f2bf(v.y * r * wv.y * siluf(g.y));
    out.z = f2bf(v.z * r * wv.z * siluf(g.z));
    out.w = f2bf(v.w * r * wv.w * siluf(g.w));
    ((ushort4*)(ob + (size_t)row * DIM))[tid] = out;
}

// ---------------- small projections: beta = sigm(h@Wb), alpha = exp(g) ----------------
__global__ void smallproj_kernel(const unsigned short* __restrict__ hbuf,
                                 const float* __restrict__ Wb, const float* __restrict__ Wa,
                                 const float* __restrict__ A_log, const float* __restrict__ dt_bias,
                                 float* __restrict__ Alpha, float* __restrict__ Beta) {
    int row = blockIdx.x;
    int tid = threadIdx.x;  // 128
    __shared__ __align__(16) float hrow[1024];
    __shared__ float part[128];
    const ushort4* h4 = (const ushort4*)(hbuf + (size_t)row * DIM);
    ushort4 u0 = h4[tid * 2], u1 = h4[tid * 2 + 1];
    hrow[tid * 8 + 0] = bf2f(u0.x); hrow[tid * 8 + 1] = bf2f(u0.y);
    hrow[tid * 8 + 2] = bf2f(u0.z); hrow[tid * 8 + 3] = bf2f(u0.w);
    hrow[tid * 8 + 4] = bf2f(u1.x); hrow[tid * 8 + 5] = bf2f(u1.y);
    hrow[tid * 8 + 6] = bf2f(u1.z); hrow[tid * 8 + 7] = bf2f(u1.w);
    __syncthreads();
    int out = tid & 15, slice = tid >> 4;
    const float* W = (out < 8) ? Wb : Wa;
    int col = out & 7;
    int k0 = slice * 128;
    float p = 0.0f;
    for (int kk = 0; kk < 128; kk++) p += hrow[k0 + kk] * W[(size_t)(k0 + kk) * 8 + col];
    part[tid] = p;
    __syncthreads();
    if (tid < 16) {
        float sum = 0.0f;
#pragma unroll
        for (int sl = 0; sl < 8; sl++) sum += part[sl * 16 + tid];
        if (tid < 8) {
            Beta[(size_t)row * 8 + tid] = 1.0f / (1.0f + expf(-sum));
        } else {
            int hh = tid - 8;
            float xg = sum + dt_bias[hh];
            float sp = fmaxf(xg, 0.0f) + log1pf(expf(-fabsf(xg)));
            Alpha[(size_t)row * 8 + hh] = expf(-expf(A_log[hh]) * sp);
        }
    }
}

// ---------------- gated delta-rule scan ----------------
// 256 blocks = 32 bh x 8 dv-groups (bh = blk&31 so all 8 groups of a bh share an XCD).
// 256 threads = 4 waves; wave = 16 dk-slices (lane&15, 8 dk each) x 4 dv (lane>>4).
// s[8] in VGPRs; 4-level DPP 16-lane reduce; 4-deep register prefetch.
#define SLOAD(P, tn) do {                                                       \
    size_t ro_ = (size_t)(tn) * 256;                                            \
    P##k0 = Kp[ro_]; P##k1 = Kp[ro_ + 1];                                       \
    P##q0 = Qp[ro_]; P##q1 = Qp[ro_ + 1];                                       \
    P##v = Vp[(size_t)(tn) * DIM];                                              \
    P##a = Ap[(size_t)(tn) * 8]; P##b = Bp[(size_t)(tn) * 8];                   \
} while (0)

#define SSTEP(P, t) do {                                                        \
    float as0 = P##a * s[0], as1 = P##a * s[1], as2 = P##a * s[2], as3 = P##a * s[3]; \
    float as4 = P##a * s[4], as5 = P##a * s[5], as6 = P##a * s[6], as7 = P##a * s[7]; \
    float p0 = fmaf(P##k0.x, s[0], P##k0.y * s[1]);                             \
    float p1 = fmaf(P##k0.z, s[2], P##k0.w * s[3]);                             \
    float p2 = fmaf(P##k1.x, s[4], P##k1.y * s[5]);                             \
    float p3 = fmaf(P##k1.z, s[6], P##k1.w * s[7]);                             \
    float kv = red16((p0 + p1) + (p2 + p3));                                    \
    float delta = fmaf(-P##a, kv, P##v) * P##b;                                 \
    float o0, o1, o2, o3;                                                       \
    s[0] = fmaf(P##k0.x, delta, as0); o0 = P##q0.x * s[0];                      \
    s[1] = fmaf(P##k0.y, delta, as1); o1 = P##q0.y * s[1];                      \
    s[2] = fmaf(P##k0.z, delta, as2); o2 = P##q0.z * s[2];                      \
    s[3] = fmaf(P##k0.w, delta, as3); o3 = P##q0.w * s[3];                      \
    s[4] = fmaf(P##k1.x, delta, as4); o0 = fmaf(P##q1.x, s[4], o0);             \
    s[5] = fmaf(P##k1.y, delta, as5); o1 = fmaf(P##q1.y, s[5], o1);             \
    s[6] = fmaf(P##k1.z, delta, as6); o2 = fmaf(P##q1.z, s[6], o2);             \
    s[7] = fmaf(P##k1.w, delta, as7); o3 = fmaf(P##q1.w, s[7], o3);             \
    float oacc = red16((o0 + o1) + (o2 + o3));                                  \
    if (wrt) Op[(size_t)(t) * DIM] = oacc * scale;                              \
} while (0)

__global__ __launch_bounds__(256) void scan_kernel(
    const float* __restrict__ Q, const float* __restrict__ Kb,
    const float* __restrict__ V, const float* __restrict__ Alpha,
    const float* __restrict__ Beta, float* __restrict__ O) {
    int blk = blockIdx.x;
    int bh = blk & 31, dvg = blk >> 5;  // same-bh blocks land on one XCD
    int b = bh >> 3, h = bh & 7;
    int tid = threadIdx.x;
    int lane = tid & 63, w = tid >> 6;
    int slice = lane & 15;              // dk slice [slice*8, slice*8+8)
    int dvl = w * 4 + (lane >> 4);      // 0..15
    int dv_col = dvg * 16 + dvl;
    size_t base0 = (size_t)b * 2048 * DIM;

    const float4* Kp = (const float4*)(Kb + base0 + h * 128 + slice * 8);
    const float4* Qp = (const float4*)(Q + base0 + h * 128 + slice * 8);
    const float* Vp = V + base0 + h * 128 + dv_col;
    const float* Ap = Alpha + (size_t)b * 2048 * 8 + h;
    const float* Bp = Beta + (size_t)b * 2048 * 8 + h;
    float* Op = O + base0 + h * 128 + dv_col;
    bool wrt = (slice == 0);

    float s[8];
#pragma unroll
    for (int i = 0; i < 8; i++) s[i] = 0.0f;

    const float scale = 0.08838834764831845f;

    float4 Ak0, Ak1, Aq0, Aq1; float Av, Aa, Ab;
    float4 Bk0, Bk1, Bq0, Bq1; float Bv, Ba, Bb;
    float4 Ck0, Ck1, Cq0, Cq1; float Cv, Ca, Cb;
    float4 Dk0, Dk1, Dq0, Dq1; float Dv, Da, Db;

    SLOAD(A, 0); SLOAD(B, 1); SLOAD(C, 2); SLOAD(D, 3);

    for (int t = 0; t < 2048; t += 4) {
        SSTEP(A, t);     SLOAD(A, (t + 4 < 2048) ? t + 4 : 2047);
        SSTEP(B, t + 1); SLOAD(B, (t + 5 < 2048) ? t + 5 : 2047);
        SSTEP(C, t + 2); SLOAD(C, (t + 6 < 2048) ? t + 6 : 2047);
        SSTEP(D, t + 3); SLOAD(D, (t + 7 < 2048) ? t + 7 : 2047);
    }
}

extern "C" void kernel_launch(void* const* d_in, const int* in_sizes, int n_in,
                              void* d_out, int out_size, void* d_ws, size_t ws_size,
                              hipStream_t stream) {
    const float* x      = (const float*)d_in[0];
    const float* Wq     = (const float*)d_in[1];
    const float* Wk     = (const float*)d_in[2];
    const float* Wv     = (const float*)d_in[3];
    const float* Wb     = (const float*)d_in[4];
    const float* Wa     = (const float*)d_in[5];
    const float* A_log  = (const float*)d_in[6];
    const float* dt_b   = (const float*)d_in[7];
    const float* Wg     = (const float*)d_in[8];
    const float* o_norm = (const float*)d_in[9];
    const float* Wo     = (const float*)d_in[10];
    const float* W_fc   = (const float*)d_in[11];
    const float* W_proj = (const float*)d_in[12];
    float* out = (float*)d_out;

    const size_t MAT = (size_t)ROWS * DIM;
    float* ws = (float*)d_ws;
    float* fq    = ws;                 // q fp32
    float* fk    = ws + MAT;           // k fp32
    float* fv    = ws + 2 * MAT;       // v fp32; later o_bf (ushort)
    float* fgate = ws + 3 * MAT;       // gate fp32
    float* fo    = ws + 4 * MAT;       // h_bf (ushort) -> o fp32 -> m_bf (ushort)
    float* alpha = ws + 5 * MAT;
    float* beta  = alpha + (size_t)ROWS * NH;
    unsigned short* wts = (unsigned short*)(beta + (size_t)ROWS * NH);
    unsigned short* WqT = wts;                    // [1024,1024]
    unsigned short* WkT = wts + (1u << 20);
    unsigned short* WvT = wts + 2 * (1u << 20);
    unsigned short* WgT = wts + 3 * (1u << 20);
    unsigned short* WoT = wts + 4 * (1u << 20);
    unsigned short* WfcT = wts + 5 * (1u << 20);  // [4096,1024]
    unsigned short* WprT = wts + 9 * (1u << 20);  // [1024,4096]
    unsigned short* h_bf = (unsigned short*)fo;
    unsigned short* m_bf = (unsigned short*)fo;
    unsigned short* o_bf = (unsigned short*)fv;
    unsigned short* fc_bf = (unsigned short*)ws;  // spans q+k regions (64MB)

    // 0. weight transposes -> bf16 [N,K]
    transpose_bf16_kernel<<<dim3(32, 32), 256, 0, stream>>>(Wq, WqT, 1024, 1024);
    transpose_bf16_kernel<<<dim3(32, 32), 256, 0, stream>>>(Wk, WkT, 1024, 1024);
    transpose_bf16_kernel<<<dim3(32, 32), 256, 0, stream>>>(Wv, WvT, 1024, 1024);
    transpose_bf16_kernel<<<dim3(32, 32), 256, 0, stream>>>(Wg, WgT, 1024, 1024);
    transpose_bf16_kernel<<<dim3(32, 32), 256, 0, stream>>>(Wo, WoT, 1024, 1024);
    transpose_bf16_kernel<<<dim3(128, 32), 256, 0, stream>>>(W_fc, WfcT, 1024, 4096);
    transpose_bf16_kernel<<<dim3(32, 128), 256, 0, stream>>>(W_proj, WprT, 4096, 1024);

    // 1. h = rms_norm(x) -> bf16
    rmsnorm_bf16_kernel<<<ROWS, 256, 0, stream>>>(x, h_bf);

    // 2. projections (bf16 MFMA, fp32 out)
    dim3 g1(DIM / 128, ROWS / 128);
    mfma_gemm<1, float><<<g1, 256, 0, stream>>>(h_bf, WqT, fq, nullptr, ROWS, DIM, DIM);
    mfma_gemm<1, float><<<g1, 256, 0, stream>>>(h_bf, WkT, fk, nullptr, ROWS, DIM, DIM);
    mfma_gemm<1, float><<<g1, 256, 0, stream>>>(h_bf, WvT, fv, nullptr, ROWS, DIM, DIM);
    mfma_gemm<0, float><<<g1, 256, 0, stream>>>(h_bf, WgT, fgate, nullptr, ROWS, DIM, DIM);

    // 3. l2norm q, k
    l2norm_kernel<<<ROWS, 256, 0, stream>>>(fq);
    l2norm_kernel<<<ROWS, 256, 0, stream>>>(fk);

    // 4. beta/alpha
    smallproj_kernel<<<ROWS, 128, 0, stream>>>(h_bf, Wb, Wa, A_log, dt_b, alpha, beta);

    // 5. delta-rule scan (writes o fp32 into fo, over dead h_bf)
    scan_kernel<<<256, 256, 0, stream>>>(fq, fk, fv, alpha, beta, fo);

    // 6. gated RMSNorm -> o_bf (over dead v)
    gating_kernel<<<ROWS, 256, 0, stream>>>(fo, fgate, o_norm, o_bf);

    // 7. d_out = x + o @ Wo
    mfma_gemm<2, float><<<g1, 256, 0, stream>>>(o_bf, WoT, out, x, ROWS, DIM, DIM);

    // 8. m = rms_norm(d_out) -> m_bf (over dead o)
    rmsnorm_bf16_kernel<<<ROWS, 256, 0, stream>>>(out, m_bf);

    // 9. fc = relu(m @ W_fc)^2 -> bf16 (over dead q,k)
    dim3 g2(DFF_ / 128, ROWS / 128);
    mfma_gemm<3, unsigned short><<<g2, 256, 0, stream>>>(m_bf, WfcT, fc_bf, nullptr, ROWS, DFF_, DIM);

    // 10. d_out += fc @ W_proj
    mfma_gemm<2, float><<<g1, 256, 0, stream>>>(fc_bf, WprT, out, out, ROWS, DIM, DFF_);
}

// Round 5
// 903.457 us; speedup vs baseline: 1.7506x; 1.7506x over previous
//
#include <hip/hip_runtime.h>
#include <math.h>
#include <stdint.h>

#define ROWS 8192   // B*S
#define DIM  1024
#define NH   8
#define DFF_ 4096
#define EPSF 1e-6f
#define SCALEQ 0.08838834764831845f  // DK^-0.5

typedef __attribute__((ext_vector_type(8))) short short8;
typedef __attribute__((ext_vector_type(4))) float f32x4;

__device__ __forceinline__ float siluf(float x) {
    return x / (1.0f + expf(-x));
}
__device__ __forceinline__ unsigned short f2bf(float f) {
    uint32_t u = __float_as_uint(f);
    uint32_t r = (u + 0x7FFFu + ((u >> 16) & 1u)) >> 16;
    return (unsigned short)r;
}
__device__ __forceinline__ float bf2f(unsigned short u) {
    return __uint_as_float(((uint32_t)u) << 16);
}

// async global->LDS 16B (wave-uniform LDS base + lane*16)
__device__ __forceinline__ void async16(const void* g, void* l) {
    __builtin_amdgcn_global_load_lds(
        (const __attribute__((address_space(1))) uint32_t*)g,
        (__attribute__((address_space(3))) uint32_t*)l, 16, 0, 0);
}

// DPP adds for fallback scan
template <int C>
__device__ __forceinline__ float dpp_add(float x) {
    int y = __builtin_amdgcn_update_dpp(0, __float_as_int(x), C, 0xF, 0xF, true);
    return x + __int_as_float(y);
}
__device__ __forceinline__ float red8(float x) {
    x = dpp_add<0xB1>(x);
    x = dpp_add<0x4E>(x);
    x = dpp_add<0x141>(x);
    return x;
}

// ---------------- RMSNorm -> bf16 out ----------------
__global__ void rmsnorm_bf16_kernel(const float* __restrict__ x, unsigned short* __restrict__ y) {
    int row = blockIdx.x;
    int tid = threadIdx.x;  // 256
    const float4* x4 = (const float4*)(x + (size_t)row * DIM);
    float4 v = x4[tid];
    float ss = v.x * v.x + v.y * v.y + v.z * v.z + v.w * v.w;
#pragma unroll
    for (int m = 1; m < 64; m <<= 1) ss += __shfl_xor(ss, m, 64);
    __shared__ float wss[4];
    if ((tid & 63) == 0) wss[tid >> 6] = ss;
    __syncthreads();
    float tot = wss[0] + wss[1] + wss[2] + wss[3];
    float r = rsqrtf(tot * (1.0f / 1024.0f) + EPSF);
    ushort4 o;
    o.x = f2bf(v.x * r); o.y = f2bf(v.y * r); o.z = f2bf(v.z * r); o.w = f2bf(v.w * r);
    ((ushort4*)(y + (size_t)row * DIM))[tid] = o;
}

// ---------------- fp32 -> bf16 transpose: W[K,N] -> WT[N,K] ----------------
__global__ void transpose_bf16_kernel(const float* __restrict__ W, unsigned short* __restrict__ WT,
                                      int K, int N) {
    __shared__ float tile[32][33];
    int n0 = blockIdx.x * 32, k0 = blockIdx.y * 32;
    int tx = threadIdx.x & 31, ty = threadIdx.x >> 5;
#pragma unroll
    for (int r = 0; r < 32; r += 8)
        tile[ty + r][tx] = W[(size_t)(k0 + ty + r) * N + n0 + tx];
    __syncthreads();
#pragma unroll
    for (int r = 0; r < 32; r += 8)
        WT[(size_t)(n0 + ty + r) * K + k0 + tx] = f2bf(tile[tx][ty + r]);
}

// ---------------- bf16 MFMA GEMM: C[M,N] = A[M,K] @ BT[N,K]^T ----------------
template <int EPI, typename CT>
__global__ __launch_bounds__(256) void mfma_gemm(
    const unsigned short* __restrict__ A, const unsigned short* __restrict__ BT,
    CT* __restrict__ C, const float* __restrict__ res, int M, int N, int K) {
    __shared__ __align__(16) unsigned short As[128 * 32];
    __shared__ __align__(16) unsigned short Bs[128 * 32];
    int tid = threadIdx.x;
    int w = tid >> 6, lane = tid & 63;

    int nwgx = gridDim.x;
    int nwg = nwgx * gridDim.y;
    int id = blockIdx.y * nwgx + blockIdx.x;
    int cpx = nwg >> 3;
    int nid = (id & 7) * cpx + (id >> 3);
    int bxs = nid % nwgx, bys = nid / nwgx;

    int bm = bys * 128, bn = bxs * 128;
    int wm = (w >> 1) * 64, wn = (w & 1) * 64;

    int srow = tid >> 2;
    int skb = (tid & 3) * 8;
    const unsigned short* Ag = A + (size_t)(bm + srow) * K + skb;
    const unsigned short* Bg = BT + (size_t)(bn + srow) * K + skb;

    f32x4 acc[4][4] = {};

    int lr = lane & 15;
    int lk = (lane >> 4) * 8;

    for (int kt = 0; kt < K; kt += 32) {
        async16(Ag + kt, As + w * 512);
        async16(Ag + kt + (size_t)64 * K, As + 2048 + w * 512);
        async16(Bg + kt, Bs + w * 512);
        async16(Bg + kt + (size_t)64 * K, Bs + 2048 + w * 512);
        __syncthreads();
        short8 af[4], bf[4];
#pragma unroll
        for (int i = 0; i < 4; i++) {
            af[i] = *(const short8*)&As[(wm + i * 16 + lr) * 32 + lk];
            bf[i] = *(const short8*)&Bs[(wn + i * 16 + lr) * 32 + lk];
        }
#pragma unroll
        for (int i = 0; i < 4; i++)
#pragma unroll
            for (int j = 0; j < 4; j++)
                acc[i][j] = __builtin_amdgcn_mfma_f32_16x16x32_bf16(af[i], bf[j], acc[i][j], 0, 0, 0);
        __syncthreads();
    }

#pragma unroll
    for (int i = 0; i < 4; i++) {
        int gr0 = bm + wm + i * 16 + (lane >> 4) * 4;
#pragma unroll
        for (int j = 0; j < 4; j++) {
            int gc = bn + wn + j * 16 + lr;
#pragma unroll
            for (int r = 0; r < 4; r++) {
                float v = acc[i][j][r];
                size_t idx = (size_t)(gr0 + r) * N + gc;
                if (EPI == 1) v = siluf(v);
                else if (EPI == 2) v += res[idx];
                else if (EPI == 3) { float t = fmaxf(v, 0.0f); v = t * t; }
                if constexpr (sizeof(CT) == 2) C[idx] = (CT)f2bf(v);
                else C[idx] = v;
            }
        }
    }
}

// ---------------- l2norm over 128-chunks (in-place fp32) ----------------
__global__ void l2norm_kernel(float* __restrict__ x) {
    int row = blockIdx.x;
    int tid = threadIdx.x;
    float4* p = (float4*)(x + (size_t)row * DIM);
    float4 v = p[tid];
    float ss = v.x * v.x + v.y * v.y + v.z * v.z + v.w * v.w;
#pragma unroll
    for (int m = 1; m < 32; m <<= 1) ss += __shfl_xor(ss, m, 32);
    float r = rsqrtf(ss + EPSF);
    v.x *= r; v.y *= r; v.z *= r; v.w *= r;
    p[tid] = v;
}

// ---------------- gated RMSNorm -> bf16 ----------------
__global__ void gating_kernel(const float* __restrict__ o, const float* __restrict__ gate,
                              const float* __restrict__ w, unsigned short* __restrict__ ob) {
    int row = blockIdx.x;
    int tid = threadIdx.x;
    const float4* op = (const float4*)(o + (size_t)row * DIM);
    const float4* gp = (const float4*)(gate + (size_t)row * DIM);
    float4 v = op[tid];
    float ss = v.x * v.x + v.y * v.y + v.z * v.z + v.w * v.w;
#pragma unroll
    for (int m = 1; m < 32; m <<= 1) ss += __shfl_xor(ss, m, 32);
    float r = rsqrtf(ss * (1.0f / 128.0f) + EPSF);
    float4 g = gp[tid];
    float4 wv = ((const float4*)w)[tid & 31];
    ushort4 out;
    out.x = f2bf(v.x * r * wv.x * siluf(g.x));
    out.y = f2bf(v.y * r * wv.y * siluf(g.y));
    out.z = f2bf(v.z * r * wv.z * siluf(g.z));
    out.w = f2bf(v.w * r * wv.w * siluf(g.w));
    ((ushort4*)(ob + (size_t)row * DIM))[tid] = out;
}

// ---------------- small projections: beta, glog, alpha ----------------
__global__ void smallproj_kernel(const unsigned short* __restrict__ hbuf,
                                 const float* __restrict__ Wb, const float* __restrict__ Wa,
                                 const float* __restrict__ A_log, const float* __restrict__ dt_bias,
                                 float* __restrict__ Glog, float* __restrict__ Alpha,
                                 float* __restrict__ Beta) {
    int row = blockIdx.x;
    int tid = threadIdx.x;  // 128
    __shared__ __align__(16) float hrow[1024];
    __shared__ float part[128];
    const ushort4* h4 = (const ushort4*)(hbuf + (size_t)row * DIM);
    ushort4 u0 = h4[tid * 2], u1 = h4[tid * 2 + 1];
    hrow[tid * 8 + 0] = bf2f(u0.x); hrow[tid * 8 + 1] = bf2f(u0.y);
    hrow[tid * 8 + 2] = bf2f(u0.z); hrow[tid * 8 + 3] = bf2f(u0.w);
    hrow[tid * 8 + 4] = bf2f(u1.x); hrow[tid * 8 + 5] = bf2f(u1.y);
    hrow[tid * 8 + 6] = bf2f(u1.z); hrow[tid * 8 + 7] = bf2f(u1.w);
    __syncthreads();
    int out = tid & 15, slice = tid >> 4;
    const float* W = (out < 8) ? Wb : Wa;
    int col = out & 7;
    int k0 = slice * 128;
    float p = 0.0f;
    for (int kk = 0; kk < 128; kk++) p += hrow[k0 + kk] * W[(size_t)(k0 + kk) * 8 + col];
    part[tid] = p;
    __syncthreads();
    if (tid < 16) {
        float sum = 0.0f;
#pragma unroll
        for (int sl = 0; sl < 8; sl++) sum += part[sl * 16 + tid];
        if (tid < 8) {
            Beta[(size_t)row * 8 + tid] = 1.0f / (1.0f + expf(-sum));
        } else {
            int hh = tid - 8;
            float xg = sum + dt_bias[hh];
            float sp = fmaxf(xg, 0.0f) + log1pf(expf(-fabsf(xg)));
            float gl = -expf(A_log[hh]) * sp;
            Glog[(size_t)row * 8 + hh] = gl;
            Alpha[(size_t)row * 8 + hh] = expf(gl);
        }
    }
}

// ---------------- fallback scan (R3 structure) ----------------
#define SCAN_LOAD(P, tn) do {                                                   \
    size_t ro_ = (size_t)(tn) * 256;                                            \
    P##k0 = Kp[ro_ + 0]; P##k1 = Kp[ro_ + 1];                                   \
    P##k2 = Kp[ro_ + 2]; P##k3 = Kp[ro_ + 3];                                   \
    P##q0 = Qp[ro_ + 0]; P##q1 = Qp[ro_ + 1];                                   \
    P##q2 = Qp[ro_ + 2]; P##q3 = Qp[ro_ + 3];                                   \
    P##v = Vp[(size_t)(tn) * DIM];                                              \
    P##a = Ap[(size_t)(tn) * 8]; P##b = Bp[(size_t)(tn) * 8];                   \
} while (0)

#define SCAN_STEP(P, t) do {                                                    \
    float kv0 = fmaf(P##k0.x, s[0], fmaf(P##k0.y, s[1], fmaf(P##k0.z, s[2], P##k0.w * s[3])));   \
    float kv1 = fmaf(P##k1.x, s[4], fmaf(P##k1.y, s[5], fmaf(P##k1.z, s[6], P##k1.w * s[7])));   \
    float kv2 = fmaf(P##k2.x, s[8], fmaf(P##k2.y, s[9], fmaf(P##k2.z, s[10], P##k2.w * s[11]))); \
    float kv3 = fmaf(P##k3.x, s[12], fmaf(P##k3.y, s[13], fmaf(P##k3.z, s[14], P##k3.w * s[15])));\
    float kv = red8((kv0 + kv1) + (kv2 + kv3));                                 \
    float delta = (P##v - P##a * kv) * P##b;                                    \
    float o0, o1, o2, o3;                                                       \
    s[0]  = fmaf(P##k0.x, delta, P##a * s[0]);  o0 = P##q0.x * s[0];            \
    s[1]  = fmaf(P##k0.y, delta, P##a * s[1]);  o1 = P##q0.y * s[1];            \
    s[2]  = fmaf(P##k0.z, delta, P##a * s[2]);  o2 = P##q0.z * s[2];            \
    s[3]  = fmaf(P##k0.w, delta, P##a * s[3]);  o3 = P##q0.w * s[3];            \
    s[4]  = fmaf(P##k1.x, delta, P##a * s[4]);  o0 = fmaf(P##q1.x, s[4], o0);   \
    s[5]  = fmaf(P##k1.y, delta, P##a * s[5]);  o1 = fmaf(P##q1.y, s[5], o1);   \
    s[6]  = fmaf(P##k1.z, delta, P##a * s[6]);  o2 = fmaf(P##q1.z, s[6], o2);   \
    s[7]  = fmaf(P##k1.w, delta, P##a * s[7]);  o3 = fmaf(P##q1.w, s[7], o3);   \
    s[8]  = fmaf(P##k2.x, delta, P##a * s[8]);  o0 = fmaf(P##q2.x, s[8], o0);   \
    s[9]  = fmaf(P##k2.y, delta, P##a * s[9]);  o1 = fmaf(P##q2.y, s[9], o1);   \
    s[10] = fmaf(P##k2.z, delta, P##a * s[10]); o2 = fmaf(P##q2.z, s[10], o2);  \
    s[11] = fmaf(P##k2.w, delta, P##a * s[11]); o3 = fmaf(P##q2.w, s[11], o3);  \
    s[12] = fmaf(P##k3.x, delta, P##a * s[12]); o0 = fmaf(P##q3.x, s[12], o0);  \
    s[13] = fmaf(P##k3.y, delta, P##a * s[13]); o1 = fmaf(P##q3.y, s[13], o1);  \
    s[14] = fmaf(P##k3.z, delta, P##a * s[14]); o2 = fmaf(P##q3.z, s[14], o2);  \
    s[15] = fmaf(P##k3.w, delta, P##a * s[15]); o3 = fmaf(P##q3.w, s[15], o3);  \
    float oacc = red8((o0 + o1) + (o2 + o3));                                   \
    if (ks == 0) Op[(size_t)(t) * DIM] = oacc * scale;                          \
} while (0)

__global__ __launch_bounds__(128) void scan_kernel(
    const float* __restrict__ Q, const float* __restrict__ Kb,
    const float* __restrict__ V, const float* __restrict__ Alpha,
    const float* __restrict__ Beta, float* __restrict__ O) {
    int blk = blockIdx.x;
    int bh = blk >> 3, dvb = blk & 7;
    int b = bh >> 3, h = bh & 7;
    int tid = threadIdx.x;
    int ks = tid & 7;
    int dvl = tid >> 3;
    int col_k = h * 128 + ks * 16;
    int col_v = h * 128 + dvb * 16 + dvl;
    size_t base0 = (size_t)b * 2048 * DIM;

    const float4* Kp = (const float4*)(Kb + base0 + col_k);
    const float4* Qp = (const float4*)(Q + base0 + col_k);
    const float* Vp = V + base0 + col_v;
    const float* Ap = Alpha + (size_t)b * 2048 * 8 + h;
    const float* Bp = Beta + (size_t)b * 2048 * 8 + h;
    float* Op = O + base0 + col_v;

    float s[16];
#pragma unroll
    for (int i = 0; i < 16; i++) s[i] = 0.0f;

    const float scale = SCALEQ;

    float4 Ak0, Ak1, Ak2, Ak3, Aq0, Aq1, Aq2, Aq3;
    float Av, Aa, Ab;
    float4 Bk0, Bk1, Bk2, Bk3, Bq0, Bq1, Bq2, Bq3;
    float Bv, Ba, Bb;

    SCAN_LOAD(A, 0);
    SCAN_LOAD(B, 1);

    int t = 0;
    for (; t < 2046; t += 2) {
        SCAN_STEP(A, t);
        SCAN_LOAD(A, t + 2);
        SCAN_STEP(B, t + 1);
        SCAN_LOAD(B, t + 3);
    }
    SCAN_STEP(A, 2046);
    SCAN_STEP(B, 2047);
}

// ================= chunked gated delta rule =================
// Phase 1: per (b,h,chunk=64): decays, L=(I+L) solve -> W,U; SM, Q', K'T, pC.
// Grid 1024 = c*32 + bh. 256 threads.
__global__ __launch_bounds__(256) void chunk_prep_kernel(
    const float* __restrict__ Q, const float* __restrict__ K,
    const float* __restrict__ V, const float* __restrict__ Glog,
    const float* __restrict__ Beta,
    unsigned short* __restrict__ Wg, unsigned short* __restrict__ Ug,
    unsigned short* __restrict__ Qg, unsigned short* __restrict__ KTg,
    unsigned short* __restrict__ SMg, float* __restrict__ Pcs) {
    int blk = blockIdx.x;
    int bh = blk & 31, c = blk >> 5;
    int b = bh >> 3, h = bh & 7;
    int bhc = bh * 32 + c;
    int row0 = b * 2048 + c * 64;
    int col0 = h * 128;
    int tid = threadIdx.x;
    int w = tid >> 6, lane = tid & 63;

    __shared__ __align__(16) unsigned short Kb[64 * 136];
    __shared__ __align__(16) unsigned short Qb[64 * 136];
    __shared__ float Lm[64 * 64];
    __shared__ float Wm[64 * 128];
    __shared__ float Um[64 * 128];
    __shared__ float garr[64], betl[64], Gl[64], Pl[64], decf[64];

    // stage K,Q -> bf16 LDS (padded rows); load g,beta
    {
        int i = tid >> 2, q4 = tid & 3;
        const float* kp = K + (size_t)(row0 + i) * DIM + col0 + q4 * 32;
        const float* qp = Q + (size_t)(row0 + i) * DIM + col0 + q4 * 32;
#pragma unroll
        for (int e = 0; e < 32; e += 8) {
            float4 a4 = *(const float4*)(kp + e);
            float4 b4 = *(const float4*)(kp + e + 4);
            short8 v8;
            v8[0] = (short)f2bf(a4.x); v8[1] = (short)f2bf(a4.y);
            v8[2] = (short)f2bf(a4.z); v8[3] = (short)f2bf(a4.w);
            v8[4] = (short)f2bf(b4.x); v8[5] = (short)f2bf(b4.y);
            v8[6] = (short)f2bf(b4.z); v8[7] = (short)f2bf(b4.w);
            *(short8*)&Kb[i * 136 + q4 * 32 + e] = v8;
            a4 = *(const float4*)(qp + e);
            b4 = *(const float4*)(qp + e + 4);
            v8[0] = (short)f2bf(a4.x); v8[1] = (short)f2bf(a4.y);
            v8[2] = (short)f2bf(a4.z); v8[3] = (short)f2bf(a4.w);
            v8[4] = (short)f2bf(b4.x); v8[5] = (short)f2bf(b4.y);
            v8[6] = (short)f2bf(b4.z); v8[7] = (short)f2bf(b4.w);
            *(short8*)&Qb[i * 136 + q4 * 32 + e] = v8;
        }
        if (tid < 64) {
            garr[tid] = Glog[(size_t)(row0 + tid) * 8 + h];
            betl[tid] = Beta[(size_t)(row0 + tid) * 8 + h];
        }
    }
    __syncthreads();
    if (tid < 64) {
        float gsum = 0.f;
        for (int j = 0; j <= tid; j++) gsum += garr[j];
        Gl[tid] = gsum;
        Pl[tid] = expf(gsum);
    }
    __syncthreads();
    if (tid == 0) Pcs[bhc] = Pl[63];
    if (tid < 64) decf[tid] = expf(Gl[63] - Gl[tid]);

    int lr = lane & 15, lk8 = (lane >> 4) * 8;
    // D = K K^T tiles (nt <= w) -> L (strict lower, scaled)
    for (int nt = 0; nt <= w; nt++) {
        f32x4 acc = {};
#pragma unroll
        for (int kk = 0; kk < 4; kk++) {
            short8 af = *(const short8*)&Kb[(w * 16 + lr) * 136 + kk * 32 + lk8];
            short8 bfr = *(const short8*)&Kb[(nt * 16 + lr) * 136 + kk * 32 + lk8];
            acc = __builtin_amdgcn_mfma_f32_16x16x32_bf16(af, bfr, acc, 0, 0, 0);
        }
#pragma unroll
        for (int r = 0; r < 4; r++) {
            int i = w * 16 + (lane >> 4) * 4 + r;
            int j = nt * 16 + lr;
            if (j < i) Lm[i * 64 + j] = betl[i] * expf(Gl[i] - Gl[j]) * acc[r];
        }
    }
    // E = Q K^T tiles -> SM (incl diag, scaled); zeros for upper
    for (int nt = 0; nt < 4; nt++) {
        f32x4 acc = {};
        if (nt <= w) {
#pragma unroll
            for (int kk = 0; kk < 4; kk++) {
                short8 af = *(const short8*)&Qb[(w * 16 + lr) * 136 + kk * 32 + lk8];
                short8 bfr = *(const short8*)&Kb[(nt * 16 + lr) * 136 + kk * 32 + lk8];
                acc = __builtin_amdgcn_mfma_f32_16x16x32_bf16(af, bfr, acc, 0, 0, 0);
            }
        }
#pragma unroll
        for (int r = 0; r < 4; r++) {
            int i = w * 16 + (lane >> 4) * 4 + r;
            int j = nt * 16 + lr;
            float vv = (nt <= w && j <= i) ? SCALEQ * expf(Gl[i] - Gl[j]) * acc[r] : 0.f;
            SMg[((size_t)bhc * 64 + i) * 64 + j] = f2bf(vv);
        }
    }
    // seeds (column ownership): t<128 -> W col d; t>=128 -> U col c
    if (tid < 128) {
        int d = tid;
        for (int i = 0; i < 64; i++)
            Wm[i * 128 + d] = betl[i] * Pl[i] * bf2f(Kb[i * 136 + d]);
    } else {
        int cc = tid - 128;
        const float* vp = V + (size_t)row0 * DIM + col0 + cc;
        for (int i = 0; i < 64; i++)
            Um[i * 128 + cc] = betl[i] * vp[(size_t)i * DIM];
    }
    __syncthreads();  // Lm visible
    // forward substitution, column-per-thread (no syncs)
    {
        float* Mm = (tid < 128) ? Wm : Um;
        int d = tid & 127;
        for (int i = 1; i < 64; i++) {
            float acc = Mm[i * 128 + d];
            for (int j = 0; j < i; j++)
                acc = fmaf(-Lm[i * 64 + j], Mm[j * 128 + d], acc);
            Mm[i * 128 + d] = acc;
        }
    }
    __syncthreads();
    // outputs: lanes along d (conflict-free LDS reads, coalesced global)
    {
        int d = tid & 127, ih = tid >> 7;
        for (int i0 = 0; i0 < 32; i0++) {
            int i = ih * 32 + i0;
            size_t gb = ((size_t)bhc * 64 + i) * 128 + d;
            Wg[gb] = f2bf(Wm[i * 128 + d]);
            Ug[gb] = f2bf(Um[i * 128 + d]);
            Qg[gb] = f2bf(SCALEQ * Pl[i] * bf2f(Qb[i * 136 + d]));
        }
        int jh = ih;
        for (int j8 = 0; j8 < 32; j8 += 8) {
            short8 v8;
#pragma unroll
            for (int e = 0; e < 8; e++) {
                int jj = jh * 32 + j8 + e;
                v8[e] = (short)f2bf(decf[jj] * bf2f(Kb[jj * 136 + d]));
            }
            *(short8*)&KTg[((size_t)bhc * 128 + d) * 64 + jh * 32 + j8] = v8;
        }
    }
}

// Phase 2: sequential over 32 chunks. Grid 256 = dvg*32 + bh (16 dv cols each), 512 thr.
__global__ __launch_bounds__(512) void chunk_scan_kernel(
    const unsigned short* __restrict__ Wg, const unsigned short* __restrict__ Ug,
    const unsigned short* __restrict__ Qg, const unsigned short* __restrict__ KTg,
    const unsigned short* __restrict__ SMg, const float* __restrict__ Pcs,
    float* __restrict__ O) {
    int blk = blockIdx.x;
    int bh = blk & 31, dvg = blk >> 5;
    int b = bh >> 3, h = bh & 7;
    int col16 = dvg * 16;
    int tid = threadIdx.x;

    __shared__ __align__(16) unsigned short Wl[64 * 136];
    __shared__ __align__(16) unsigned short Ql[64 * 136];
    __shared__ __align__(16) unsigned short KTl[128 * 72];
    __shared__ __align__(16) unsigned short SMl[64 * 72];
    __shared__ float Sf[128 * 16];
    __shared__ float Dl[64 * 16];

    for (int e = tid; e < 128 * 16; e += 512) Sf[e] = 0.f;
    __syncthreads();

    for (int c = 0; c < 32; c++) {
        int bhc = bh * 32 + c;
        float pc = Pcs[bhc];
        size_t base8k = (size_t)bhc * 8192;
        // stage
        {
            const short8* ws8 = (const short8*)(Wg + base8k);
            const short8* qs8 = (const short8*)(Qg + base8k);
            const short8* ks8 = (const short8*)(KTg + base8k);
            const short8* ss8 = (const short8*)(SMg + (size_t)bhc * 4096);
            int v = tid;
            *(short8*)&Wl[(v >> 4) * 136 + (v & 15) * 8] = ws8[v];
            *(short8*)&Ql[(v >> 4) * 136 + (v & 15) * 8] = qs8[v];
            *(short8*)&KTl[(v >> 3) * 72 + (v & 7) * 8] = ks8[v];
            *(short8*)&SMl[(v >> 3) * 72 + (v & 7) * 8] = ss8[v];
            v = tid + 512;
            *(short8*)&Wl[(v >> 4) * 136 + (v & 15) * 8] = ws8[v];
            *(short8*)&Ql[(v >> 4) * 136 + (v & 15) * 8] = qs8[v];
            *(short8*)&KTl[(v >> 3) * 72 + (v & 7) * 8] = ks8[v];
        }
        __syncthreads();
        int i = tid >> 3, cg = tid & 7, cc = cg * 2;
        // Delta = U - W @ S0
        {
            float a0 = 0.f, a1 = 0.f;
            for (int d8 = 0; d8 < 128; d8 += 8) {
                short8 wv8 = *(const short8*)&Wl[i * 136 + d8];
#pragma unroll
                for (int e = 0; e < 8; e++) {
                    float wv = bf2f((unsigned short)wv8[e]);
                    const float* sp = &Sf[(d8 + e) * 16];
                    a0 = fmaf(wv, sp[cc], a0);
                    a1 = fmaf(wv, sp[cc + 1], a1);
                }
            }
            const unsigned short* up = Ug + base8k + (size_t)i * 128 + col16 + cc;
            Dl[i * 16 + cc] = bf2f(up[0]) - a0;
            Dl[i * 16 + cc + 1] = bf2f(up[1]) - a1;
        }
        __syncthreads();
        // O = Q' @ S0 + SM @ Delta
        {
            float a0 = 0.f, a1 = 0.f;
            for (int d8 = 0; d8 < 128; d8 += 8) {
                short8 qv8 = *(const short8*)&Ql[i * 136 + d8];
#pragma unroll
                for (int e = 0; e < 8; e++) {
                    float qv = bf2f((unsigned short)qv8[e]);
                    const float* sp = &Sf[(d8 + e) * 16];
                    a0 = fmaf(qv, sp[cc], a0);
                    a1 = fmaf(qv, sp[cc + 1], a1);
                }
            }
            for (int j8 = 0; j8 < 64; j8 += 8) {
                short8 sv8 = *(const short8*)&SMl[i * 72 + j8];
#pragma unroll
                for (int e = 0; e < 8; e++) {
                    float sm = bf2f((unsigned short)sv8[e]);
                    const float* dp = &Dl[(j8 + e) * 16];
                    a0 = fmaf(sm, dp[cc], a0);
                    a1 = fmaf(sm, dp[cc + 1], a1);
                }
            }
            size_t orow = ((size_t)(b * 2048 + c * 64 + i)) * DIM + h * 128 + col16 + cc;
            O[orow] = a0;
            O[orow + 1] = a1;
        }
        __syncthreads();
        // S = pc*S + K'^T @ Delta
        {
            int d = tid >> 2, cg4 = tid & 3, c4 = cg4 * 4;
            float b0 = 0.f, b1 = 0.f, b2 = 0.f, b3 = 0.f;
            for (int j8 = 0; j8 < 64; j8 += 8) {
                short8 kv8 = *(const short8*)&KTl[d * 72 + j8];
#pragma unroll
                for (int e = 0; e < 8; e++) {
                    float kv = bf2f((unsigned short)kv8[e]);
                    float4 dv = *(const float4*)&Dl[(j8 + e) * 16 + c4];
                    b0 = fmaf(kv, dv.x, b0);
                    b1 = fmaf(kv, dv.y, b1);
                    b2 = fmaf(kv, dv.z, b2);
                    b3 = fmaf(kv, dv.w, b3);
                }
            }
            float* sp = &Sf[d * 16 + c4];
            sp[0] = pc * sp[0] + b0;
            sp[1] = pc * sp[1] + b1;
            sp[2] = pc * sp[2] + b2;
            sp[3] = pc * sp[3] + b3;
        }
        __syncthreads();
    }
}

extern "C" void kernel_launch(void* const* d_in, const int* in_sizes, int n_in,
                              void* d_out, int out_size, void* d_ws, size_t ws_size,
                              hipStream_t stream) {
    const float* x      = (const float*)d_in[0];
    const float* Wq     = (const float*)d_in[1];
    const float* Wk     = (const float*)d_in[2];
    const float* Wv     = (const float*)d_in[3];
    const float* Wb     = (const float*)d_in[4];
    const float* Wa     = (const float*)d_in[5];
    const float* A_log  = (const float*)d_in[6];
    const float* dt_b   = (const float*)d_in[7];
    const float* Wg_in  = (const float*)d_in[8];
    const float* o_norm = (const float*)d_in[9];
    const float* Wo     = (const float*)d_in[10];
    const float* W_fc   = (const float*)d_in[11];
    const float* W_proj = (const float*)d_in[12];
    float* out = (float*)d_out;

    const size_t MAT = (size_t)ROWS * DIM;
    float* ws = (float*)d_ws;
    float* fq    = ws;                 // q fp32 -> O (chunked)
    float* fk    = ws + MAT;
    float* fv    = ws + 2 * MAT;       // v fp32; later o_bf
    float* fgate = ws + 3 * MAT;
    float* fo    = ws + 4 * MAT;       // h_bf -> Wg/Ug (chunked) or o f32 (fallback) -> m_bf
    float* glog  = ws + 5 * MAT;
    float* beta  = glog + (size_t)ROWS * NH;
    float* alpha = beta + (size_t)ROWS * NH;
    unsigned short* wts = (unsigned short*)(alpha + (size_t)ROWS * NH);
    unsigned short* WqT = wts;
    unsigned short* WkT = wts + (1u << 20);
    unsigned short* WvT = wts + 2 * (1u << 20);
    unsigned short* WgT = wts + 3 * (1u << 20);
    unsigned short* WoT = wts + 4 * (1u << 20);
    unsigned short* WfcT = wts + 5 * (1u << 20);
    unsigned short* WprT = wts + 9 * (1u << 20);
    // chunked extra region
    unsigned short* Qg2 = wts + 13 * (1u << 20);
    unsigned short* KTg = Qg2 + (8u << 20);
    unsigned short* SMg = KTg + (8u << 20);
    float* pcs = (float*)(SMg + (4u << 20));
    size_t need = (size_t)((char*)(pcs + 1024) - (char*)d_ws);
    bool chunked = (ws_size >= need);
    unsigned short* Wgb = (unsigned short*)fo;
    unsigned short* Ugb = Wgb + (8u << 20);

    unsigned short* h_bf = (unsigned short*)fo;
    unsigned short* m_bf = (unsigned short*)fo;
    unsigned short* o_bf = (unsigned short*)fv;
    unsigned short* fc_bf = (unsigned short*)ws;

    // 0. weight transposes -> bf16 [N,K]
    transpose_bf16_kernel<<<dim3(32, 32), 256, 0, stream>>>(Wq, WqT, 1024, 1024);
    transpose_bf16_kernel<<<dim3(32, 32), 256, 0, stream>>>(Wk, WkT, 1024, 1024);
    transpose_bf16_kernel<<<dim3(32, 32), 256, 0, stream>>>(Wv, WvT, 1024, 1024);
    transpose_bf16_kernel<<<dim3(32, 32), 256, 0, stream>>>(Wg_in, WgT, 1024, 1024);
    transpose_bf16_kernel<<<dim3(32, 32), 256, 0, stream>>>(Wo, WoT, 1024, 1024);
    transpose_bf16_kernel<<<dim3(128, 32), 256, 0, stream>>>(W_fc, WfcT, 1024, 4096);
    transpose_bf16_kernel<<<dim3(32, 128), 256, 0, stream>>>(W_proj, WprT, 4096, 1024);

    // 1. h = rms_norm(x) -> bf16
    rmsnorm_bf16_kernel<<<ROWS, 256, 0, stream>>>(x, h_bf);

    // 2. projections
    dim3 g1(DIM / 128, ROWS / 128);
    mfma_gemm<1, float><<<g1, 256, 0, stream>>>(h_bf, WqT, fq, nullptr, ROWS, DIM, DIM);
    mfma_gemm<1, float><<<g1, 256, 0, stream>>>(h_bf, WkT, fk, nullptr, ROWS, DIM, DIM);
    mfma_gemm<1, float><<<g1, 256, 0, stream>>>(h_bf, WvT, fv, nullptr, ROWS, DIM, DIM);
    mfma_gemm<0, float><<<g1, 256, 0, stream>>>(h_bf, WgT, fgate, nullptr, ROWS, DIM, DIM);

    // 3. l2norm q, k
    l2norm_kernel<<<ROWS, 256, 0, stream>>>(fq);
    l2norm_kernel<<<ROWS, 256, 0, stream>>>(fk);

    // 4. beta/glog/alpha
    smallproj_kernel<<<ROWS, 128, 0, stream>>>(h_bf, Wb, Wa, A_log, dt_b, glog, alpha, beta);

    // 5. delta-rule scan
    const float* o_src;
    if (chunked) {
        chunk_prep_kernel<<<1024, 256, 0, stream>>>(fq, fk, fv, glog, beta,
                                                    Wgb, Ugb, Qg2, KTg, SMg, pcs);
        chunk_scan_kernel<<<256, 512, 0, stream>>>(Wgb, Ugb, Qg2, KTg, SMg, pcs, fq);
        o_src = fq;
    } else {
        scan_kernel<<<256, 128, 0, stream>>>(fq, fk, fv, alpha, beta, fo);
        o_src = fo;
    }

    // 6. gated RMSNorm -> o_bf
    gating_kernel<<<ROWS, 256, 0, stream>>>(o_src, fgate, o_norm, o_bf);

    // 7. d_out = x + o @ Wo
    mfma_gemm<2, float><<<g1, 256, 0, stream>>>(o_bf, WoT, out, x, ROWS, DIM, DIM);

    // 8. m = rms_norm(d_out) -> m_bf
    rmsnorm_bf16_kernel<<<ROWS, 256, 0, stream>>>(out, m_bf);

    // 9. fc = relu(m @ W_fc)^2 -> bf16
    dim3 g2(DFF_ / 128, ROWS / 128);
    mfma_gemm<3, unsigned short><<<g2, 256, 0, stream>>>(m_bf, WfcT, fc_bf, nullptr, ROWS, DFF_, DIM);

    // 10. d_out += fc @ W_proj
    mfma_gemm<2, float><<<g1, 256, 0, stream>>>(fc_bf, WprT, out, out, ROWS, DIM, DFF_);
}

// Round 6
// 722.165 us; speedup vs baseline: 2.1900x; 1.2510x over previous
//
#include <hip/hip_runtime.h>
#include <math.h>
#include <stdint.h>

#define ROWS 8192   // B*S
#define DIM  1024
#define NH   8
#define DFF_ 4096
#define EPSF 1e-6f
#define SCALEQ 0.08838834764831845f  // DK^-0.5

typedef __attribute__((ext_vector_type(8))) short short8;
typedef __attribute__((ext_vector_type(4))) float f32x4;

__device__ __forceinline__ float siluf(float x) {
    return x / (1.0f + expf(-x));
}
__device__ __forceinline__ unsigned short f2bf(float f) {
    uint32_t u = __float_as_uint(f);
    uint32_t r = (u + 0x7FFFu + ((u >> 16) & 1u)) >> 16;
    return (unsigned short)r;
}
__device__ __forceinline__ float bf2f(unsigned short u) {
    return __uint_as_float(((uint32_t)u) << 16);
}

// async global->LDS 16B (wave-uniform LDS base + lane*16)
__device__ __forceinline__ void async16(const void* g, void* l) {
    __builtin_amdgcn_global_load_lds(
        (const __attribute__((address_space(1))) uint32_t*)g,
        (__attribute__((address_space(3))) uint32_t*)l, 16, 0, 0);
}

// DPP adds for fallback scan
template <int C>
__device__ __forceinline__ float dpp_add(float x) {
    int y = __builtin_amdgcn_update_dpp(0, __float_as_int(x), C, 0xF, 0xF, true);
    return x + __int_as_float(y);
}
__device__ __forceinline__ float red8(float x) {
    x = dpp_add<0xB1>(x);
    x = dpp_add<0x4E>(x);
    x = dpp_add<0x141>(x);
    return x;
}

// ---------------- RMSNorm -> bf16 out ----------------
__global__ void rmsnorm_bf16_kernel(const float* __restrict__ x, unsigned short* __restrict__ y) {
    int row = blockIdx.x;
    int tid = threadIdx.x;  // 256
    const float4* x4 = (const float4*)(x + (size_t)row * DIM);
    float4 v = x4[tid];
    float ss = v.x * v.x + v.y * v.y + v.z * v.z + v.w * v.w;
#pragma unroll
    for (int m = 1; m < 64; m <<= 1) ss += __shfl_xor(ss, m, 64);
    __shared__ float wss[4];
    if ((tid & 63) == 0) wss[tid >> 6] = ss;
    __syncthreads();
    float tot = wss[0] + wss[1] + wss[2] + wss[3];
    float r = rsqrtf(tot * (1.0f / 1024.0f) + EPSF);
    ushort4 o;
    o.x = f2bf(v.x * r); o.y = f2bf(v.y * r); o.z = f2bf(v.z * r); o.w = f2bf(v.w * r);
    ((ushort4*)(y + (size_t)row * DIM))[tid] = o;
}

// ---------------- fp32 -> bf16 transpose: W[K,N] -> WT[N,K] ----------------
__global__ void transpose_bf16_kernel(const float* __restrict__ W, unsigned short* __restrict__ WT,
                                      int K, int N) {
    __shared__ float tile[32][33];
    int n0 = blockIdx.x * 32, k0 = blockIdx.y * 32;
    int tx = threadIdx.x & 31, ty = threadIdx.x >> 5;
#pragma unroll
    for (int r = 0; r < 32; r += 8)
        tile[ty + r][tx] = W[(size_t)(k0 + ty + r) * N + n0 + tx];
    __syncthreads();
#pragma unroll
    for (int r = 0; r < 32; r += 8)
        WT[(size_t)(n0 + ty + r) * K + k0 + tx] = f2bf(tile[tx][ty + r]);
}

// ---------------- bf16 MFMA GEMM: C[M,N] = A[M,K] @ BT[N,K]^T ----------------
template <int EPI, typename CT>
__global__ __launch_bounds__(256) void mfma_gemm(
    const unsigned short* __restrict__ A, const unsigned short* __restrict__ BT,
    CT* __restrict__ C, const float* __restrict__ res, int M, int N, int K) {
    __shared__ __align__(16) unsigned short As[128 * 32];
    __shared__ __align__(16) unsigned short Bs[128 * 32];
    int tid = threadIdx.x;
    int w = tid >> 6, lane = tid & 63;

    int nwgx = gridDim.x;
    int nwg = nwgx * gridDim.y;
    int id = blockIdx.y * nwgx + blockIdx.x;
    int cpx = nwg >> 3;
    int nid = (id & 7) * cpx + (id >> 3);
    int bxs = nid % nwgx, bys = nid / nwgx;

    int bm = bys * 128, bn = bxs * 128;
    int wm = (w >> 1) * 64, wn = (w & 1) * 64;

    int srow = tid >> 2;
    int skb = (tid & 3) * 8;
    const unsigned short* Ag = A + (size_t)(bm + srow) * K + skb;
    const unsigned short* Bg = BT + (size_t)(bn + srow) * K + skb;

    f32x4 acc[4][4] = {};

    int lr = lane & 15;
    int lk = (lane >> 4) * 8;

    for (int kt = 0; kt < K; kt += 32) {
        async16(Ag + kt, As + w * 512);
        async16(Ag + kt + (size_t)64 * K, As + 2048 + w * 512);
        async16(Bg + kt, Bs + w * 512);
        async16(Bg + kt + (size_t)64 * K, Bs + 2048 + w * 512);
        __syncthreads();
        short8 af[4], bf[4];
#pragma unroll
        for (int i = 0; i < 4; i++) {
            af[i] = *(const short8*)&As[(wm + i * 16 + lr) * 32 + lk];
            bf[i] = *(const short8*)&Bs[(wn + i * 16 + lr) * 32 + lk];
        }
#pragma unroll
        for (int i = 0; i < 4; i++)
#pragma unroll
            for (int j = 0; j < 4; j++)
                acc[i][j] = __builtin_amdgcn_mfma_f32_16x16x32_bf16(af[i], bf[j], acc[i][j], 0, 0, 0);
        __syncthreads();
    }

#pragma unroll
    for (int i = 0; i < 4; i++) {
        int gr0 = bm + wm + i * 16 + (lane >> 4) * 4;
#pragma unroll
        for (int j = 0; j < 4; j++) {
            int gc = bn + wn + j * 16 + lr;
#pragma unroll
            for (int r = 0; r < 4; r++) {
                float v = acc[i][j][r];
                size_t idx = (size_t)(gr0 + r) * N + gc;
                if (EPI == 1) v = siluf(v);
                else if (EPI == 2) v += res[idx];
                else if (EPI == 3) { float t = fmaxf(v, 0.0f); v = t * t; }
                if constexpr (sizeof(CT) == 2) C[idx] = (CT)f2bf(v);
                else C[idx] = v;
            }
        }
    }
}

// ---------------- fused QKVG projection: N=4096 concat of [Wq|Wk|Wv|Wg]^T ----------------
// silu on q,k,v (bsel<3); raw for gate. Outputs to 4 separate [M,1024] fp32 buffers.
__global__ __launch_bounds__(256) void mfma_gemm_qkvg(
    const unsigned short* __restrict__ A, const unsigned short* __restrict__ BT,
    float* __restrict__ oq, float* __restrict__ ok, float* __restrict__ ov,
    float* __restrict__ og, int M, int K) {
    const int N = 4096;
    __shared__ __align__(16) unsigned short As[128 * 32];
    __shared__ __align__(16) unsigned short Bs[128 * 32];
    int tid = threadIdx.x;
    int w = tid >> 6, lane = tid & 63;

    int nwgx = gridDim.x;
    int nwg = nwgx * gridDim.y;
    int id = blockIdx.y * nwgx + blockIdx.x;
    int cpx = nwg >> 3;
    int nid = (id & 7) * cpx + (id >> 3);
    int bxs = nid % nwgx, bys = nid / nwgx;

    int bm = bys * 128, bn = bxs * 128;
    int wm = (w >> 1) * 64, wn = (w & 1) * 64;

    int srow = tid >> 2;
    int skb = (tid & 3) * 8;
    const unsigned short* Ag = A + (size_t)(bm + srow) * K + skb;
    const unsigned short* Bg = BT + (size_t)(bn + srow) * K + skb;

    f32x4 acc[4][4] = {};
    int lr = lane & 15;
    int lk = (lane >> 4) * 8;

    for (int kt = 0; kt < K; kt += 32) {
        async16(Ag + kt, As + w * 512);
        async16(Ag + kt + (size_t)64 * K, As + 2048 + w * 512);
        async16(Bg + kt, Bs + w * 512);
        async16(Bg + kt + (size_t)64 * K, Bs + 2048 + w * 512);
        __syncthreads();
        short8 af[4], bf[4];
#pragma unroll
        for (int i = 0; i < 4; i++) {
            af[i] = *(const short8*)&As[(wm + i * 16 + lr) * 32 + lk];
            bf[i] = *(const short8*)&Bs[(wn + i * 16 + lr) * 32 + lk];
        }
#pragma unroll
        for (int i = 0; i < 4; i++)
#pragma unroll
            for (int j = 0; j < 4; j++)
                acc[i][j] = __builtin_amdgcn_mfma_f32_16x16x32_bf16(af[i], bf[j], acc[i][j], 0, 0, 0);
        __syncthreads();
    }

    int bsel = bn >> 10;
    float* C = (bsel == 0) ? oq : (bsel == 1) ? ok : (bsel == 2) ? ov : og;
    int bnl = bn & 1023;
    bool dosilu = (bsel < 3);
#pragma unroll
    for (int i = 0; i < 4; i++) {
        int gr0 = bm + wm + i * 16 + (lane >> 4) * 4;
#pragma unroll
        for (int j = 0; j < 4; j++) {
            int gc = bnl + wn + j * 16 + lr;
#pragma unroll
            for (int r = 0; r < 4; r++) {
                float v = acc[i][j][r];
                if (dosilu) v = siluf(v);
                C[(size_t)(gr0 + r) * 1024 + gc] = v;
            }
        }
    }
}

// ---------------- l2norm over 128-chunks (in-place fp32) ----------------
__global__ void l2norm_kernel(float* __restrict__ x) {
    int row = blockIdx.x;
    int tid = threadIdx.x;
    float4* p = (float4*)(x + (size_t)row * DIM);
    float4 v = p[tid];
    float ss = v.x * v.x + v.y * v.y + v.z * v.z + v.w * v.w;
#pragma unroll
    for (int m = 1; m < 32; m <<= 1) ss += __shfl_xor(ss, m, 32);
    float r = rsqrtf(ss + EPSF);
    v.x *= r; v.y *= r; v.z *= r; v.w *= r;
    p[tid] = v;
}

// ---------------- gated RMSNorm -> bf16 ----------------
__global__ void gating_kernel(const float* __restrict__ o, const float* __restrict__ gate,
                              const float* __restrict__ w, unsigned short* __restrict__ ob) {
    int row = blockIdx.x;
    int tid = threadIdx.x;
    const float4* op = (const float4*)(o + (size_t)row * DIM);
    const float4* gp = (const float4*)(gate + (size_t)row * DIM);
    float4 v = op[tid];
    float ss = v.x * v.x + v.y * v.y + v.z * v.z + v.w * v.w;
#pragma unroll
    for (int m = 1; m < 32; m <<= 1) ss += __shfl_xor(ss, m, 32);
    float r = rsqrtf(ss * (1.0f / 128.0f) + EPSF);
    float4 g = gp[tid];
    float4 wv = ((const float4*)w)[tid & 31];
    ushort4 out;
    out.x = f2bf(v.x * r * wv.x * siluf(g.x));
    out.y = f2bf(v.y * r * wv.y * siluf(g.y));
    out.z = f2bf(v.z * r * wv.z * siluf(g.z));
    out.w = f2bf(v.w * r * wv.w * siluf(g.w));
    ((ushort4*)(ob + (size_t)row * DIM))[tid] = out;
}

// ---------------- small projections: beta, glog, alpha ----------------
__global__ void smallproj_kernel(const unsigned short* __restrict__ hbuf,
                                 const float* __restrict__ Wb, const float* __restrict__ Wa,
                                 const float* __restrict__ A_log, const float* __restrict__ dt_bias,
                                 float* __restrict__ Glog, float* __restrict__ Alpha,
                                 float* __restrict__ Beta) {
    int row = blockIdx.x;
    int tid = threadIdx.x;  // 128
    __shared__ __align__(16) float hrow[1024];
    __shared__ float part[128];
    const ushort4* h4 = (const ushort4*)(hbuf + (size_t)row * DIM);
    ushort4 u0 = h4[tid * 2], u1 = h4[tid * 2 + 1];
    hrow[tid * 8 + 0] = bf2f(u0.x); hrow[tid * 8 + 1] = bf2f(u0.y);
    hrow[tid * 8 + 2] = bf2f(u0.z); hrow[tid * 8 + 3] = bf2f(u0.w);
    hrow[tid * 8 + 4] = bf2f(u1.x); hrow[tid * 8 + 5] = bf2f(u1.y);
    hrow[tid * 8 + 6] = bf2f(u1.z); hrow[tid * 8 + 7] = bf2f(u1.w);
    __syncthreads();
    int out = tid & 15, slice = tid >> 4;
    const float* W = (out < 8) ? Wb : Wa;
    int col = out & 7;
    int k0 = slice * 128;
    float p = 0.0f;
    for (int kk = 0; kk < 128; kk++) p += hrow[k0 + kk] * W[(size_t)(k0 + kk) * 8 + col];
    part[tid] = p;
    __syncthreads();
    if (tid < 16) {
        float sum = 0.0f;
#pragma unroll
        for (int sl = 0; sl < 8; sl++) sum += part[sl * 16 + tid];
        if (tid < 8) {
            Beta[(size_t)row * 8 + tid] = 1.0f / (1.0f + expf(-sum));
        } else {
            int hh = tid - 8;
            float xg = sum + dt_bias[hh];
            float sp = fmaxf(xg, 0.0f) + log1pf(expf(-fabsf(xg)));
            float gl = -expf(A_log[hh]) * sp;
            Glog[(size_t)row * 8 + hh] = gl;
            Alpha[(size_t)row * 8 + hh] = expf(gl);
        }
    }
}

// ---------------- fallback scan (R3 structure) ----------------
#define SCAN_LOAD(P, tn) do {                                                   \
    size_t ro_ = (size_t)(tn) * 256;                                            \
    P##k0 = Kp[ro_ + 0]; P##k1 = Kp[ro_ + 1];                                   \
    P##k2 = Kp[ro_ + 2]; P##k3 = Kp[ro_ + 3];                                   \
    P##q0 = Qp[ro_ + 0]; P##q1 = Qp[ro_ + 1];                                   \
    P##q2 = Qp[ro_ + 2]; P##q3 = Qp[ro_ + 3];                                   \
    P##v = Vp[(size_t)(tn) * DIM];                                              \
    P##a = Ap[(size_t)(tn) * 8]; P##b = Bp[(size_t)(tn) * 8];                   \
} while (0)

#define SCAN_STEP(P, t) do {                                                    \
    float kv0 = fmaf(P##k0.x, s[0], fmaf(P##k0.y, s[1], fmaf(P##k0.z, s[2], P##k0.w * s[3])));   \
    float kv1 = fmaf(P##k1.x, s[4], fmaf(P##k1.y, s[5], fmaf(P##k1.z, s[6], P##k1.w * s[7])));   \
    float kv2 = fmaf(P##k2.x, s[8], fmaf(P##k2.y, s[9], fmaf(P##k2.z, s[10], P##k2.w * s[11]))); \
    float kv3 = fmaf(P##k3.x, s[12], fmaf(P##k3.y, s[13], fmaf(P##k3.z, s[14], P##k3.w * s[15])));\
    float kv = red8((kv0 + kv1) + (kv2 + kv3));                                 \
    float delta = (P##v - P##a * kv) * P##b;                                    \
    float o0, o1, o2, o3;                                                       \
    s[0]  = fmaf(P##k0.x, delta, P##a * s[0]);  o0 = P##q0.x * s[0];            \
    s[1]  = fmaf(P##k0.y, delta, P##a * s[1]);  o1 = P##q0.y * s[1];            \
    s[2]  = fmaf(P##k0.z, delta, P##a * s[2]);  o2 = P##q0.z * s[2];            \
    s[3]  = fmaf(P##k0.w, delta, P##a * s[3]);  o3 = P##q0.w * s[3];            \
    s[4]  = fmaf(P##k1.x, delta, P##a * s[4]);  o0 = fmaf(P##q1.x, s[4], o0);   \
    s[5]  = fmaf(P##k1.y, delta, P##a * s[5]);  o1 = fmaf(P##q1.y, s[5], o1);   \
    s[6]  = fmaf(P##k1.z, delta, P##a * s[6]);  o2 = fmaf(P##q1.z, s[6], o2);   \
    s[7]  = fmaf(P##k1.w, delta, P##a * s[7]);  o3 = fmaf(P##q1.w, s[7], o3);   \
    s[8]  = fmaf(P##k2.x, delta, P##a * s[8]);  o0 = fmaf(P##q2.x, s[8], o0);   \
    s[9]  = fmaf(P##k2.y, delta, P##a * s[9]);  o1 = fmaf(P##q2.y, s[9], o1);   \
    s[10] = fmaf(P##k2.z, delta, P##a * s[10]); o2 = fmaf(P##q2.z, s[10], o2);  \
    s[11] = fmaf(P##k2.w, delta, P##a * s[11]); o3 = fmaf(P##q2.w, s[11], o3);  \
    s[12] = fmaf(P##k3.x, delta, P##a * s[12]); o0 = fmaf(P##q3.x, s[12], o0);  \
    s[13] = fmaf(P##k3.y, delta, P##a * s[13]); o1 = fmaf(P##q3.y, s[13], o1);  \
    s[14] = fmaf(P##k3.z, delta, P##a * s[14]); o2 = fmaf(P##q3.z, s[14], o2);  \
    s[15] = fmaf(P##k3.w, delta, P##a * s[15]); o3 = fmaf(P##q3.w, s[15], o3);  \
    float oacc = red8((o0 + o1) + (o2 + o3));                                   \
    if (ks == 0) Op[(size_t)(t) * DIM] = oacc * scale;                          \
} while (0)

__global__ __launch_bounds__(128) void scan_kernel(
    const float* __restrict__ Q, const float* __restrict__ Kb,
    const float* __restrict__ V, const float* __restrict__ Alpha,
    const float* __restrict__ Beta, float* __restrict__ O) {
    int blk = blockIdx.x;
    int bh = blk >> 3, dvb = blk & 7;
    int b = bh >> 3, h = bh & 7;
    int tid = threadIdx.x;
    int ks = tid & 7;
    int dvl = tid >> 3;
    int col_k = h * 128 + ks * 16;
    int col_v = h * 128 + dvb * 16 + dvl;
    size_t base0 = (size_t)b * 2048 * DIM;

    const float4* Kp = (const float4*)(Kb + base0 + col_k);
    const float4* Qp = (const float4*)(Q + base0 + col_k);
    const float* Vp = V + base0 + col_v;
    const float* Ap = Alpha + (size_t)b * 2048 * 8 + h;
    const float* Bp = Beta + (size_t)b * 2048 * 8 + h;
    float* Op = O + base0 + col_v;

    float s[16];
#pragma unroll
    for (int i = 0; i < 16; i++) s[i] = 0.0f;

    const float scale = SCALEQ;

    float4 Ak0, Ak1, Ak2, Ak3, Aq0, Aq1, Aq2, Aq3;
    float Av, Aa, Ab;
    float4 Bk0, Bk1, Bk2, Bk3, Bq0, Bq1, Bq2, Bq3;
    float Bv, Ba, Bb;

    SCAN_LOAD(A, 0);
    SCAN_LOAD(B, 1);

    int t = 0;
    for (; t < 2046; t += 2) {
        SCAN_STEP(A, t);
        SCAN_LOAD(A, t + 2);
        SCAN_STEP(B, t + 1);
        SCAN_LOAD(B, t + 3);
    }
    SCAN_STEP(A, 2046);
    SCAN_STEP(B, 2047);
}

// ================= chunked gated delta rule =================
// Phase 1: per (b,h,chunk=64): decays, (I+L) solve -> W,U; SM, Q', K'T, pC.
__global__ __launch_bounds__(256) void chunk_prep_kernel(
    const float* __restrict__ Q, const float* __restrict__ K,
    const float* __restrict__ V, const float* __restrict__ Glog,
    const float* __restrict__ Beta,
    unsigned short* __restrict__ Wg, unsigned short* __restrict__ Ug,
    unsigned short* __restrict__ Qg, unsigned short* __restrict__ KTg,
    unsigned short* __restrict__ SMg, float* __restrict__ Pcs) {
    int blk = blockIdx.x;
    int bh = blk & 31, c = blk >> 5;
    int b = bh >> 3, h = bh & 7;
    int bhc = bh * 32 + c;
    int row0 = b * 2048 + c * 64;
    int col0 = h * 128;
    int tid = threadIdx.x;
    int w = tid >> 6, lane = tid & 63;

    __shared__ __align__(16) unsigned short Kb[64 * 136];
    __shared__ __align__(16) unsigned short Qb[64 * 136];
    __shared__ float Lm[64 * 64];
    __shared__ float Wm[64 * 128];
    __shared__ float Um[64 * 128];
    __shared__ float garr[64], betl[64], Gl[64], Pl[64], decf[64];

    {
        int i = tid >> 2, q4 = tid & 3;
        const float* kp = K + (size_t)(row0 + i) * DIM + col0 + q4 * 32;
        const float* qp = Q + (size_t)(row0 + i) * DIM + col0 + q4 * 32;
#pragma unroll
        for (int e = 0; e < 32; e += 8) {
            float4 a4 = *(const float4*)(kp + e);
            float4 b4 = *(const float4*)(kp + e + 4);
            short8 v8;
            v8[0] = (short)f2bf(a4.x); v8[1] = (short)f2bf(a4.y);
            v8[2] = (short)f2bf(a4.z); v8[3] = (short)f2bf(a4.w);
            v8[4] = (short)f2bf(b4.x); v8[5] = (short)f2bf(b4.y);
            v8[6] = (short)f2bf(b4.z); v8[7] = (short)f2bf(b4.w);
            *(short8*)&Kb[i * 136 + q4 * 32 + e] = v8;
            a4 = *(const float4*)(qp + e);
            b4 = *(const float4*)(qp + e + 4);
            v8[0] = (short)f2bf(a4.x); v8[1] = (short)f2bf(a4.y);
            v8[2] = (short)f2bf(a4.z); v8[3] = (short)f2bf(a4.w);
            v8[4] = (short)f2bf(b4.x); v8[5] = (short)f2bf(b4.y);
            v8[6] = (short)f2bf(b4.z); v8[7] = (short)f2bf(b4.w);
            *(short8*)&Qb[i * 136 + q4 * 32 + e] = v8;
        }
        if (tid < 64) {
            garr[tid] = Glog[(size_t)(row0 + tid) * 8 + h];
            betl[tid] = Beta[(size_t)(row0 + tid) * 8 + h];
        }
    }
    __syncthreads();
    if (tid < 64) {
        float gsum = 0.f;
        for (int j = 0; j <= tid; j++) gsum += garr[j];
        Gl[tid] = gsum;
        Pl[tid] = expf(gsum);
    }
    __syncthreads();
    if (tid == 0) Pcs[bhc] = Pl[63];
    if (tid < 64) decf[tid] = expf(Gl[63] - Gl[tid]);

    int lr = lane & 15, lk8 = (lane >> 4) * 8;
    for (int nt = 0; nt <= w; nt++) {
        f32x4 acc = {};
#pragma unroll
        for (int kk = 0; kk < 4; kk++) {
            short8 af = *(const short8*)&Kb[(w * 16 + lr) * 136 + kk * 32 + lk8];
            short8 bfr = *(const short8*)&Kb[(nt * 16 + lr) * 136 + kk * 32 + lk8];
            acc = __builtin_amdgcn_mfma_f32_16x16x32_bf16(af, bfr, acc, 0, 0, 0);
        }
#pragma unroll
        for (int r = 0; r < 4; r++) {
            int i = w * 16 + (lane >> 4) * 4 + r;
            int j = nt * 16 + lr;
            if (j < i) Lm[i * 64 + j] = betl[i] * expf(Gl[i] - Gl[j]) * acc[r];
        }
    }
    for (int nt = 0; nt < 4; nt++) {
        f32x4 acc = {};
        if (nt <= w) {
#pragma unroll
            for (int kk = 0; kk < 4; kk++) {
                short8 af = *(const short8*)&Qb[(w * 16 + lr) * 136 + kk * 32 + lk8];
                short8 bfr = *(const short8*)&Kb[(nt * 16 + lr) * 136 + kk * 32 + lk8];
                acc = __builtin_amdgcn_mfma_f32_16x16x32_bf16(af, bfr, acc, 0, 0, 0);
            }
        }
#pragma unroll
        for (int r = 0; r < 4; r++) {
            int i = w * 16 + (lane >> 4) * 4 + r;
            int j = nt * 16 + lr;
            float vv = (nt <= w && j <= i) ? SCALEQ * expf(Gl[i] - Gl[j]) * acc[r] : 0.f;
            SMg[((size_t)bhc * 64 + i) * 64 + j] = f2bf(vv);
        }
    }
    if (tid < 128) {
        int d = tid;
        for (int i = 0; i < 64; i++)
            Wm[i * 128 + d] = betl[i] * Pl[i] * bf2f(Kb[i * 136 + d]);
    } else {
        int cc = tid - 128;
        const float* vp = V + (size_t)row0 * DIM + col0 + cc;
        for (int i = 0; i < 64; i++)
            Um[i * 128 + cc] = betl[i] * vp[(size_t)i * DIM];
    }
    __syncthreads();
    {
        float* Mm = (tid < 128) ? Wm : Um;
        int d = tid & 127;
        for (int i = 1; i < 64; i++) {
            float acc = Mm[i * 128 + d];
            for (int j = 0; j < i; j++)
                acc = fmaf(-Lm[i * 64 + j], Mm[j * 128 + d], acc);
            Mm[i * 128 + d] = acc;
        }
    }
    __syncthreads();
    {
        int d = tid & 127, ih = tid >> 7;
        for (int i0 = 0; i0 < 32; i0++) {
            int i = ih * 32 + i0;
            size_t gb = ((size_t)bhc * 64 + i) * 128 + d;
            Wg[gb] = f2bf(Wm[i * 128 + d]);
            Ug[gb] = f2bf(Um[i * 128 + d]);
            Qg[gb] = f2bf(SCALEQ * Pl[i] * bf2f(Qb[i * 136 + d]));
        }
        int jh = ih;
        for (int j8 = 0; j8 < 32; j8 += 8) {
            short8 v8;
#pragma unroll
            for (int e = 0; e < 8; e++) {
                int jj = jh * 32 + j8 + e;
                v8[e] = (short)f2bf(decf[jj] * bf2f(Kb[jj * 136 + d]));
            }
            *(short8*)&KTg[((size_t)bhc * 128 + d) * 64 + jh * 32 + j8] = v8;
        }
    }
}

// Phase 2 (MFMA): sequential over 32 chunks. Grid 256 = dvg*32 + bh, 256 thr (4 waves).
// Wave wv owns i-tile wv (Delta/O rows 16wv..16wv+15) and S d-tiles {2wv, 2wv+1}.
// State acc stays fp32 across chunks; S^T readout copy is bf16 in LDS (non-accumulating error).
__global__ __launch_bounds__(256) void chunk_scan2_kernel(
    const unsigned short* __restrict__ Wg, const unsigned short* __restrict__ Ug,
    const unsigned short* __restrict__ Qg, const unsigned short* __restrict__ KTg,
    const unsigned short* __restrict__ SMg, const float* __restrict__ Pcs,
    float* __restrict__ O) {
    int blk = blockIdx.x;
    int bh = blk & 31, dvg = blk >> 5;  // same-bh blocks share blk%8 -> one XCD
    int b = bh >> 3, h = bh & 7;
    int col16 = dvg * 16;
    int tid = threadIdx.x;
    int wv = tid >> 6, lane = tid & 63;
    int lr = lane & 15, lk8 = (lane >> 4) * 8, l4 = (lane >> 4) * 4;
    int i0 = wv * 16;

    __shared__ __align__(16) unsigned short Wl[64 * 136];   // [i][d]
    __shared__ __align__(16) unsigned short Ql[64 * 136];   // [i][d]
    __shared__ __align__(16) unsigned short KTl[128 * 72];  // [d][j]
    __shared__ __align__(16) unsigned short SMl[64 * 72];   // [i][j]
    __shared__ __align__(16) unsigned short Ul[64 * 24];    // [i][c16]
    __shared__ __align__(16) unsigned short STl[16 * 136];  // S^T [c][d]
    __shared__ __align__(16) unsigned short DTl[16 * 72];   // Delta^T [c][j]

    for (int e = tid; e < 16 * 136; e += 256) STl[e] = 0;

    f32x4 Sacc[2] = {};  // d-tiles 2wv, 2wv+1 (fp32 state, persists across chunks)

    for (int c = 0; c < 32; c++) {
        int bhc = bh * 32 + c;
        size_t base8k = (size_t)bhc * 8192;
        float pc = Pcs[bhc];
        // ---- stage chunk operands ----
#pragma unroll
        for (int r = 0; r < 4; r++) {
            int v = tid + r * 256;
            *(short8*)&Wl[(v >> 4) * 136 + (v & 15) * 8] = *(const short8*)(Wg + base8k + (size_t)v * 8);
            *(short8*)&Ql[(v >> 4) * 136 + (v & 15) * 8] = *(const short8*)(Qg + base8k + (size_t)v * 8);
            *(short8*)&KTl[(v >> 3) * 72 + (v & 7) * 8] = *(const short8*)(KTg + base8k + (size_t)v * 8);
        }
#pragma unroll
        for (int r = 0; r < 2; r++) {
            int v = tid + r * 256;
            *(short8*)&SMl[(v >> 3) * 72 + (v & 7) * 8] = *(const short8*)(SMg + (size_t)bhc * 4096 + (size_t)v * 8);
        }
        if (tid < 128) {
            int row = tid >> 1, hf = tid & 1;
            *(short8*)&Ul[row * 24 + hf * 8] =
                *(const short8*)(Ug + base8k + (size_t)row * 128 + col16 + hf * 8);
        }
        __syncthreads();  // bar1: stage + prev S^T visible

        // ---- phase A: acc0 = W@S0, acc1 = Q'@S0; Delta = U - acc0 ----
        f32x4 acc0 = {}, acc1 = {};
#pragma unroll
        for (int kd = 0; kd < 4; kd++) {
            short8 bfs = *(const short8*)&STl[lr * 136 + kd * 32 + lk8];
            short8 aw = *(const short8*)&Wl[(i0 + lr) * 136 + kd * 32 + lk8];
            short8 aq = *(const short8*)&Ql[(i0 + lr) * 136 + kd * 32 + lk8];
            acc0 = __builtin_amdgcn_mfma_f32_16x16x32_bf16(aw, bfs, acc0, 0, 0, 0);
            acc1 = __builtin_amdgcn_mfma_f32_16x16x32_bf16(aq, bfs, acc1, 0, 0, 0);
        }
        ushort4 dpk;
        dpk.x = f2bf(bf2f(Ul[(i0 + l4 + 0) * 24 + lr]) - acc0[0]);
        dpk.y = f2bf(bf2f(Ul[(i0 + l4 + 1) * 24 + lr]) - acc0[1]);
        dpk.z = f2bf(bf2f(Ul[(i0 + l4 + 2) * 24 + lr]) - acc0[2]);
        dpk.w = f2bf(bf2f(Ul[(i0 + l4 + 3) * 24 + lr]) - acc0[3]);
        *(ushort4*)&DTl[lr * 72 + i0 + l4] = dpk;
        __syncthreads();  // bar2: Delta^T visible

        // ---- phase B: O = acc1 + SM@Delta; S = pc*S + K'T@Delta ----
#pragma unroll
        for (int dt = 0; dt < 2; dt++)
#pragma unroll
            for (int r = 0; r < 4; r++) Sacc[dt][r] *= pc;
#pragma unroll
        for (int kj = 0; kj < 2; kj++) {
            short8 bfd = *(const short8*)&DTl[lr * 72 + kj * 32 + lk8];
            short8 as = *(const short8*)&SMl[(i0 + lr) * 72 + kj * 32 + lk8];
            acc1 = __builtin_amdgcn_mfma_f32_16x16x32_bf16(as, bfd, acc1, 0, 0, 0);
#pragma unroll
            for (int dt = 0; dt < 2; dt++) {
                short8 ak = *(const short8*)&KTl[((2 * wv + dt) * 16 + lr) * 72 + kj * 32 + lk8];
                Sacc[dt] = __builtin_amdgcn_mfma_f32_16x16x32_bf16(ak, bfd, Sacc[dt], 0, 0, 0);
            }
        }
        {
            int orow0 = b * 2048 + c * 64 + i0 + l4;
            int ocol = h * 128 + col16 + lr;
#pragma unroll
            for (int r = 0; r < 4; r++)
                O[(size_t)(orow0 + r) * DIM + ocol] = acc1[r];
        }
#pragma unroll
        for (int dt = 0; dt < 2; dt++) {
            ushort4 sp;
            sp.x = f2bf(Sacc[dt][0]);
            sp.y = f2bf(Sacc[dt][1]);
            sp.z = f2bf(Sacc[dt][2]);
            sp.w = f2bf(Sacc[dt][3]);
            *(ushort4*)&STl[lr * 136 + (2 * wv + dt) * 16 + l4] = sp;
        }
        __syncthreads();  // bar3: S^T written; SMl/KTl/DTl reads done before restage
    }
}

extern "C" void kernel_launch(void* const* d_in, const int* in_sizes, int n_in,
                              void* d_out, int out_size, void* d_ws, size_t ws_size,
                              hipStream_t stream) {
    const float* x      = (const float*)d_in[0];
    const float* Wq     = (const float*)d_in[1];
    const float* Wk     = (const float*)d_in[2];
    const float* Wv     = (const float*)d_in[3];
    const float* Wb     = (const float*)d_in[4];
    const float* Wa     = (const float*)d_in[5];
    const float* A_log  = (const float*)d_in[6];
    const float* dt_b   = (const float*)d_in[7];
    const float* Wg_in  = (const float*)d_in[8];
    const float* o_norm = (const float*)d_in[9];
    const float* Wo     = (const float*)d_in[10];
    const float* W_fc   = (const float*)d_in[11];
    const float* W_proj = (const float*)d_in[12];
    float* out = (float*)d_out;

    const size_t MAT = (size_t)ROWS * DIM;
    float* ws = (float*)d_ws;
    float* fq    = ws;                 // q fp32 -> O (chunked)
    float* fk    = ws + MAT;
    float* fv    = ws + 2 * MAT;       // v fp32; later o_bf
    float* fgate = ws + 3 * MAT;
    float* fo    = ws + 4 * MAT;       // h_bf -> Wg/Ug (chunked) or o f32 (fallback) -> m_bf
    float* glog  = ws + 5 * MAT;
    float* beta  = glog + (size_t)ROWS * NH;
    float* alpha = beta + (size_t)ROWS * NH;
    unsigned short* wts = (unsigned short*)(alpha + (size_t)ROWS * NH);
    unsigned short* WqT = wts;          // [4096,1024] concat: Wq|Wk|Wv|Wg rows
    unsigned short* WkT = wts + (1u << 20);
    unsigned short* WvT = wts + 2 * (1u << 20);
    unsigned short* WgT = wts + 3 * (1u << 20);
    unsigned short* WoT = wts + 4 * (1u << 20);
    unsigned short* WfcT = wts + 5 * (1u << 20);
    unsigned short* WprT = wts + 9 * (1u << 20);
    // chunked extra region
    unsigned short* Qg2 = wts + 13 * (1u << 20);
    unsigned short* KTg = Qg2 + (8u << 20);
    unsigned short* SMg = KTg + (8u << 20);
    float* pcs = (float*)(SMg + (4u << 20));
    size_t need = (size_t)((char*)(pcs + 1024) - (char*)d_ws);
    bool chunked = (ws_size >= need);
    unsigned short* Wgb = (unsigned short*)fo;
    unsigned short* Ugb = Wgb + (8u << 20);

    unsigned short* h_bf = (unsigned short*)fo;
    unsigned short* m_bf = (unsigned short*)fo;
    unsigned short* o_bf = (unsigned short*)fv;
    unsigned short* fc_bf = (unsigned short*)ws;

    // 0. weight transposes -> bf16 [N,K]
    transpose_bf16_kernel<<<dim3(32, 32), 256, 0, stream>>>(Wq, WqT, 1024, 1024);
    transpose_bf16_kernel<<<dim3(32, 32), 256, 0, stream>>>(Wk, WkT, 1024, 1024);
    transpose_bf16_kernel<<<dim3(32, 32), 256, 0, stream>>>(Wv, WvT, 1024, 1024);
    transpose_bf16_kernel<<<dim3(32, 32), 256, 0, stream>>>(Wg_in, WgT, 1024, 1024);
    transpose_bf16_kernel<<<dim3(32, 32), 256, 0, stream>>>(Wo, WoT, 1024, 1024);
    transpose_bf16_kernel<<<dim3(128, 32), 256, 0, stream>>>(W_fc, WfcT, 1024, 4096);
    transpose_bf16_kernel<<<dim3(32, 128), 256, 0, stream>>>(W_proj, WprT, 4096, 1024);

    // 1. h = rms_norm(x) -> bf16
    rmsnorm_bf16_kernel<<<ROWS, 256, 0, stream>>>(x, h_bf);

    // 2. fused QKVG projection (WqT..WgT are contiguous -> single BT of N=4096)
    mfma_gemm_qkvg<<<dim3(4096 / 128, ROWS / 128), 256, 0, stream>>>(
        h_bf, WqT, fq, fk, fv, fgate, ROWS, DIM);

    // 3. l2norm q, k
    l2norm_kernel<<<ROWS, 256, 0, stream>>>(fq);
    l2norm_kernel<<<ROWS, 256, 0, stream>>>(fk);

    // 4. beta/glog/alpha
    smallproj_kernel<<<ROWS, 128, 0, stream>>>(h_bf, Wb, Wa, A_log, dt_b, glog, alpha, beta);

    // 5. delta-rule scan
    const float* o_src;
    dim3 g1(DIM / 128, ROWS / 128);
    if (chunked) {
        chunk_prep_kernel<<<1024, 256, 0, stream>>>(fq, fk, fv, glog, beta,
                                                    Wgb, Ugb, Qg2, KTg, SMg, pcs);
        chunk_scan2_kernel<<<256, 256, 0, stream>>>(Wgb, Ugb, Qg2, KTg, SMg, pcs, fq);
        o_src = fq;
    } else {
        scan_kernel<<<256, 128, 0, stream>>>(fq, fk, fv, alpha, beta, fo);
        o_src = fo;
    }

    // 6. gated RMSNorm -> o_bf
    gating_kernel<<<ROWS, 256, 0, stream>>>(o_src, fgate, o_norm, o_bf);

    // 7. d_out = x + o @ Wo
    mfma_gemm<2, float><<<g1, 256, 0, stream>>>(o_bf, WoT, out, x, ROWS, DIM, DIM);

    // 8. m = rms_norm(d_out) -> m_bf
    rmsnorm_bf16_kernel<<<ROWS, 256, 0, stream>>>(out, m_bf);

    // 9. fc = relu(m @ W_fc)^2 -> bf16
    dim3 g2(DFF_ / 128, ROWS / 128);
    mfma_gemm<3, unsigned short><<<g2, 256, 0, stream>>>(m_bf, WfcT, fc_bf, nullptr, ROWS, DFF_, DIM);

    // 10. d_out += fc @ W_proj
    mfma_gemm<2, float><<<g1, 256, 0, stream>>>(fc_bf, WprT, out, out, ROWS, DIM, DFF_);
}

// Round 7
// 646.728 us; speedup vs baseline: 2.4455x; 1.1166x over previous
//
#include <hip/hip_runtime.h>
#include <math.h>
#include <stdint.h>

#define ROWS 8192   // B*S
#define DIM  1024
#define NH   8
#define DFF_ 4096
#define EPSF 1e-6f
#define SCALEQ 0.08838834764831845f  // DK^-0.5

typedef __attribute__((ext_vector_type(8))) short short8;
typedef __attribute__((ext_vector_type(4))) float f32x4;

__device__ __forceinline__ float siluf(float x) {
    return x / (1.0f + expf(-x));
}
__device__ __forceinline__ unsigned short f2bf(float f) {
    uint32_t u = __float_as_uint(f);
    uint32_t r = (u + 0x7FFFu + ((u >> 16) & 1u)) >> 16;
    return (unsigned short)r;
}
__device__ __forceinline__ float bf2f(unsigned short u) {
    return __uint_as_float(((uint32_t)u) << 16);
}

// async global->LDS 16B (wave-uniform LDS base + lane*16)
__device__ __forceinline__ void async16(const void* g, void* l) {
    __builtin_amdgcn_global_load_lds(
        (const __attribute__((address_space(1))) uint32_t*)g,
        (__attribute__((address_space(3))) uint32_t*)l, 16, 0, 0);
}

// DPP adds for fallback scan
template <int C>
__device__ __forceinline__ float dpp_add(float x) {
    int y = __builtin_amdgcn_update_dpp(0, __float_as_int(x), C, 0xF, 0xF, true);
    return x + __int_as_float(y);
}
__device__ __forceinline__ float red8(float x) {
    x = dpp_add<0xB1>(x);
    x = dpp_add<0x4E>(x);
    x = dpp_add<0x141>(x);
    return x;
}

// ---------------- RMSNorm -> bf16 out ----------------
__global__ void rmsnorm_bf16_kernel(const float* __restrict__ x, unsigned short* __restrict__ y) {
    int row = blockIdx.x;
    int tid = threadIdx.x;  // 256
    const float4* x4 = (const float4*)(x + (size_t)row * DIM);
    float4 v = x4[tid];
    float ss = v.x * v.x + v.y * v.y + v.z * v.z + v.w * v.w;
#pragma unroll
    for (int m = 1; m < 64; m <<= 1) ss += __shfl_xor(ss, m, 64);
    __shared__ float wss[4];
    if ((tid & 63) == 0) wss[tid >> 6] = ss;
    __syncthreads();
    float tot = wss[0] + wss[1] + wss[2] + wss[3];
    float r = rsqrtf(tot * (1.0f / 1024.0f) + EPSF);
    ushort4 o;
    o.x = f2bf(v.x * r); o.y = f2bf(v.y * r); o.z = f2bf(v.z * r); o.w = f2bf(v.w * r);
    ((ushort4*)(y + (size_t)row * DIM))[tid] = o;
}

// ---------------- fp32 -> bf16 transpose: W[K,N] -> WT[N,K] ----------------
__global__ void transpose_bf16_kernel(const float* __restrict__ W, unsigned short* __restrict__ WT,
                                      int K, int N) {
    __shared__ float tile[32][33];
    int n0 = blockIdx.x * 32, k0 = blockIdx.y * 32;
    int tx = threadIdx.x & 31, ty = threadIdx.x >> 5;
#pragma unroll
    for (int r = 0; r < 32; r += 8)
        tile[ty + r][tx] = W[(size_t)(k0 + ty + r) * N + n0 + tx];
    __syncthreads();
#pragma unroll
    for (int r = 0; r < 32; r += 8)
        WT[(size_t)(n0 + ty + r) * K + k0 + tx] = f2bf(tile[tx][ty + r]);
}

// ---------------- bf16 MFMA GEMM: C[M,N] = A[M,K] @ BT[N,K]^T ----------------
template <int EPI, typename CT>
__global__ __launch_bounds__(256) void mfma_gemm(
    const unsigned short* __restrict__ A, const unsigned short* __restrict__ BT,
    CT* __restrict__ C, const float* __restrict__ res, int M, int N, int K) {
    __shared__ __align__(16) unsigned short As[128 * 32];
    __shared__ __align__(16) unsigned short Bs[128 * 32];
    int tid = threadIdx.x;
    int w = tid >> 6, lane = tid & 63;

    int nwgx = gridDim.x;
    int nwg = nwgx * gridDim.y;
    int id = blockIdx.y * nwgx + blockIdx.x;
    int cpx = nwg >> 3;
    int nid = (id & 7) * cpx + (id >> 3);
    int bxs = nid % nwgx, bys = nid / nwgx;

    int bm = bys * 128, bn = bxs * 128;
    int wm = (w >> 1) * 64, wn = (w & 1) * 64;

    int srow = tid >> 2;
    int skb = (tid & 3) * 8;
    const unsigned short* Ag = A + (size_t)(bm + srow) * K + skb;
    const unsigned short* Bg = BT + (size_t)(bn + srow) * K + skb;

    f32x4 acc[4][4] = {};

    int lr = lane & 15;
    int lk = (lane >> 4) * 8;

    for (int kt = 0; kt < K; kt += 32) {
        async16(Ag + kt, As + w * 512);
        async16(Ag + kt + (size_t)64 * K, As + 2048 + w * 512);
        async16(Bg + kt, Bs + w * 512);
        async16(Bg + kt + (size_t)64 * K, Bs + 2048 + w * 512);
        __syncthreads();
        short8 af[4], bf[4];
#pragma unroll
        for (int i = 0; i < 4; i++) {
            af[i] = *(const short8*)&As[(wm + i * 16 + lr) * 32 + lk];
            bf[i] = *(const short8*)&Bs[(wn + i * 16 + lr) * 32 + lk];
        }
#pragma unroll
        for (int i = 0; i < 4; i++)
#pragma unroll
            for (int j = 0; j < 4; j++)
                acc[i][j] = __builtin_amdgcn_mfma_f32_16x16x32_bf16(af[i], bf[j], acc[i][j], 0, 0, 0);
        __syncthreads();
    }

#pragma unroll
    for (int i = 0; i < 4; i++) {
        int gr0 = bm + wm + i * 16 + (lane >> 4) * 4;
#pragma unroll
        for (int j = 0; j < 4; j++) {
            int gc = bn + wn + j * 16 + lr;
#pragma unroll
            for (int r = 0; r < 4; r++) {
                float v = acc[i][j][r];
                size_t idx = (size_t)(gr0 + r) * N + gc;
                if (EPI == 1) v = siluf(v);
                else if (EPI == 2) v += res[idx];
                else if (EPI == 3) { float t = fmaxf(v, 0.0f); v = t * t; }
                if constexpr (sizeof(CT) == 2) C[idx] = (CT)f2bf(v);
                else C[idx] = v;
            }
        }
    }
}

// ---------------- fused QKVG projection + silu + per-head l2norm ----------------
// N=4096 concat [Wq|Wk|Wv|Wg]^T. bsel<3: silu; bsel<2 (q,k): per-row l2norm over
// the block's 128 cols (exactly one head chunk). Outputs 4 separate [M,1024] f32.
__global__ __launch_bounds__(256) void mfma_gemm_qkvg(
    const unsigned short* __restrict__ A, const unsigned short* __restrict__ BT,
    float* __restrict__ oq, float* __restrict__ ok, float* __restrict__ ov,
    float* __restrict__ og, int M, int K) {
    __shared__ __align__(16) unsigned short As[128 * 32];
    __shared__ __align__(16) unsigned short Bs[128 * 32];
    int tid = threadIdx.x;
    int w = tid >> 6, lane = tid & 63;

    int nwgx = gridDim.x;
    int nwg = nwgx * gridDim.y;
    int id = blockIdx.y * nwgx + blockIdx.x;
    int cpx = nwg >> 3;
    int nid = (id & 7) * cpx + (id >> 3);
    int bxs = nid % nwgx, bys = nid / nwgx;

    int bm = bys * 128, bn = bxs * 128;
    int wm = (w >> 1) * 64, wn = (w & 1) * 64;

    int srow = tid >> 2;
    int skb = (tid & 3) * 8;
    const unsigned short* Ag = A + (size_t)(bm + srow) * K + skb;
    const unsigned short* Bg = BT + (size_t)(bn + srow) * K + skb;

    f32x4 acc[4][4] = {};
    int lr = lane & 15;
    int lk = (lane >> 4) * 8;
    int l4 = (lane >> 4) * 4;

    for (int kt = 0; kt < K; kt += 32) {
        async16(Ag + kt, As + w * 512);
        async16(Ag + kt + (size_t)64 * K, As + 2048 + w * 512);
        async16(Bg + kt, Bs + w * 512);
        async16(Bg + kt + (size_t)64 * K, Bs + 2048 + w * 512);
        __syncthreads();
        short8 af[4], bf[4];
#pragma unroll
        for (int i = 0; i < 4; i++) {
            af[i] = *(const short8*)&As[(wm + i * 16 + lr) * 32 + lk];
            bf[i] = *(const short8*)&Bs[(wn + i * 16 + lr) * 32 + lk];
        }
#pragma unroll
        for (int i = 0; i < 4; i++)
#pragma unroll
            for (int j = 0; j < 4; j++)
                acc[i][j] = __builtin_amdgcn_mfma_f32_16x16x32_bf16(af[i], bf[j], acc[i][j], 0, 0, 0);
        __syncthreads();
    }

    int bsel = bn >> 10;
    int bnl = bn & 1023;
    if (bsel < 3) {
#pragma unroll
        for (int i = 0; i < 4; i++)
#pragma unroll
            for (int j = 0; j < 4; j++)
#pragma unroll
                for (int r = 0; r < 4; r++)
                    acc[i][j][r] = siluf(acc[i][j][r]);
    }
    float* sums = (float*)As;  // [128][2] partial row sums (As dead after main loop)
    bool donorm = (bsel < 2);
    if (donorm) {
#pragma unroll
        for (int i = 0; i < 4; i++) {
#pragma unroll
            for (int r = 0; r < 4; r++) {
                float p = acc[i][0][r] * acc[i][0][r] + acc[i][1][r] * acc[i][1][r] +
                          acc[i][2][r] * acc[i][2][r] + acc[i][3][r] * acc[i][3][r];
                p += __shfl_xor(p, 1, 16);
                p += __shfl_xor(p, 2, 16);
                p += __shfl_xor(p, 4, 16);
                p += __shfl_xor(p, 8, 16);
                if (lr == 0) sums[(wm + i * 16 + l4 + r) * 2 + (wn >> 6)] = p;
            }
        }
        __syncthreads();
    }
    float* C = (bsel == 0) ? oq : (bsel == 1) ? ok : (bsel == 2) ? ov : og;
#pragma unroll
    for (int i = 0; i < 4; i++) {
#pragma unroll
        for (int r = 0; r < 4; r++) {
            int lrow = wm + i * 16 + l4 + r;
            float rn = 1.0f;
            if (donorm) rn = rsqrtf(sums[lrow * 2] + sums[lrow * 2 + 1] + EPSF);
            size_t gr = (size_t)(bm + lrow) * 1024;
#pragma unroll
            for (int j = 0; j < 4; j++) {
                int gc = bnl + wn + j * 16 + lr;
                C[gr + gc] = acc[i][j][r] * rn;
            }
        }
    }
}

// ---------------- gated RMSNorm -> bf16 ----------------
__global__ void gating_kernel(const float* __restrict__ o, const float* __restrict__ gate,
                              const float* __restrict__ w, unsigned short* __restrict__ ob) {
    int row = blockIdx.x;
    int tid = threadIdx.x;
    const float4* op = (const float4*)(o + (size_t)row * DIM);
    const float4* gp = (const float4*)(gate + (size_t)row * DIM);
    float4 v = op[tid];
    float ss = v.x * v.x + v.y * v.y + v.z * v.z + v.w * v.w;
#pragma unroll
    for (int m = 1; m < 32; m <<= 1) ss += __shfl_xor(ss, m, 32);
    float r = rsqrtf(ss * (1.0f / 128.0f) + EPSF);
    float4 g = gp[tid];
    float4 wv = ((const float4*)w)[tid & 31];
    ushort4 out;
    out.x = f2bf(v.x * r * wv.x * siluf(g.x));
    out.y = f2bf(v.y * r * wv.y * siluf(g.y));
    out.z = f2bf(v.z * r * wv.z * siluf(g.z));
    out.w = f2bf(v.w * r * wv.w * siluf(g.w));
    ((ushort4*)(ob + (size_t)row * DIM))[tid] = out;
}

// ---------------- small projections: beta, glog, alpha ----------------
__global__ void smallproj_kernel(const unsigned short* __restrict__ hbuf,
                                 const float* __restrict__ Wb, const float* __restrict__ Wa,
                                 const float* __restrict__ A_log, const float* __restrict__ dt_bias,
                                 float* __restrict__ Glog, float* __restrict__ Alpha,
                                 float* __restrict__ Beta) {
    int row = blockIdx.x;
    int tid = threadIdx.x;  // 128
    __shared__ __align__(16) float hrow[1024];
    __shared__ float part[128];
    const ushort4* h4 = (const ushort4*)(hbuf + (size_t)row * DIM);
    ushort4 u0 = h4[tid * 2], u1 = h4[tid * 2 + 1];
    hrow[tid * 8 + 0] = bf2f(u0.x); hrow[tid * 8 + 1] = bf2f(u0.y);
    hrow[tid * 8 + 2] = bf2f(u0.z); hrow[tid * 8 + 3] = bf2f(u0.w);
    hrow[tid * 8 + 4] = bf2f(u1.x); hrow[tid * 8 + 5] = bf2f(u1.y);
    hrow[tid * 8 + 6] = bf2f(u1.z); hrow[tid * 8 + 7] = bf2f(u1.w);
    __syncthreads();
    int out = tid & 15, slice = tid >> 4;
    const float* W = (out < 8) ? Wb : Wa;
    int col = out & 7;
    int k0 = slice * 128;
    float p = 0.0f;
    for (int kk = 0; kk < 128; kk++) p += hrow[k0 + kk] * W[(size_t)(k0 + kk) * 8 + col];
    part[tid] = p;
    __syncthreads();
    if (tid < 16) {
        float sum = 0.0f;
#pragma unroll
        for (int sl = 0; sl < 8; sl++) sum += part[sl * 16 + tid];
        if (tid < 8) {
            Beta[(size_t)row * 8 + tid] = 1.0f / (1.0f + expf(-sum));
        } else {
            int hh = tid - 8;
            float xg = sum + dt_bias[hh];
            float sp = fmaxf(xg, 0.0f) + log1pf(expf(-fabsf(xg)));
            float gl = -expf(A_log[hh]) * sp;
            Glog[(size_t)row * 8 + hh] = gl;
            Alpha[(size_t)row * 8 + hh] = expf(gl);
        }
    }
}

// ---------------- fallback scan (R3 structure) ----------------
#define SCAN_LOAD(P, tn) do {                                                   \
    size_t ro_ = (size_t)(tn) * 256;                                            \
    P##k0 = Kp[ro_ + 0]; P##k1 = Kp[ro_ + 1];                                   \
    P##k2 = Kp[ro_ + 2]; P##k3 = Kp[ro_ + 3];                                   \
    P##q0 = Qp[ro_ + 0]; P##q1 = Qp[ro_ + 1];                                   \
    P##q2 = Qp[ro_ + 2]; P##q3 = Qp[ro_ + 3];                                   \
    P##v = Vp[(size_t)(tn) * DIM];                                              \
    P##a = Ap[(size_t)(tn) * 8]; P##b = Bp[(size_t)(tn) * 8];                   \
} while (0)

#define SCAN_STEP(P, t) do {                                                    \
    float kv0 = fmaf(P##k0.x, s[0], fmaf(P##k0.y, s[1], fmaf(P##k0.z, s[2], P##k0.w * s[3])));   \
    float kv1 = fmaf(P##k1.x, s[4], fmaf(P##k1.y, s[5], fmaf(P##k1.z, s[6], P##k1.w * s[7])));   \
    float kv2 = fmaf(P##k2.x, s[8], fmaf(P##k2.y, s[9], fmaf(P##k2.z, s[10], P##k2.w * s[11]))); \
    float kv3 = fmaf(P##k3.x, s[12], fmaf(P##k3.y, s[13], fmaf(P##k3.z, s[14], P##k3.w * s[15])));\
    float kv = red8((kv0 + kv1) + (kv2 + kv3));                                 \
    float delta = (P##v - P##a * kv) * P##b;                                    \
    float o0, o1, o2, o3;                                                       \
    s[0]  = fmaf(P##k0.x, delta, P##a * s[0]);  o0 = P##q0.x * s[0];            \
    s[1]  = fmaf(P##k0.y, delta, P##a * s[1]);  o1 = P##q0.y * s[1];            \
    s[2]  = fmaf(P##k0.z, delta, P##a * s[2]);  o2 = P##q0.z * s[2];            \
    s[3]  = fmaf(P##k0.w, delta, P##a * s[3]);  o3 = P##q0.w * s[3];            \
    s[4]  = fmaf(P##k1.x, delta, P##a * s[4]);  o0 = fmaf(P##q1.x, s[4], o0);   \
    s[5]  = fmaf(P##k1.y, delta, P##a * s[5]);  o1 = fmaf(P##q1.y, s[5], o1);   \
    s[6]  = fmaf(P##k1.z, delta, P##a * s[6]);  o2 = fmaf(P##q1.z, s[6], o2);   \
    s[7]  = fmaf(P##k1.w, delta, P##a * s[7]);  o3 = fmaf(P##q1.w, s[7], o3);   \
    s[8]  = fmaf(P##k2.x, delta, P##a * s[8]);  o0 = fmaf(P##q2.x, s[8], o0);   \
    s[9]  = fmaf(P##k2.y, delta, P##a * s[9]);  o1 = fmaf(P##q2.y, s[9], o1);   \
    s[10] = fmaf(P##k2.z, delta, P##a * s[10]); o2 = fmaf(P##q2.z, s[10], o2);  \
    s[11] = fmaf(P##k2.w, delta, P##a * s[11]); o3 = fmaf(P##q2.w, s[11], o3);  \
    s[12] = fmaf(P##k3.x, delta, P##a * s[12]); o0 = fmaf(P##q3.x, s[12], o0);  \
    s[13] = fmaf(P##k3.y, delta, P##a * s[13]); o1 = fmaf(P##q3.y, s[13], o1);  \
    s[14] = fmaf(P##k3.z, delta, P##a * s[14]); o2 = fmaf(P##q3.z, s[14], o2);  \
    s[15] = fmaf(P##k3.w, delta, P##a * s[15]); o3 = fmaf(P##q3.w, s[15], o3);  \
    float oacc = red8((o0 + o1) + (o2 + o3));                                   \
    if (ks == 0) Op[(size_t)(t) * DIM] = oacc * scale;                          \
} while (0)

__global__ __launch_bounds__(128) void scan_kernel(
    const float* __restrict__ Q, const float* __restrict__ Kb,
    const float* __restrict__ V, const float* __restrict__ Alpha,
    const float* __restrict__ Beta, float* __restrict__ O) {
    int blk = blockIdx.x;
    int bh = blk >> 3, dvb = blk & 7;
    int b = bh >> 3, h = bh & 7;
    int tid = threadIdx.x;
    int ks = tid & 7;
    int dvl = tid >> 3;
    int col_k = h * 128 + ks * 16;
    int col_v = h * 128 + dvb * 16 + dvl;
    size_t base0 = (size_t)b * 2048 * DIM;

    const float4* Kp = (const float4*)(Kb + base0 + col_k);
    const float4* Qp = (const float4*)(Q + base0 + col_k);
    const float* Vp = V + base0 + col_v;
    const float* Ap = Alpha + (size_t)b * 2048 * 8 + h;
    const float* Bp = Beta + (size_t)b * 2048 * 8 + h;
    float* Op = O + base0 + col_v;

    float s[16];
#pragma unroll
    for (int i = 0; i < 16; i++) s[i] = 0.0f;

    const float scale = SCALEQ;

    float4 Ak0, Ak1, Ak2, Ak3, Aq0, Aq1, Aq2, Aq3;
    float Av, Aa, Ab;
    float4 Bk0, Bk1, Bk2, Bk3, Bq0, Bq1, Bq2, Bq3;
    float Bv, Ba, Bb;

    SCAN_LOAD(A, 0);
    SCAN_LOAD(B, 1);

    int t = 0;
    for (; t < 2046; t += 2) {
        SCAN_STEP(A, t);
        SCAN_LOAD(A, t + 2);
        SCAN_STEP(B, t + 1);
        SCAN_LOAD(B, t + 3);
    }
    SCAN_STEP(A, 2046);
    SCAN_STEP(B, 2047);
}

// ================= chunked gated delta rule =================
// Phase 1 v2: blocked-MFMA forward substitution.
// per (b,h,chunk=64): decays; L,SM via MFMA; (I+L)X=B solved in 4 blocks of 16:
// off-block corr via MFMA over Mt=X^T (bf16, zero-init self-masks), in-block
// serial per-column in registers. W/U stored register->global coalesced.
__global__ __launch_bounds__(256) void chunk_prep_kernel(
    const float* __restrict__ Q, const float* __restrict__ K,
    const float* __restrict__ V, const float* __restrict__ Glog,
    const float* __restrict__ Beta,
    unsigned short* __restrict__ Wg, unsigned short* __restrict__ Ug,
    unsigned short* __restrict__ Qg, unsigned short* __restrict__ KTg,
    unsigned short* __restrict__ SMg, float* __restrict__ Pcs) {
    int blk = blockIdx.x;
    int bh = blk & 31, c = blk >> 5;
    int b = bh >> 3, h = bh & 7;
    int bhc = bh * 32 + c;
    int row0 = b * 2048 + c * 64;
    int col0 = h * 128;
    int tid = threadIdx.x;
    int wv = tid >> 6, lane = tid & 63;
    int lr = lane & 15, lk8 = (lane >> 4) * 8, l4 = (lane >> 4) * 4;

    __shared__ __align__(16) unsigned short Kb[64 * 136];
    __shared__ __align__(16) unsigned short Qb[64 * 136];
    __shared__ __align__(16) unsigned short Vb[64 * 136];
    __shared__ __align__(16) unsigned short Lm[64 * 72];    // bf16, zero上 (j>=i)
    __shared__ __align__(16) unsigned short Mt[256 * 72];   // X^T [n][j], zero-init
    __shared__ __align__(16) unsigned short Yl[16 * 264];   // corr [i-in-block][n]
    __shared__ float garr[64], betl[64], Gl[64], Pl[64], decf[64];

    // ---- stage K,Q,V -> bf16 LDS; zero Lm/Mt ----
    {
        int i = tid >> 2, q4 = tid & 3;
        const float* kp = K + (size_t)(row0 + i) * DIM + col0 + q4 * 32;
        const float* qp = Q + (size_t)(row0 + i) * DIM + col0 + q4 * 32;
        const float* vp = V + (size_t)(row0 + i) * DIM + col0 + q4 * 32;
#pragma unroll
        for (int e = 0; e < 32; e += 8) {
            float4 a4, b4;
            short8 v8;
            a4 = *(const float4*)(kp + e); b4 = *(const float4*)(kp + e + 4);
            v8[0] = (short)f2bf(a4.x); v8[1] = (short)f2bf(a4.y);
            v8[2] = (short)f2bf(a4.z); v8[3] = (short)f2bf(a4.w);
            v8[4] = (short)f2bf(b4.x); v8[5] = (short)f2bf(b4.y);
            v8[6] = (short)f2bf(b4.z); v8[7] = (short)f2bf(b4.w);
            *(short8*)&Kb[i * 136 + q4 * 32 + e] = v8;
            a4 = *(const float4*)(qp + e); b4 = *(const float4*)(qp + e + 4);
            v8[0] = (short)f2bf(a4.x); v8[1] = (short)f2bf(a4.y);
            v8[2] = (short)f2bf(a4.z); v8[3] = (short)f2bf(a4.w);
            v8[4] = (short)f2bf(b4.x); v8[5] = (short)f2bf(b4.y);
            v8[6] = (short)f2bf(b4.z); v8[7] = (short)f2bf(b4.w);
            *(short8*)&Qb[i * 136 + q4 * 32 + e] = v8;
            a4 = *(const float4*)(vp + e); b4 = *(const float4*)(vp + e + 4);
            v8[0] = (short)f2bf(a4.x); v8[1] = (short)f2bf(a4.y);
            v8[2] = (short)f2bf(a4.z); v8[3] = (short)f2bf(a4.w);
            v8[4] = (short)f2bf(b4.x); v8[5] = (short)f2bf(b4.y);
            v8[6] = (short)f2bf(b4.z); v8[7] = (short)f2bf(b4.w);
            *(short8*)&Vb[i * 136 + q4 * 32 + e] = v8;
        }
        if (tid < 64) {
            garr[tid] = Glog[(size_t)(row0 + tid) * 8 + h];
            betl[tid] = Beta[(size_t)(row0 + tid) * 8 + h];
        }
        short8 z = {};
        for (int o = tid * 8; o < 64 * 72; o += 256 * 8) *(short8*)&Lm[o] = z;
        for (int o = tid * 8; o < 256 * 72; o += 256 * 8) *(short8*)&Mt[o] = z;
    }
    __syncthreads();
    // ---- decay scan (wave 0, shfl_up) ----
    if (tid < 64) {
        float g = garr[tid];
#pragma unroll
        for (int d = 1; d < 64; d <<= 1) {
            float t = __shfl_up(g, d, 64);
            if (tid >= (unsigned)d) g += t;
        }
        Gl[tid] = g;
        Pl[tid] = expf(g);
    }
    __syncthreads();
    if (tid == 0) Pcs[bhc] = Pl[63];
    if (tid < 64) decf[tid] = expf(Gl[63] - Gl[tid]);
    __syncthreads();

    // ---- L = strict-lower(beta_i e^{Gi-Gj} K K^T) via MFMA -> bf16 Lm ----
    for (int nt = 0; nt <= wv; nt++) {
        f32x4 acc = {};
#pragma unroll
        for (int kk = 0; kk < 4; kk++) {
            short8 af = *(const short8*)&Kb[(wv * 16 + lr) * 136 + kk * 32 + lk8];
            short8 bfr = *(const short8*)&Kb[(nt * 16 + lr) * 136 + kk * 32 + lk8];
            acc = __builtin_amdgcn_mfma_f32_16x16x32_bf16(af, bfr, acc, 0, 0, 0);
        }
#pragma unroll
        for (int r = 0; r < 4; r++) {
            int i = wv * 16 + l4 + r;
            int j = nt * 16 + lr;
            if (j < i) Lm[i * 72 + j] = f2bf(betl[i] * expf(Gl[i] - Gl[j]) * acc[r]);
        }
    }
    // ---- SM = lower(scale e^{Gi-Gj} Q K^T) -> global ----
    for (int nt = 0; nt < 4; nt++) {
        f32x4 acc = {};
        if (nt <= wv) {
#pragma unroll
            for (int kk = 0; kk < 4; kk++) {
                short8 af = *(const short8*)&Qb[(wv * 16 + lr) * 136 + kk * 32 + lk8];
                short8 bfr = *(const short8*)&Kb[(nt * 16 + lr) * 136 + kk * 32 + lk8];
                acc = __builtin_amdgcn_mfma_f32_16x16x32_bf16(af, bfr, acc, 0, 0, 0);
            }
        }
#pragma unroll
        for (int r = 0; r < 4; r++) {
            int i = wv * 16 + l4 + r;
            int j = nt * 16 + lr;
            float vv = (nt <= wv && j <= i) ? SCALEQ * expf(Gl[i] - Gl[j]) * acc[r] : 0.f;
            SMg[((size_t)bhc * 64 + i) * 64 + j] = f2bf(vv);
        }
    }
    // ---- Qg, KTg outputs ----
    {
        int d = tid & 127, ih = tid >> 7;
        for (int i0 = 0; i0 < 32; i0++) {
            int i = ih * 32 + i0;
            Qg[((size_t)bhc * 64 + i) * 128 + d] = f2bf(SCALEQ * Pl[i] * bf2f(Qb[i * 136 + d]));
        }
        for (int j8 = 0; j8 < 32; j8 += 8) {
            short8 v8;
#pragma unroll
            for (int e = 0; e < 8; e++) {
                int jj = ih * 32 + j8 + e;
                v8[e] = (short)f2bf(decf[jj] * bf2f(Kb[jj * 136 + d]));
            }
            *(short8*)&KTg[((size_t)bhc * 128 + d) * 64 + ih * 32 + j8] = v8;
        }
    }
    __syncthreads();  // Lm visible; Mt zeros visible

    // ---- blocked forward substitution: (I+L) X = [beta*P*K | beta*V] ----
    int n = tid;
    bool isW = n < 128;
    int cW = n & 127;
    unsigned short* Gout = isW ? Wg : Ug;
    for (int bi = 0; bi < 4; ++bi) {
        if (bi > 0) {
            int ib = bi * 16;
#pragma unroll
            for (int t4 = 0; t4 < 4; ++t4) {
                int nt = wv * 4 + t4;
                f32x4 acc = {};
#pragma unroll
                for (int ks = 0; ks < 2; ++ks) {
                    short8 af = *(const short8*)&Lm[(ib + lr) * 72 + ks * 32 + lk8];
                    short8 bfr = *(const short8*)&Mt[(nt * 16 + lr) * 72 + ks * 32 + lk8];
                    acc = __builtin_amdgcn_mfma_f32_16x16x32_bf16(af, bfr, acc, 0, 0, 0);
                }
#pragma unroll
                for (int r = 0; r < 4; ++r)
                    Yl[(l4 + r) * 264 + nt * 16 + lr] = f2bf(acc[r]);
            }
        }
        __syncthreads();  // Yl visible
        float xs[16];
#pragma unroll
        for (int ii = 0; ii < 16; ++ii) {
            int i = bi * 16 + ii;
            float a = isW ? betl[i] * Pl[i] * bf2f(Kb[i * 136 + cW])
                          : betl[i] * bf2f(Vb[i * 136 + cW]);
            if (bi > 0) a -= bf2f(Yl[ii * 264 + n]);
#pragma unroll
            for (int j = 0; j < 15; ++j)
                if (j < ii) a = fmaf(-bf2f(Lm[i * 72 + bi * 16 + j]), xs[j], a);
            xs[ii] = a;
            Mt[n * 72 + i] = f2bf(a);
        }
#pragma unroll
        for (int ii = 0; ii < 16; ++ii)
            Gout[((size_t)bhc * 64 + bi * 16 + ii) * 128 + cW] = f2bf(xs[ii]);
        __syncthreads();  // Mt visible for next block's corr MFMA
    }
}

// Phase 2 (MFMA): sequential over 32 chunks. Grid 256 = dvg*32 + bh, 256 thr (4 waves).
__global__ __launch_bounds__(256) void chunk_scan2_kernel(
    const unsigned short* __restrict__ Wg, const unsigned short* __restrict__ Ug,
    const unsigned short* __restrict__ Qg, const unsigned short* __restrict__ KTg,
    const unsigned short* __restrict__ SMg, const float* __restrict__ Pcs,
    float* __restrict__ O) {
    int blk = blockIdx.x;
    int bh = blk & 31, dvg = blk >> 5;  // same-bh blocks share blk%8 -> one XCD
    int b = bh >> 3, h = bh & 7;
    int col16 = dvg * 16;
    int tid = threadIdx.x;
    int wv = tid >> 6, lane = tid & 63;
    int lr = lane & 15, lk8 = (lane >> 4) * 8, l4 = (lane >> 4) * 4;
    int i0 = wv * 16;

    __shared__ __align__(16) unsigned short Wl[64 * 136];   // [i][d]
    __shared__ __align__(16) unsigned short Ql[64 * 136];   // [i][d]
    __shared__ __align__(16) unsigned short KTl[128 * 72];  // [d][j]
    __shared__ __align__(16) unsigned short SMl[64 * 72];   // [i][j]
    __shared__ __align__(16) unsigned short Ul[64 * 24];    // [i][c16]
    __shared__ __align__(16) unsigned short STl[16 * 136];  // S^T [c][d]
    __shared__ __align__(16) unsigned short DTl[16 * 72];   // Delta^T [c][j]

    for (int e = tid; e < 16 * 136; e += 256) STl[e] = 0;

    f32x4 Sacc[2] = {};

    for (int c = 0; c < 32; c++) {
        int bhc = bh * 32 + c;
        size_t base8k = (size_t)bhc * 8192;
        float pc = Pcs[bhc];
#pragma unroll
        for (int r = 0; r < 4; r++) {
            int v = tid + r * 256;
            *(short8*)&Wl[(v >> 4) * 136 + (v & 15) * 8] = *(const short8*)(Wg + base8k + (size_t)v * 8);
            *(short8*)&Ql[(v >> 4) * 136 + (v & 15) * 8] = *(const short8*)(Qg + base8k + (size_t)v * 8);
            *(short8*)&KTl[(v >> 3) * 72 + (v & 7) * 8] = *(const short8*)(KTg + base8k + (size_t)v * 8);
        }
#pragma unroll
        for (int r = 0; r < 2; r++) {
            int v = tid + r * 256;
            *(short8*)&SMl[(v >> 3) * 72 + (v & 7) * 8] = *(const short8*)(SMg + (size_t)bhc * 4096 + (size_t)v * 8);
        }
        if (tid < 128) {
            int row = tid >> 1, hf = tid & 1;
            *(short8*)&Ul[row * 24 + hf * 8] =
                *(const short8*)(Ug + base8k + (size_t)row * 128 + col16 + hf * 8);
        }
        __syncthreads();

        f32x4 acc0 = {}, acc1 = {};
#pragma unroll
        for (int kd = 0; kd < 4; kd++) {
            short8 bfs = *(const short8*)&STl[lr * 136 + kd * 32 + lk8];
            short8 aw = *(const short8*)&Wl[(i0 + lr) * 136 + kd * 32 + lk8];
            short8 aq = *(const short8*)&Ql[(i0 + lr) * 136 + kd * 32 + lk8];
            acc0 = __builtin_amdgcn_mfma_f32_16x16x32_bf16(aw, bfs, acc0, 0, 0, 0);
            acc1 = __builtin_amdgcn_mfma_f32_16x16x32_bf16(aq, bfs, acc1, 0, 0, 0);
        }
        ushort4 dpk;
        dpk.x = f2bf(bf2f(Ul[(i0 + l4 + 0) * 24 + lr]) - acc0[0]);
        dpk.y = f2bf(bf2f(Ul[(i0 + l4 + 1) * 24 + lr]) - acc0[1]);
        dpk.z = f2bf(bf2f(Ul[(i0 + l4 + 2) * 24 + lr]) - acc0[2]);
        dpk.w = f2bf(bf2f(Ul[(i0 + l4 + 3) * 24 + lr]) - acc0[3]);
        *(ushort4*)&DTl[lr * 72 + i0 + l4] = dpk;
        __syncthreads();

#pragma unroll
        for (int dt = 0; dt < 2; dt++)
#pragma unroll
            for (int r = 0; r < 4; r++) Sacc[dt][r] *= pc;
#pragma unroll
        for (int kj = 0; kj < 2; kj++) {
            short8 bfd = *(const short8*)&DTl[lr * 72 + kj * 32 + lk8];
            short8 as = *(const short8*)&SMl[(i0 + lr) * 72 + kj * 32 + lk8];
            acc1 = __builtin_amdgcn_mfma_f32_16x16x32_bf16(as, bfd, acc1, 0, 0, 0);
#pragma unroll
            for (int dt = 0; dt < 2; dt++) {
                short8 ak = *(const short8*)&KTl[((2 * wv + dt) * 16 + lr) * 72 + kj * 32 + lk8];
                Sacc[dt] = __builtin_amdgcn_mfma_f32_16x16x32_bf16(ak, bfd, Sacc[dt], 0, 0, 0);
            }
        }
        {
            int orow0 = b * 2048 + c * 64 + i0 + l4;
            int ocol = h * 128 + col16 + lr;
#pragma unroll
            for (int r = 0; r < 4; r++)
                O[(size_t)(orow0 + r) * DIM + ocol] = acc1[r];
        }
#pragma unroll
        for (int dt = 0; dt < 2; dt++) {
            ushort4 sp;
            sp.x = f2bf(Sacc[dt][0]);
            sp.y = f2bf(Sacc[dt][1]);
            sp.z = f2bf(Sacc[dt][2]);
            sp.w = f2bf(Sacc[dt][3]);
            *(ushort4*)&STl[lr * 136 + (2 * wv + dt) * 16 + l4] = sp;
        }
        __syncthreads();
    }
}

extern "C" void kernel_launch(void* const* d_in, const int* in_sizes, int n_in,
                              void* d_out, int out_size, void* d_ws, size_t ws_size,
                              hipStream_t stream) {
    const float* x      = (const float*)d_in[0];
    const float* Wq     = (const float*)d_in[1];
    const float* Wk     = (const float*)d_in[2];
    const float* Wv     = (const float*)d_in[3];
    const float* Wb     = (const float*)d_in[4];
    const float* Wa     = (const float*)d_in[5];
    const float* A_log  = (const float*)d_in[6];
    const float* dt_b   = (const float*)d_in[7];
    const float* Wg_in  = (const float*)d_in[8];
    const float* o_norm = (const float*)d_in[9];
    const float* Wo     = (const float*)d_in[10];
    const float* W_fc   = (const float*)d_in[11];
    const float* W_proj = (const float*)d_in[12];
    float* out = (float*)d_out;

    const size_t MAT = (size_t)ROWS * DIM;
    float* ws = (float*)d_ws;
    float* fq    = ws;                 // q f32 (normalized) -> O (chunked)
    float* fk    = ws + MAT;
    float* fv    = ws + 2 * MAT;       // v f32; later o_bf
    float* fgate = ws + 3 * MAT;
    float* fo    = ws + 4 * MAT;       // h_bf -> Wg/Ug (chunked) -> m_bf
    float* glog  = ws + 5 * MAT;
    float* beta  = glog + (size_t)ROWS * NH;
    float* alpha = beta + (size_t)ROWS * NH;
    unsigned short* wts = (unsigned short*)(alpha + (size_t)ROWS * NH);
    unsigned short* WqT = wts;          // [4096,1024] concat Wq|Wk|Wv|Wg
    unsigned short* WkT = wts + (1u << 20);
    unsigned short* WvT = wts + 2 * (1u << 20);
    unsigned short* WgT = wts + 3 * (1u << 20);
    unsigned short* WoT = wts + 4 * (1u << 20);
    unsigned short* WfcT = wts + 5 * (1u << 20);
    unsigned short* WprT = wts + 9 * (1u << 20);
    unsigned short* Qg2 = wts + 13 * (1u << 20);
    unsigned short* KTg = Qg2 + (8u << 20);
    unsigned short* SMg = KTg + (8u << 20);
    float* pcs = (float*)(SMg + (4u << 20));
    size_t need = (size_t)((char*)(pcs + 1024) - (char*)d_ws);
    bool chunked = (ws_size >= need);
    unsigned short* Wgb = (unsigned short*)fo;
    unsigned short* Ugb = Wgb + (8u << 20);

    unsigned short* h_bf = (unsigned short*)fo;
    unsigned short* m_bf = (unsigned short*)fo;
    unsigned short* o_bf = (unsigned short*)fv;
    unsigned short* fc_bf = (unsigned short*)ws;

    // 0. weight transposes -> bf16 [N,K]
    transpose_bf16_kernel<<<dim3(32, 32), 256, 0, stream>>>(Wq, WqT, 1024, 1024);
    transpose_bf16_kernel<<<dim3(32, 32), 256, 0, stream>>>(Wk, WkT, 1024, 1024);
    transpose_bf16_kernel<<<dim3(32, 32), 256, 0, stream>>>(Wv, WvT, 1024, 1024);
    transpose_bf16_kernel<<<dim3(32, 32), 256, 0, stream>>>(Wg_in, WgT, 1024, 1024);
    transpose_bf16_kernel<<<dim3(32, 32), 256, 0, stream>>>(Wo, WoT, 1024, 1024);
    transpose_bf16_kernel<<<dim3(128, 32), 256, 0, stream>>>(W_fc, WfcT, 1024, 4096);
    transpose_bf16_kernel<<<dim3(32, 128), 256, 0, stream>>>(W_proj, WprT, 4096, 1024);

    // 1. h = rms_norm(x) -> bf16
    rmsnorm_bf16_kernel<<<ROWS, 256, 0, stream>>>(x, h_bf);

    // 2. fused QKVG projection + silu + l2norm(q,k)
    mfma_gemm_qkvg<<<dim3(4096 / 128, ROWS / 128), 256, 0, stream>>>(
        h_bf, WqT, fq, fk, fv, fgate, ROWS, DIM);

    // 3. beta/glog/alpha
    smallproj_kernel<<<ROWS, 128, 0, stream>>>(h_bf, Wb, Wa, A_log, dt_b, glog, alpha, beta);

    // 4. delta-rule scan
    const float* o_src;
    dim3 g1(DIM / 128, ROWS / 128);
    if (chunked) {
        chunk_prep_kernel<<<1024, 256, 0, stream>>>(fq, fk, fv, glog, beta,
                                                    Wgb, Ugb, Qg2, KTg, SMg, pcs);
        chunk_scan2_kernel<<<256, 256, 0, stream>>>(Wgb, Ugb, Qg2, KTg, SMg, pcs, fq);
        o_src = fq;
    } else {
        scan_kernel<<<256, 128, 0, stream>>>(fq, fk, fv, alpha, beta, fo);
        o_src = fo;
    }

    // 5. gated RMSNorm -> o_bf
    gating_kernel<<<ROWS, 256, 0, stream>>>(o_src, fgate, o_norm, o_bf);

    // 6. d_out = x + o @ Wo
    mfma_gemm<2, float><<<g1, 256, 0, stream>>>(o_bf, WoT, out, x, ROWS, DIM, DIM);

    // 7. m = rms_norm(d_out) -> m_bf
    rmsnorm_bf16_kernel<<<ROWS, 256, 0, stream>>>(out, m_bf);

    // 8. fc = relu(m @ W_fc)^2 -> bf16
    dim3 g2(DFF_ / 128, ROWS / 128);
    mfma_gemm<3, unsigned short><<<g2, 256, 0, stream>>>(m_bf, WfcT, fc_bf, nullptr, ROWS, DFF_, DIM);

    // 9. d_out += fc @ W_proj
    mfma_gemm<2, float><<<g1, 256, 0, stream>>>(fc_bf, WprT, out, out, ROWS, DIM, DFF_);
}

// Round 9
// 559.369 us; speedup vs baseline: 2.8274x; 1.1562x over previous
//
#include <hip/hip_runtime.h>
#include <math.h>
#include <stdint.h>

#define ROWS 8192   // B*S
#define DIM  1024
#define NH   8
#define DFF_ 4096
#define EPSF 1e-6f
#define SCALEQ 0.08838834764831845f  // DK^-0.5

typedef __attribute__((ext_vector_type(8))) short short8;
typedef __attribute__((ext_vector_type(4))) float f32x4;

__device__ __forceinline__ float siluf(float x) {
    return x / (1.0f + expf(-x));
}
__device__ __forceinline__ unsigned short f2bf(float f) {
    uint32_t u = __float_as_uint(f);
    uint32_t r = (u + 0x7FFFu + ((u >> 16) & 1u)) >> 16;
    return (unsigned short)r;
}
__device__ __forceinline__ float bf2f(unsigned short u) {
    return __uint_as_float(((uint32_t)u) << 16);
}

// async global->LDS 16B (wave-uniform LDS base + lane*16)
__device__ __forceinline__ void async16(const void* g, void* l) {
    __builtin_amdgcn_global_load_lds(
        (const __attribute__((address_space(1))) uint32_t*)g,
        (__attribute__((address_space(3))) uint32_t*)l, 16, 0, 0);
}

// ---------------- RMSNorm -> bf16 out ----------------
__global__ void rmsnorm_bf16_kernel(const float* __restrict__ x, unsigned short* __restrict__ y) {
    int row = blockIdx.x;
    int tid = threadIdx.x;  // 256
    const float4* x4 = (const float4*)(x + (size_t)row * DIM);
    float4 v = x4[tid];
    float ss = v.x * v.x + v.y * v.y + v.z * v.z + v.w * v.w;
#pragma unroll
    for (int m = 1; m < 64; m <<= 1) ss += __shfl_xor(ss, m, 64);
    __shared__ float wss[4];
    if ((tid & 63) == 0) wss[tid >> 6] = ss;
    __syncthreads();
    float tot = wss[0] + wss[1] + wss[2] + wss[3];
    float r = rsqrtf(tot * (1.0f / 1024.0f) + EPSF);
    ushort4 o;
    o.x = f2bf(v.x * r); o.y = f2bf(v.y * r); o.z = f2bf(v.z * r); o.w = f2bf(v.w * r);
    ((ushort4*)(y + (size_t)row * DIM))[tid] = o;
}

// ---------------- fp32 -> bf16 transpose: W[K,N] -> WT[N,K] ----------------
__global__ void transpose_bf16_kernel(const float* __restrict__ W, unsigned short* __restrict__ WT,
                                      int K, int N) {
    __shared__ float tile[32][33];
    int n0 = blockIdx.x * 32, k0 = blockIdx.y * 32;
    int tx = threadIdx.x & 31, ty = threadIdx.x >> 5;
#pragma unroll
    for (int r = 0; r < 32; r += 8)
        tile[ty + r][tx] = W[(size_t)(k0 + ty + r) * N + n0 + tx];
    __syncthreads();
#pragma unroll
    for (int r = 0; r < 32; r += 8)
        WT[(size_t)(n0 + ty + r) * K + k0 + tx] = f2bf(tile[tx][ty + r]);
}

// ---------------- bf16 MFMA GEMM: C[M,N] = A[M,K] @ BT[N,K]^T ----------------
template <int EPI, typename CT>
__global__ __launch_bounds__(256) void mfma_gemm(
    const unsigned short* __restrict__ A, const unsigned short* __restrict__ BT,
    CT* __restrict__ C, const float* __restrict__ res, int M, int N, int K) {
    __shared__ __align__(16) unsigned short As[128 * 32];
    __shared__ __align__(16) unsigned short Bs[128 * 32];
    int tid = threadIdx.x;
    int w = tid >> 6, lane = tid & 63;

    int nwgx = gridDim.x;
    int nwg = nwgx * gridDim.y;
    int id = blockIdx.y * nwgx + blockIdx.x;
    int cpx = nwg >> 3;
    int nid = (id & 7) * cpx + (id >> 3);
    int bxs = nid % nwgx, bys = nid / nwgx;

    int bm = bys * 128, bn = bxs * 128;
    int wm = (w >> 1) * 64, wn = (w & 1) * 64;

    int srow = tid >> 2;
    int skb = (tid & 3) * 8;
    const unsigned short* Ag = A + (size_t)(bm + srow) * K + skb;
    const unsigned short* Bg = BT + (size_t)(bn + srow) * K + skb;

    f32x4 acc[4][4] = {};

    int lr = lane & 15;
    int lk = (lane >> 4) * 8;

    for (int kt = 0; kt < K; kt += 32) {
        async16(Ag + kt, As + w * 512);
        async16(Ag + kt + (size_t)64 * K, As + 2048 + w * 512);
        async16(Bg + kt, Bs + w * 512);
        async16(Bg + kt + (size_t)64 * K, Bs + 2048 + w * 512);
        __syncthreads();
        short8 af[4], bf[4];
#pragma unroll
        for (int i = 0; i < 4; i++) {
            af[i] = *(const short8*)&As[(wm + i * 16 + lr) * 32 + lk];
            bf[i] = *(const short8*)&Bs[(wn + i * 16 + lr) * 32 + lk];
        }
#pragma unroll
        for (int i = 0; i < 4; i++)
#pragma unroll
            for (int j = 0; j < 4; j++)
                acc[i][j] = __builtin_amdgcn_mfma_f32_16x16x32_bf16(af[i], bf[j], acc[i][j], 0, 0, 0);
        __syncthreads();
    }

#pragma unroll
    for (int i = 0; i < 4; i++) {
        int gr0 = bm + wm + i * 16 + (lane >> 4) * 4;
#pragma unroll
        for (int j = 0; j < 4; j++) {
            int gc = bn + wn + j * 16 + lr;
#pragma unroll
            for (int r = 0; r < 4; r++) {
                float v = acc[i][j][r];
                size_t idx = (size_t)(gr0 + r) * N + gc;
                if (EPI == 1) v = siluf(v);
                else if (EPI == 2) v += res[idx];
                else if (EPI == 3) { float t = fmaxf(v, 0.0f); v = t * t; }
                if constexpr (sizeof(CT) == 2) C[idx] = (CT)f2bf(v);
                else C[idx] = v;
            }
        }
    }
}

// ---------------- fused QKVG projection + silu + per-head l2norm -> bf16 ----------------
__global__ __launch_bounds__(256) void mfma_gemm_qkvg(
    const unsigned short* __restrict__ A, const unsigned short* __restrict__ BT,
    unsigned short* __restrict__ oq, unsigned short* __restrict__ ok,
    unsigned short* __restrict__ ov, unsigned short* __restrict__ og, int M, int K) {
    __shared__ __align__(16) unsigned short As[128 * 32];
    __shared__ __align__(16) unsigned short Bs[128 * 32];
    int tid = threadIdx.x;
    int w = tid >> 6, lane = tid & 63;

    int nwgx = gridDim.x;
    int nwg = nwgx * gridDim.y;
    int id = blockIdx.y * nwgx + blockIdx.x;
    int cpx = nwg >> 3;
    int nid = (id & 7) * cpx + (id >> 3);
    int bxs = nid % nwgx, bys = nid / nwgx;

    int bm = bys * 128, bn = bxs * 128;
    int wm = (w >> 1) * 64, wn = (w & 1) * 64;

    int srow = tid >> 2;
    int skb = (tid & 3) * 8;
    const unsigned short* Ag = A + (size_t)(bm + srow) * K + skb;
    const unsigned short* Bg = BT + (size_t)(bn + srow) * K + skb;

    f32x4 acc[4][4] = {};
    int lr = lane & 15;
    int lk = (lane >> 4) * 8;
    int l4 = (lane >> 4) * 4;

    for (int kt = 0; kt < K; kt += 32) {
        async16(Ag + kt, As + w * 512);
        async16(Ag + kt + (size_t)64 * K, As + 2048 + w * 512);
        async16(Bg + kt, Bs + w * 512);
        async16(Bg + kt + (size_t)64 * K, Bs + 2048 + w * 512);
        __syncthreads();
        short8 af[4], bf[4];
#pragma unroll
        for (int i = 0; i < 4; i++) {
            af[i] = *(const short8*)&As[(wm + i * 16 + lr) * 32 + lk];
            bf[i] = *(const short8*)&Bs[(wn + i * 16 + lr) * 32 + lk];
        }
#pragma unroll
        for (int i = 0; i < 4; i++)
#pragma unroll
            for (int j = 0; j < 4; j++)
                acc[i][j] = __builtin_amdgcn_mfma_f32_16x16x32_bf16(af[i], bf[j], acc[i][j], 0, 0, 0);
        __syncthreads();
    }

    int bsel = bn >> 10;
    int bnl = bn & 1023;
    if (bsel < 3) {
#pragma unroll
        for (int i = 0; i < 4; i++)
#pragma unroll
            for (int j = 0; j < 4; j++)
#pragma unroll
                for (int r = 0; r < 4; r++)
                    acc[i][j][r] = siluf(acc[i][j][r]);
    }
    float* sums = (float*)As;  // [128][2] partial row sums (As dead after main loop)
    bool donorm = (bsel < 2);
    if (donorm) {
#pragma unroll
        for (int i = 0; i < 4; i++) {
#pragma unroll
            for (int r = 0; r < 4; r++) {
                float p = acc[i][0][r] * acc[i][0][r] + acc[i][1][r] * acc[i][1][r] +
                          acc[i][2][r] * acc[i][2][r] + acc[i][3][r] * acc[i][3][r];
                p += __shfl_xor(p, 1, 16);
                p += __shfl_xor(p, 2, 16);
                p += __shfl_xor(p, 4, 16);
                p += __shfl_xor(p, 8, 16);
                if (lr == 0) sums[(wm + i * 16 + l4 + r) * 2 + (wn >> 6)] = p;
            }
        }
        __syncthreads();
    }
    unsigned short* C = (bsel == 0) ? oq : (bsel == 1) ? ok : (bsel == 2) ? ov : og;
#pragma unroll
    for (int i = 0; i < 4; i++) {
#pragma unroll
        for (int r = 0; r < 4; r++) {
            int lrow = wm + i * 16 + l4 + r;
            float rn = 1.0f;
            if (donorm) rn = rsqrtf(sums[lrow * 2] + sums[lrow * 2 + 1] + EPSF);
            size_t gr = (size_t)(bm + lrow) * 1024;
#pragma unroll
            for (int j = 0; j < 4; j++) {
                int gc = bnl + wn + j * 16 + lr;
                C[gr + gc] = f2bf(acc[i][j][r] * rn);
            }
        }
    }
}

// ---------------- gated RMSNorm -> bf16 (gate is bf16) ----------------
__global__ void gating_kernel(const float* __restrict__ o, const unsigned short* __restrict__ gate,
                              const float* __restrict__ w, unsigned short* __restrict__ ob) {
    int row = blockIdx.x;
    int tid = threadIdx.x;
    const float4* op = (const float4*)(o + (size_t)row * DIM);
    float4 v = op[tid];
    float ss = v.x * v.x + v.y * v.y + v.z * v.z + v.w * v.w;
#pragma unroll
    for (int m = 1; m < 32; m <<= 1) ss += __shfl_xor(ss, m, 32);
    float r = rsqrtf(ss * (1.0f / 128.0f) + EPSF);
    ushort4 gu = ((const ushort4*)(gate + (size_t)row * DIM))[tid];
    float4 wv = ((const float4*)w)[tid & 31];
    ushort4 out;
    out.x = f2bf(v.x * r * wv.x * siluf(bf2f(gu.x)));
    out.y = f2bf(v.y * r * wv.y * siluf(bf2f(gu.y)));
    out.z = f2bf(v.z * r * wv.z * siluf(bf2f(gu.z)));
    out.w = f2bf(v.w * r * wv.w * siluf(bf2f(gu.w)));
    ((ushort4*)(ob + (size_t)row * DIM))[tid] = out;
}

// ---------------- small projections: beta, glog ----------------
__global__ void smallproj_kernel(const unsigned short* __restrict__ hbuf,
                                 const float* __restrict__ Wb, const float* __restrict__ Wa,
                                 const float* __restrict__ A_log, const float* __restrict__ dt_bias,
                                 float* __restrict__ Glog, float* __restrict__ Beta) {
    int row = blockIdx.x;
    int tid = threadIdx.x;  // 128
    __shared__ __align__(16) float hrow[1024];
    __shared__ float part[128];
    const ushort4* h4 = (const ushort4*)(hbuf + (size_t)row * DIM);
    ushort4 u0 = h4[tid * 2], u1 = h4[tid * 2 + 1];
    hrow[tid * 8 + 0] = bf2f(u0.x); hrow[tid * 8 + 1] = bf2f(u0.y);
    hrow[tid * 8 + 2] = bf2f(u0.z); hrow[tid * 8 + 3] = bf2f(u0.w);
    hrow[tid * 8 + 4] = bf2f(u1.x); hrow[tid * 8 + 5] = bf2f(u1.y);
    hrow[tid * 8 + 6] = bf2f(u1.z); hrow[tid * 8 + 7] = bf2f(u1.w);
    __syncthreads();
    int out = tid & 15, slice = tid >> 4;
    const float* W = (out < 8) ? Wb : Wa;
    int col = out & 7;
    int k0 = slice * 128;
    float p = 0.0f;
    for (int kk = 0; kk < 128; kk++) p += hrow[k0 + kk] * W[(size_t)(k0 + kk) * 8 + col];
    part[tid] = p;
    __syncthreads();
    if (tid < 16) {
        float sum = 0.0f;
#pragma unroll
        for (int sl = 0; sl < 8; sl++) sum += part[sl * 16 + tid];
        if (tid < 8) {
            Beta[(size_t)row * 8 + tid] = 1.0f / (1.0f + expf(-sum));
        } else {
            int hh = tid - 8;
            float xg = sum + dt_bias[hh];
            float sp = fmaxf(xg, 0.0f) + log1pf(expf(-fabsf(xg)));
            Glog[(size_t)row * 8 + hh] = -expf(A_log[hh]) * sp;
        }
    }
}

// ================= chunked gated delta rule =================
// Phase 1 v3: bf16 inputs, 76KB LDS (2 blocks/CU), swizzled Mt, vectorized writes.
#define PRE_KB 0          // [64][136] bf16   17408 B
#define PRE_QB 17408      // [64][136] bf16   17408 B (aliased by Yl after use)
#define PRE_YL 17408      // [16][264] bf16    8448 B
#define PRE_LM 34816      // [64][72]  bf16    9216 B
#define PRE_MT 44032      // [256][64] bf16 (swizzled 16B chunks) 32768 B
#define PRE_FL 76800      // betl,Gl,Pl,decf   1024 B
#define PRE_SZ 77824

__global__ __launch_bounds__(256) void chunk_prep_kernel(
    const unsigned short* __restrict__ Q16, const unsigned short* __restrict__ K16,
    const unsigned short* __restrict__ V16, const float* __restrict__ Glog,
    const float* __restrict__ Beta,
    unsigned short* __restrict__ Wg, unsigned short* __restrict__ Ug,
    unsigned short* __restrict__ Qg, unsigned short* __restrict__ KTg,
    unsigned short* __restrict__ SMg, float* __restrict__ Pcs) {
    __shared__ __align__(16) unsigned char smem[PRE_SZ];
    unsigned short* Kb = (unsigned short*)(smem + PRE_KB);
    unsigned short* Qb = (unsigned short*)(smem + PRE_QB);
    unsigned short* Yl = (unsigned short*)(smem + PRE_YL);
    unsigned short* Lm = (unsigned short*)(smem + PRE_LM);
    float* betl = (float*)(smem + PRE_FL);
    float* Gl = betl + 64;
    float* Pl = Gl + 64;
    float* decf = Pl + 64;

    int blk = blockIdx.x;
    int bh = blk & 31, c = blk >> 5;
    int b = bh >> 3, h = bh & 7;
    int bhc = bh * 32 + c;
    int row0 = b * 2048 + c * 64;
    int col0 = h * 128;
    int tid = threadIdx.x;
    int wv = tid >> 6, lane = tid & 63;
    int lr = lane & 15, lk8 = (lane >> 4) * 8, l4 = (lane >> 4) * 4;

    // ---- stage K,Q (bf16, no cvt); zero Lm, Mt ----
#pragma unroll
    for (int r = 0; r < 4; ++r) {
        int cc = tid + r * 256;                 // 0..1023
        int i = cc >> 4, jc = (cc & 15) * 8;
        *(short8*)&Kb[i * 136 + jc] = *(const short8*)(K16 + (size_t)(row0 + i) * DIM + col0 + jc);
        *(short8*)&Qb[i * 136 + jc] = *(const short8*)(Q16 + (size_t)(row0 + i) * DIM + col0 + jc);
    }
    {
        short8 z = {};
        for (int o = tid; o < 576; o += 256) ((short8*)Lm)[o] = z;          // 9216 B
        for (int o = tid; o < 2048; o += 256) ((short8*)(smem + PRE_MT))[o] = z;  // 32768 B
    }
    if (tid < 64) {
        float g = Glog[(size_t)(row0 + tid) * 8 + h];
        betl[tid] = Beta[(size_t)(row0 + tid) * 8 + h];
#pragma unroll
        for (int d = 1; d < 64; d <<= 1) {
            float t = __shfl_up(g, d, 64);
            if (tid >= d) g += t;
        }
        Gl[tid] = g;
        Pl[tid] = expf(g);
        float g63 = __shfl(g, 63, 64);
        decf[tid] = expf(g63 - g);
        if (tid == 63) Pcs[bhc] = expf(g);
    }
    __syncthreads();

    // ---- L = strict-lower(beta_i e^{Gi-Gj} K K^T) via MFMA -> bf16 Lm ----
    for (int nt = 0; nt <= wv; nt++) {
        f32x4 acc = {};
#pragma unroll
        for (int kk = 0; kk < 4; kk++) {
            short8 af = *(const short8*)&Kb[(wv * 16 + lr) * 136 + kk * 32 + lk8];
            short8 bfr = *(const short8*)&Kb[(nt * 16 + lr) * 136 + kk * 32 + lk8];
            acc = __builtin_amdgcn_mfma_f32_16x16x32_bf16(af, bfr, acc, 0, 0, 0);
        }
#pragma unroll
        for (int r = 0; r < 4; r++) {
            int i = wv * 16 + l4 + r;
            int j = nt * 16 + lr;
            if (j < i) Lm[i * 72 + j] = f2bf(betl[i] * expf(Gl[i] - Gl[j]) * acc[r]);
        }
    }
    // ---- SM = lower(scale e^{Gi-Gj} Q K^T) -> global ----
    for (int nt = 0; nt < 4; nt++) {
        f32x4 acc = {};
        if (nt <= wv) {
#pragma unroll
            for (int kk = 0; kk < 4; kk++) {
                short8 af = *(const short8*)&Qb[(wv * 16 + lr) * 136 + kk * 32 + lk8];
                short8 bfr = *(const short8*)&Kb[(nt * 16 + lr) * 136 + kk * 32 + lk8];
                acc = __builtin_amdgcn_mfma_f32_16x16x32_bf16(af, bfr, acc, 0, 0, 0);
            }
        }
#pragma unroll
        for (int r = 0; r < 4; r++) {
            int i = wv * 16 + l4 + r;
            int j = nt * 16 + lr;
            float vv = (nt <= wv && j <= i) ? SCALEQ * expf(Gl[i] - Gl[j]) * acc[r] : 0.f;
            SMg[((size_t)bhc * 64 + i) * 64 + j] = f2bf(vv);
        }
    }
    // ---- Qg, KTg outputs (column reads, coalesced writes) ----
    {
        int d = tid & 127, ih = tid >> 7;
        for (int i0 = 0; i0 < 32; i0++) {
            int i = ih * 32 + i0;
            Qg[((size_t)bhc * 64 + i) * 128 + d] = f2bf(SCALEQ * Pl[i] * bf2f(Qb[i * 136 + d]));
        }
        for (int j8 = 0; j8 < 32; j8 += 8) {
            short8 v8;
#pragma unroll
            for (int e = 0; e < 8; e++) {
                int jj = ih * 32 + j8 + e;
                v8[e] = (short)f2bf(decf[jj] * bf2f(Kb[jj * 136 + d]));  // FIXED index
            }
            *(short8*)&KTg[((size_t)bhc * 128 + d) * 64 + ih * 32 + j8] = v8;
        }
    }
    __syncthreads();  // Lm visible; Qb reads done (Yl may alias)

    // ---- blocked forward substitution: (I+L) X = [beta*P*K | beta*V] ----
    int n = tid;
    bool isW = n < 128;
    int cW = n & 127;
    unsigned short* Gout = isW ? Wg : Ug;
    const unsigned short* Vcol = V16 + (size_t)row0 * DIM + col0 + cW;
    for (int bi = 0; bi < 4; ++bi) {
        if (bi > 0) {
            int ib = bi * 16;
#pragma unroll
            for (int t4 = 0; t4 < 4; ++t4) {
                int nt = wv * 4 + t4;
                f32x4 acc = {};
#pragma unroll
                for (int ks = 0; ks < 2; ++ks) {
                    short8 af = *(const short8*)&Lm[(ib + lr) * 72 + ks * 32 + lk8];
                    int nr = nt * 16 + lr;
                    int cj = ks * 4 + (lk8 >> 3);
                    short8 bfr = *(const short8*)(smem + PRE_MT + nr * 128 + (((cj ^ (nr & 7)) & 7) << 4));
                    acc = __builtin_amdgcn_mfma_f32_16x16x32_bf16(af, bfr, acc, 0, 0, 0);
                }
#pragma unroll
                for (int r = 0; r < 4; ++r)
                    Yl[(l4 + r) * 264 + nt * 16 + lr] = f2bf(acc[r]);
            }
        }
        __syncthreads();  // Yl visible (bi=0: Mt zeros + staging settled)
        float xs[16];
#pragma unroll
        for (int ii = 0; ii < 16; ++ii) {
            int i = bi * 16 + ii;
            float a = isW ? betl[i] * Pl[i] * bf2f(Kb[i * 136 + cW])
                          : betl[i] * bf2f(Vcol[(size_t)i * DIM]);
            if (bi > 0) a -= bf2f(Yl[ii * 264 + n]);
#pragma unroll
            for (int j = 0; j < 15; ++j)
                if (j < ii) a = fmaf(-bf2f(Lm[i * 72 + bi * 16 + j]), xs[j], a);
            xs[ii] = a;
        }
        // vectorized swizzled Mt row write (chunks bi*2, bi*2+1)
        {
            short8 m0, m1;
#pragma unroll
            for (int e = 0; e < 8; ++e) { m0[e] = (short)f2bf(xs[e]); m1[e] = (short)f2bf(xs[8 + e]); }
            int cj0 = bi * 2, cj1 = bi * 2 + 1;
            *(short8*)(smem + PRE_MT + n * 128 + (((cj0 ^ (n & 7)) & 7) << 4)) = m0;
            *(short8*)(smem + PRE_MT + n * 128 + (((cj1 ^ (n & 7)) & 7) << 4)) = m1;
        }
#pragma unroll
        for (int ii = 0; ii < 16; ++ii)
            Gout[((size_t)bhc * 64 + bi * 16 + ii) * 128 + cW] = f2bf(xs[ii]);
        __syncthreads();  // Mt visible for next bi corr
    }
}

// Phase 2 (MFMA): sequential over 32 chunks. Grid 256 = dvg*32 + bh, 256 thr (4 waves).
__global__ __launch_bounds__(256) void chunk_scan2_kernel(
    const unsigned short* __restrict__ Wg, const unsigned short* __restrict__ Ug,
    const unsigned short* __restrict__ Qg, const unsigned short* __restrict__ KTg,
    const unsigned short* __restrict__ SMg, const float* __restrict__ Pcs,
    float* __restrict__ O) {
    int blk = blockIdx.x;
    int bh = blk & 31, dvg = blk >> 5;  // same-bh blocks share blk%8 -> one XCD
    int b = bh >> 3, h = bh & 7;
    int col16 = dvg * 16;
    int tid = threadIdx.x;
    int wv = tid >> 6, lane = tid & 63;
    int lr = lane & 15, lk8 = (lane >> 4) * 8, l4 = (lane >> 4) * 4;
    int i0 = wv * 16;

    __shared__ __align__(16) unsigned short Wl[64 * 136];   // [i][d]
    __shared__ __align__(16) unsigned short Ql[64 * 136];   // [i][d]
    __shared__ __align__(16) unsigned short KTl[128 * 72];  // [d][j]
    __shared__ __align__(16) unsigned short SMl[64 * 72];   // [i][j]
    __shared__ __align__(16) unsigned short Ul[64 * 24];    // [i][c16]
    __shared__ __align__(16) unsigned short STl[16 * 136];  // S^T [c][d]
    __shared__ __align__(16) unsigned short DTl[16 * 72];   // Delta^T [c][j]

    for (int e = tid; e < 16 * 136; e += 256) STl[e] = 0;

    f32x4 Sacc[2] = {};

    for (int c = 0; c < 32; c++) {
        int bhc = bh * 32 + c;
        size_t base8k = (size_t)bhc * 8192;
        float pc = Pcs[bhc];
#pragma unroll
        for (int r = 0; r < 4; r++) {
            int v = tid + r * 256;
            *(short8*)&Wl[(v >> 4) * 136 + (v & 15) * 8] = *(const short8*)(Wg + base8k + (size_t)v * 8);
            *(short8*)&Ql[(v >> 4) * 136 + (v & 15) * 8] = *(const short8*)(Qg + base8k + (size_t)v * 8);
            *(short8*)&KTl[(v >> 3) * 72 + (v & 7) * 8] = *(const short8*)(KTg + base8k + (size_t)v * 8);
        }
#pragma unroll
        for (int r = 0; r < 2; r++) {
            int v = tid + r * 256;
            *(short8*)&SMl[(v >> 3) * 72 + (v & 7) * 8] = *(const short8*)(SMg + (size_t)bhc * 4096 + (size_t)v * 8);
        }
        if (tid < 128) {
            int row = tid >> 1, hf = tid & 1;
            *(short8*)&Ul[row * 24 + hf * 8] =
                *(const short8*)(Ug + base8k + (size_t)row * 128 + col16 + hf * 8);
        }
        __syncthreads();

        f32x4 acc0 = {}, acc1 = {};
#pragma unroll
        for (int kd = 0; kd < 4; kd++) {
            short8 bfs = *(const short8*)&STl[lr * 136 + kd * 32 + lk8];
            short8 aw = *(const short8*)&Wl[(i0 + lr) * 136 + kd * 32 + lk8];
            short8 aq = *(const short8*)&Ql[(i0 + lr) * 136 + kd * 32 + lk8];
            acc0 = __builtin_amdgcn_mfma_f32_16x16x32_bf16(aw, bfs, acc0, 0, 0, 0);
            acc1 = __builtin_amdgcn_mfma_f32_16x16x32_bf16(aq, bfs, acc1, 0, 0, 0);
        }
        ushort4 dpk;
        dpk.x = f2bf(bf2f(Ul[(i0 + l4 + 0) * 24 + lr]) - acc0[0]);
        dpk.y = f2bf(bf2f(Ul[(i0 + l4 + 1) * 24 + lr]) - acc0[1]);
        dpk.z = f2bf(bf2f(Ul[(i0 + l4 + 2) * 24 + lr]) - acc0[2]);
        dpk.w = f2bf(bf2f(Ul[(i0 + l4 + 3) * 24 + lr]) - acc0[3]);
        *(ushort4*)&DTl[lr * 72 + i0 + l4] = dpk;
        __syncthreads();

#pragma unroll
        for (int dt = 0; dt < 2; dt++)
#pragma unroll
            for (int r = 0; r < 4; r++) Sacc[dt][r] *= pc;
#pragma unroll
        for (int kj = 0; kj < 2; kj++) {
            short8 bfd = *(const short8*)&DTl[lr * 72 + kj * 32 + lk8];
            short8 as = *(const short8*)&SMl[(i0 + lr) * 72 + kj * 32 + lk8];
            acc1 = __builtin_amdgcn_mfma_f32_16x16x32_bf16(as, bfd, acc1, 0, 0, 0);
#pragma unroll
            for (int dt = 0; dt < 2; dt++) {
                short8 ak = *(const short8*)&KTl[((2 * wv + dt) * 16 + lr) * 72 + kj * 32 + lk8];
                Sacc[dt] = __builtin_amdgcn_mfma_f32_16x16x32_bf16(ak, bfd, Sacc[dt], 0, 0, 0);
            }
        }
        {
            int orow0 = b * 2048 + c * 64 + i0 + l4;
            int ocol = h * 128 + col16 + lr;
#pragma unroll
            for (int r = 0; r < 4; r++)
                O[(size_t)(orow0 + r) * DIM + ocol] = acc1[r];
        }
#pragma unroll
        for (int dt = 0; dt < 2; dt++) {
            ushort4 sp;
            sp.x = f2bf(Sacc[dt][0]);
            sp.y = f2bf(Sacc[dt][1]);
            sp.z = f2bf(Sacc[dt][2]);
            sp.w = f2bf(Sacc[dt][3]);
            *(ushort4*)&STl[lr * 136 + (2 * wv + dt) * 16 + l4] = sp;
        }
        __syncthreads();
    }
}

extern "C" void kernel_launch(void* const* d_in, const int* in_sizes, int n_in,
                              void* d_out, int out_size, void* d_ws, size_t ws_size,
                              hipStream_t stream) {
    const float* x      = (const float*)d_in[0];
    const float* Wq     = (const float*)d_in[1];
    const float* Wk     = (const float*)d_in[2];
    const float* Wv     = (const float*)d_in[3];
    const float* Wb     = (const float*)d_in[4];
    const float* Wa     = (const float*)d_in[5];
    const float* A_log  = (const float*)d_in[6];
    const float* dt_b   = (const float*)d_in[7];
    const float* Wg_in  = (const float*)d_in[8];
    const float* o_norm = (const float*)d_in[9];
    const float* Wo     = (const float*)d_in[10];
    const float* W_fc   = (const float*)d_in[11];
    const float* W_proj = (const float*)d_in[12];
    float* out = (float*)d_out;

    const size_t MATE = (size_t)ROWS * DIM;  // 8M elems
    unsigned short* qb16 = (unsigned short*)d_ws;
    unsigned short* kb16 = qb16 + MATE;
    unsigned short* vb16 = kb16 + MATE;
    unsigned short* gt16 = vb16 + MATE;
    float* o_f = (float*)(gt16 + MATE);
    unsigned short* h_bf = (unsigned short*)(o_f + MATE);
    float* glog = (float*)(h_bf + MATE);
    float* beta = glog + (size_t)ROWS * NH;
    unsigned short* wts = (unsigned short*)(beta + (size_t)ROWS * NH);
    unsigned short* WqT = wts;                     // [4096,1024] concat Wq|Wk|Wv|Wg
    unsigned short* WkT = wts + (1u << 20);
    unsigned short* WvT = wts + 2 * (1u << 20);
    unsigned short* WgT = wts + 3 * (1u << 20);
    unsigned short* WoT = wts + 4 * (1u << 20);
    unsigned short* WfcT = wts + 5 * (1u << 20);
    unsigned short* WprT = wts + 9 * (1u << 20);
    unsigned short* Wgb = wts + 13 * (1u << 20);
    unsigned short* Ugb = Wgb + (8u << 20);
    unsigned short* Qg2 = Ugb + (8u << 20);
    unsigned short* KTg = Qg2 + (8u << 20);
    unsigned short* SMg = KTg + (8u << 20);
    float* pcs = (float*)(SMg + (4u << 20));
    unsigned short* m_bf = h_bf;                   // alias (h dead after smallproj)
    unsigned short* o_bf = vb16;                   // alias (v dead after prep)
    unsigned short* fc_bf = qb16;                  // alias (q..gate dead by step 8)

    // 0. weight transposes -> bf16 [N,K]
    transpose_bf16_kernel<<<dim3(32, 32), 256, 0, stream>>>(Wq, WqT, 1024, 1024);
    transpose_bf16_kernel<<<dim3(32, 32), 256, 0, stream>>>(Wk, WkT, 1024, 1024);
    transpose_bf16_kernel<<<dim3(32, 32), 256, 0, stream>>>(Wv, WvT, 1024, 1024);
    transpose_bf16_kernel<<<dim3(32, 32), 256, 0, stream>>>(Wg_in, WgT, 1024, 1024);
    transpose_bf16_kernel<<<dim3(32, 32), 256, 0, stream>>>(Wo, WoT, 1024, 1024);
    transpose_bf16_kernel<<<dim3(128, 32), 256, 0, stream>>>(W_fc, WfcT, 1024, 4096);
    transpose_bf16_kernel<<<dim3(32, 128), 256, 0, stream>>>(W_proj, WprT, 4096, 1024);

    // 1. h = rms_norm(x) -> bf16
    rmsnorm_bf16_kernel<<<ROWS, 256, 0, stream>>>(x, h_bf);

    // 2. fused QKVG projection + silu + l2norm -> bf16
    mfma_gemm_qkvg<<<dim3(4096 / 128, ROWS / 128), 256, 0, stream>>>(
        h_bf, WqT, qb16, kb16, vb16, gt16, ROWS, DIM);

    // 3. beta/glog
    smallproj_kernel<<<ROWS, 128, 0, stream>>>(h_bf, Wb, Wa, A_log, dt_b, glog, beta);

    // 4. chunked delta rule
    chunk_prep_kernel<<<1024, 256, 0, stream>>>(qb16, kb16, vb16, glog, beta,
                                                Wgb, Ugb, Qg2, KTg, SMg, pcs);
    chunk_scan2_kernel<<<256, 256, 0, stream>>>(Wgb, Ugb, Qg2, KTg, SMg, pcs, o_f);

    // 5. gated RMSNorm -> o_bf
    gating_kernel<<<ROWS, 256, 0, stream>>>(o_f, gt16, o_norm, o_bf);

    // 6. d_out = x + o @ Wo
    dim3 g1(DIM / 128, ROWS / 128);
    mfma_gemm<2, float><<<g1, 256, 0, stream>>>(o_bf, WoT, out, x, ROWS, DIM, DIM);

    // 7. m = rms_norm(d_out) -> m_bf
    rmsnorm_bf16_kernel<<<ROWS, 256, 0, stream>>>(out, m_bf);

    // 8. fc = relu(m @ W_fc)^2 -> bf16
    dim3 g2(DFF_ / 128, ROWS / 128);
    mfma_gemm<3, unsigned short><<<g2, 256, 0, stream>>>(m_bf, WfcT, fc_bf, nullptr, ROWS, DFF_, DIM);

    // 9. d_out += fc @ W_proj
    mfma_gemm<2, float><<<g1, 256, 0, stream>>>(fc_bf, WprT, out, out, ROWS, DIM, DFF_);
}

// Round 10
// 548.117 us; speedup vs baseline: 2.8855x; 1.0205x over previous
//
#include <hip/hip_runtime.h>
#include <math.h>
#include <stdint.h>

#define ROWS 8192   // B*S
#define DIM  1024
#define NH   8
#define DFF_ 4096
#define EPSF 1e-6f
#define SCALEQ 0.08838834764831845f  // DK^-0.5

typedef __attribute__((ext_vector_type(8))) short short8;
typedef __attribute__((ext_vector_type(4))) float f32x4;

__device__ __forceinline__ float siluf(float x) {
    return x / (1.0f + expf(-x));
}
__device__ __forceinline__ unsigned short f2bf(float f) {
    uint32_t u = __float_as_uint(f);
    uint32_t r = (u + 0x7FFFu + ((u >> 16) & 1u)) >> 16;
    return (unsigned short)r;
}
__device__ __forceinline__ float bf2f(unsigned short u) {
    return __uint_as_float(((uint32_t)u) << 16);
}

// async global->LDS 16B (wave-uniform LDS base + lane*16)
__device__ __forceinline__ void async16(const void* g, void* l) {
    __builtin_amdgcn_global_load_lds(
        (const __attribute__((address_space(1))) uint32_t*)g,
        (__attribute__((address_space(3))) uint32_t*)l, 16, 0, 0);
}

// ---------------- RMSNorm -> bf16 out ----------------
__global__ void rmsnorm_bf16_kernel(const float* __restrict__ x, unsigned short* __restrict__ y) {
    int row = blockIdx.x;
    int tid = threadIdx.x;  // 256
    const float4* x4 = (const float4*)(x + (size_t)row * DIM);
    float4 v = x4[tid];
    float ss = v.x * v.x + v.y * v.y + v.z * v.z + v.w * v.w;
#pragma unroll
    for (int m = 1; m < 64; m <<= 1) ss += __shfl_xor(ss, m, 64);
    __shared__ float wss[4];
    if ((tid & 63) == 0) wss[tid >> 6] = ss;
    __syncthreads();
    float tot = wss[0] + wss[1] + wss[2] + wss[3];
    float r = rsqrtf(tot * (1.0f / 1024.0f) + EPSF);
    ushort4 o;
    o.x = f2bf(v.x * r); o.y = f2bf(v.y * r); o.z = f2bf(v.z * r); o.w = f2bf(v.w * r);
    ((ushort4*)(y + (size_t)row * DIM))[tid] = o;
}

// ---------------- fp32 -> bf16 transpose: W[K,N] -> WT[N,K] ----------------
__global__ void transpose_bf16_kernel(const float* __restrict__ W, unsigned short* __restrict__ WT,
                                      int K, int N) {
    __shared__ float tile[32][33];
    int n0 = blockIdx.x * 32, k0 = blockIdx.y * 32;
    int tx = threadIdx.x & 31, ty = threadIdx.x >> 5;
#pragma unroll
    for (int r = 0; r < 32; r += 8)
        tile[ty + r][tx] = W[(size_t)(k0 + ty + r) * N + n0 + tx];
    __syncthreads();
#pragma unroll
    for (int r = 0; r < 32; r += 8)
        WT[(size_t)(n0 + ty + r) * K + k0 + tx] = f2bf(tile[tx][ty + r]);
}

// ---------------- bf16 MFMA GEMM: C[M,N] = A[M,K] @ BT[N,K]^T ----------------
// LDS tiles XOR-swizzled (T2, both-sides): global source chunk gchunk = (tid&3)^((tid>>3)&3)
// lands logical chunk c of row r at slot c^((r>>1)&3); read slot = (lane>>4)^((lr>>1)&3)
// (constant per thread since fragment rows == 0 mod 16). 8-lane b128 group -> 32 distinct banks.
template <int EPI, typename CT>
__global__ __launch_bounds__(256) void mfma_gemm(
    const unsigned short* __restrict__ A, const unsigned short* __restrict__ BT,
    CT* __restrict__ C, const float* __restrict__ res, int M, int N, int K) {
    __shared__ __align__(16) unsigned short As[128 * 32];
    __shared__ __align__(16) unsigned short Bs[128 * 32];
    int tid = threadIdx.x;
    int w = tid >> 6, lane = tid & 63;

    int nwgx = gridDim.x;
    int nwg = nwgx * gridDim.y;
    int id = blockIdx.y * nwgx + blockIdx.x;
    int cpx = nwg >> 3;
    int nid = (id & 7) * cpx + (id >> 3);
    int bxs = nid % nwgx, bys = nid / nwgx;

    int bm = bys * 128, bn = bxs * 128;
    int wm = (w >> 1) * 64, wn = (w & 1) * 64;

    int srow = tid >> 2;
    int skb = ((tid & 3) ^ ((tid >> 3) & 3)) * 8;   // swizzled global 16B-chunk
    const unsigned short* Ag = A + (size_t)(bm + srow) * K + skb;
    const unsigned short* Bg = BT + (size_t)(bn + srow) * K + skb;

    f32x4 acc[4][4] = {};

    int lr = lane & 15;
    int lk = (((lane >> 4) ^ ((lr >> 1) & 3))) * 8; // swizzled read slot

    for (int kt = 0; kt < K; kt += 32) {
        async16(Ag + kt, As + w * 512);
        async16(Ag + kt + (size_t)64 * K, As + 2048 + w * 512);
        async16(Bg + kt, Bs + w * 512);
        async16(Bg + kt + (size_t)64 * K, Bs + 2048 + w * 512);
        __syncthreads();
        short8 af[4], bf[4];
#pragma unroll
        for (int i = 0; i < 4; i++) {
            af[i] = *(const short8*)&As[(wm + i * 16 + lr) * 32 + lk];
            bf[i] = *(const short8*)&Bs[(wn + i * 16 + lr) * 32 + lk];
        }
#pragma unroll
        for (int i = 0; i < 4; i++)
#pragma unroll
            for (int j = 0; j < 4; j++)
                acc[i][j] = __builtin_amdgcn_mfma_f32_16x16x32_bf16(af[i], bf[j], acc[i][j], 0, 0, 0);
        __syncthreads();
    }

#pragma unroll
    for (int i = 0; i < 4; i++) {
        int gr0 = bm + wm + i * 16 + (lane >> 4) * 4;
#pragma unroll
        for (int j = 0; j < 4; j++) {
            int gc = bn + wn + j * 16 + lr;
#pragma unroll
            for (int r = 0; r < 4; r++) {
                float v = acc[i][j][r];
                size_t idx = (size_t)(gr0 + r) * N + gc;
                if (EPI == 1) v = siluf(v);
                else if (EPI == 2) v += res[idx];
                else if (EPI == 3) { float t = fmaxf(v, 0.0f); v = t * t; }
                if constexpr (sizeof(CT) == 2) C[idx] = (CT)f2bf(v);
                else C[idx] = v;
            }
        }
    }
}

// ---------------- fused QKVG projection + silu + per-head l2norm -> bf16 ----------------
__global__ __launch_bounds__(256) void mfma_gemm_qkvg(
    const unsigned short* __restrict__ A, const unsigned short* __restrict__ BT,
    unsigned short* __restrict__ oq, unsigned short* __restrict__ ok,
    unsigned short* __restrict__ ov, unsigned short* __restrict__ og, int M, int K) {
    __shared__ __align__(16) unsigned short As[128 * 32];
    __shared__ __align__(16) unsigned short Bs[128 * 32];
    int tid = threadIdx.x;
    int w = tid >> 6, lane = tid & 63;

    int nwgx = gridDim.x;
    int nwg = nwgx * gridDim.y;
    int id = blockIdx.y * nwgx + blockIdx.x;
    int cpx = nwg >> 3;
    int nid = (id & 7) * cpx + (id >> 3);
    int bxs = nid % nwgx, bys = nid / nwgx;

    int bm = bys * 128, bn = bxs * 128;
    int wm = (w >> 1) * 64, wn = (w & 1) * 64;

    int srow = tid >> 2;
    int skb = ((tid & 3) ^ ((tid >> 3) & 3)) * 8;   // swizzled global 16B-chunk
    const unsigned short* Ag = A + (size_t)(bm + srow) * K + skb;
    const unsigned short* Bg = BT + (size_t)(bn + srow) * K + skb;

    f32x4 acc[4][4] = {};
    int lr = lane & 15;
    int lk = (((lane >> 4) ^ ((lr >> 1) & 3))) * 8; // swizzled read slot
    int l4 = (lane >> 4) * 4;

    for (int kt = 0; kt < K; kt += 32) {
        async16(Ag + kt, As + w * 512);
        async16(Ag + kt + (size_t)64 * K, As + 2048 + w * 512);
        async16(Bg + kt, Bs + w * 512);
        async16(Bg + kt + (size_t)64 * K, Bs + 2048 + w * 512);
        __syncthreads();
        short8 af[4], bf[4];
#pragma unroll
        for (int i = 0; i < 4; i++) {
            af[i] = *(const short8*)&As[(wm + i * 16 + lr) * 32 + lk];
            bf[i] = *(const short8*)&Bs[(wn + i * 16 + lr) * 32 + lk];
        }
#pragma unroll
        for (int i = 0; i < 4; i++)
#pragma unroll
            for (int j = 0; j < 4; j++)
                acc[i][j] = __builtin_amdgcn_mfma_f32_16x16x32_bf16(af[i], bf[j], acc[i][j], 0, 0, 0);
        __syncthreads();
    }

    int bsel = bn >> 10;
    int bnl = bn & 1023;
    if (bsel < 3) {
#pragma unroll
        for (int i = 0; i < 4; i++)
#pragma unroll
            for (int j = 0; j < 4; j++)
#pragma unroll
                for (int r = 0; r < 4; r++)
                    acc[i][j][r] = siluf(acc[i][j][r]);
    }
    float* sums = (float*)As;  // [128][2] partial row sums (As dead after main loop)
    bool donorm = (bsel < 2);
    if (donorm) {
#pragma unroll
        for (int i = 0; i < 4; i++) {
#pragma unroll
            for (int r = 0; r < 4; r++) {
                float p = acc[i][0][r] * acc[i][0][r] + acc[i][1][r] * acc[i][1][r] +
                          acc[i][2][r] * acc[i][2][r] + acc[i][3][r] * acc[i][3][r];
                p += __shfl_xor(p, 1, 16);
                p += __shfl_xor(p, 2, 16);
                p += __shfl_xor(p, 4, 16);
                p += __shfl_xor(p, 8, 16);
                if (lr == 0) sums[(wm + i * 16 + l4 + r) * 2 + (wn >> 6)] = p;
            }
        }
        __syncthreads();
    }
    unsigned short* C = (bsel == 0) ? oq : (bsel == 1) ? ok : (bsel == 2) ? ov : og;
#pragma unroll
    for (int i = 0; i < 4; i++) {
#pragma unroll
        for (int r = 0; r < 4; r++) {
            int lrow = wm + i * 16 + l4 + r;
            float rn = 1.0f;
            if (donorm) rn = rsqrtf(sums[lrow * 2] + sums[lrow * 2 + 1] + EPSF);
            size_t gr = (size_t)(bm + lrow) * 1024;
#pragma unroll
            for (int j = 0; j < 4; j++) {
                int gc = bnl + wn + j * 16 + lr;
                C[gr + gc] = f2bf(acc[i][j][r] * rn);
            }
        }
    }
}

// ---------------- gated RMSNorm -> bf16 (gate is bf16) ----------------
__global__ void gating_kernel(const float* __restrict__ o, const unsigned short* __restrict__ gate,
                              const float* __restrict__ w, unsigned short* __restrict__ ob) {
    int row = blockIdx.x;
    int tid = threadIdx.x;
    const float4* op = (const float4*)(o + (size_t)row * DIM);
    float4 v = op[tid];
    float ss = v.x * v.x + v.y * v.y + v.z * v.z + v.w * v.w;
#pragma unroll
    for (int m = 1; m < 32; m <<= 1) ss += __shfl_xor(ss, m, 32);
    float r = rsqrtf(ss * (1.0f / 128.0f) + EPSF);
    ushort4 gu = ((const ushort4*)(gate + (size_t)row * DIM))[tid];
    float4 wv = ((const float4*)w)[tid & 31];
    ushort4 out;
    out.x = f2bf(v.x * r * wv.x * siluf(bf2f(gu.x)));
    out.y = f2bf(v.y * r * wv.y * siluf(bf2f(gu.y)));
    out.z = f2bf(v.z * r * wv.z * siluf(bf2f(gu.z)));
    out.w = f2bf(v.w * r * wv.w * siluf(bf2f(gu.w)));
    ((ushort4*)(ob + (size_t)row * DIM))[tid] = out;
}

// ---------------- small projections: beta, glog ----------------
__global__ void smallproj_kernel(const unsigned short* __restrict__ hbuf,
                                 const float* __restrict__ Wb, const float* __restrict__ Wa,
                                 const float* __restrict__ A_log, const float* __restrict__ dt_bias,
                                 float* __restrict__ Glog, float* __restrict__ Beta) {
    int row = blockIdx.x;
    int tid = threadIdx.x;  // 128
    __shared__ __align__(16) float hrow[1024];
    __shared__ float part[128];
    const ushort4* h4 = (const ushort4*)(hbuf + (size_t)row * DIM);
    ushort4 u0 = h4[tid * 2], u1 = h4[tid * 2 + 1];
    hrow[tid * 8 + 0] = bf2f(u0.x); hrow[tid * 8 + 1] = bf2f(u0.y);
    hrow[tid * 8 + 2] = bf2f(u0.z); hrow[tid * 8 + 3] = bf2f(u0.w);
    hrow[tid * 8 + 4] = bf2f(u1.x); hrow[tid * 8 + 5] = bf2f(u1.y);
    hrow[tid * 8 + 6] = bf2f(u1.z); hrow[tid * 8 + 7] = bf2f(u1.w);
    __syncthreads();
    int out = tid & 15, slice = tid >> 4;
    const float* W = (out < 8) ? Wb : Wa;
    int col = out & 7;
    int k0 = slice * 128;
    float p = 0.0f;
    for (int kk = 0; kk < 128; kk++) p += hrow[k0 + kk] * W[(size_t)(k0 + kk) * 8 + col];
    part[tid] = p;
    __syncthreads();
    if (tid < 16) {
        float sum = 0.0f;
#pragma unroll
        for (int sl = 0; sl < 8; sl++) sum += part[sl * 16 + tid];
        if (tid < 8) {
            Beta[(size_t)row * 8 + tid] = 1.0f / (1.0f + expf(-sum));
        } else {
            int hh = tid - 8;
            float xg = sum + dt_bias[hh];
            float sp = fmaxf(xg, 0.0f) + log1pf(expf(-fabsf(xg)));
            Glog[(size_t)row * 8 + hh] = -expf(A_log[hh]) * sp;
        }
    }
}

// ================= chunked gated delta rule =================
// Phase 1 v3: bf16 inputs, 76KB LDS (2 blocks/CU), swizzled Mt, vectorized writes.
#define PRE_KB 0          // [64][136] bf16   17408 B
#define PRE_QB 17408      // [64][136] bf16   17408 B (aliased by Yl after use)
#define PRE_YL 17408      // [16][264] bf16    8448 B
#define PRE_LM 34816      // [64][72]  bf16    9216 B
#define PRE_MT 44032      // [256][64] bf16 (swizzled 16B chunks) 32768 B
#define PRE_FL 76800      // betl,Gl,Pl,decf   1024 B
#define PRE_SZ 77824

__global__ __launch_bounds__(256) void chunk_prep_kernel(
    const unsigned short* __restrict__ Q16, const unsigned short* __restrict__ K16,
    const unsigned short* __restrict__ V16, const float* __restrict__ Glog,
    const float* __restrict__ Beta,
    unsigned short* __restrict__ Wg, unsigned short* __restrict__ Ug,
    unsigned short* __restrict__ Qg, unsigned short* __restrict__ KTg,
    unsigned short* __restrict__ SMg, float* __restrict__ Pcs) {
    __shared__ __align__(16) unsigned char smem[PRE_SZ];
    unsigned short* Kb = (unsigned short*)(smem + PRE_KB);
    unsigned short* Qb = (unsigned short*)(smem + PRE_QB);
    unsigned short* Yl = (unsigned short*)(smem + PRE_YL);
    unsigned short* Lm = (unsigned short*)(smem + PRE_LM);
    float* betl = (float*)(smem + PRE_FL);
    float* Gl = betl + 64;
    float* Pl = Gl + 64;
    float* decf = Pl + 64;

    int blk = blockIdx.x;
    int bh = blk & 31, c = blk >> 5;
    int b = bh >> 3, h = bh & 7;
    int bhc = bh * 32 + c;
    int row0 = b * 2048 + c * 64;
    int col0 = h * 128;
    int tid = threadIdx.x;
    int wv = tid >> 6, lane = tid & 63;
    int lr = lane & 15, lk8 = (lane >> 4) * 8, l4 = (lane >> 4) * 4;

    // ---- stage K,Q (bf16, no cvt); zero Lm, Mt ----
#pragma unroll
    for (int r = 0; r < 4; ++r) {
        int cc = tid + r * 256;                 // 0..1023
        int i = cc >> 4, jc = (cc & 15) * 8;
        *(short8*)&Kb[i * 136 + jc] = *(const short8*)(K16 + (size_t)(row0 + i) * DIM + col0 + jc);
        *(short8*)&Qb[i * 136 + jc] = *(const short8*)(Q16 + (size_t)(row0 + i) * DIM + col0 + jc);
    }
    {
        short8 z = {};
        for (int o = tid; o < 576; o += 256) ((short8*)Lm)[o] = z;          // 9216 B
        for (int o = tid; o < 2048; o += 256) ((short8*)(smem + PRE_MT))[o] = z;  // 32768 B
    }
    if (tid < 64) {
        float g = Glog[(size_t)(row0 + tid) * 8 + h];
        betl[tid] = Beta[(size_t)(row0 + tid) * 8 + h];
#pragma unroll
        for (int d = 1; d < 64; d <<= 1) {
            float t = __shfl_up(g, d, 64);
            if (tid >= d) g += t;
        }
        Gl[tid] = g;
        Pl[tid] = expf(g);
        float g63 = __shfl(g, 63, 64);
        decf[tid] = expf(g63 - g);
        if (tid == 63) Pcs[bhc] = expf(g);
    }
    __syncthreads();

    // ---- L = strict-lower(beta_i e^{Gi-Gj} K K^T) via MFMA -> bf16 Lm ----
    for (int nt = 0; nt <= wv; nt++) {
        f32x4 acc = {};
#pragma unroll
        for (int kk = 0; kk < 4; kk++) {
            short8 af = *(const short8*)&Kb[(wv * 16 + lr) * 136 + kk * 32 + lk8];
            short8 bfr = *(const short8*)&Kb[(nt * 16 + lr) * 136 + kk * 32 + lk8];
            acc = __builtin_amdgcn_mfma_f32_16x16x32_bf16(af, bfr, acc, 0, 0, 0);
        }
#pragma unroll
        for (int r = 0; r < 4; r++) {
            int i = wv * 16 + l4 + r;
            int j = nt * 16 + lr;
            if (j < i) Lm[i * 72 + j] = f2bf(betl[i] * expf(Gl[i] - Gl[j]) * acc[r]);
        }
    }
    // ---- SM = lower(scale e^{Gi-Gj} Q K^T) -> global ----
    for (int nt = 0; nt < 4; nt++) {
        f32x4 acc = {};
        if (nt <= wv) {
#pragma unroll
            for (int kk = 0; kk < 4; kk++) {
                short8 af = *(const short8*)&Qb[(wv * 16 + lr) * 136 + kk * 32 + lk8];
                short8 bfr = *(const short8*)&Kb[(nt * 16 + lr) * 136 + kk * 32 + lk8];
                acc = __builtin_amdgcn_mfma_f32_16x16x32_bf16(af, bfr, acc, 0, 0, 0);
            }
        }
#pragma unroll
        for (int r = 0; r < 4; r++) {
            int i = wv * 16 + l4 + r;
            int j = nt * 16 + lr;
            float vv = (nt <= wv && j <= i) ? SCALEQ * expf(Gl[i] - Gl[j]) * acc[r] : 0.f;
            SMg[((size_t)bhc * 64 + i) * 64 + j] = f2bf(vv);
        }
    }
    // ---- Qg, KTg outputs (column reads, coalesced writes) ----
    {
        int d = tid & 127, ih = tid >> 7;
        for (int i0 = 0; i0 < 32; i0++) {
            int i = ih * 32 + i0;
            Qg[((size_t)bhc * 64 + i) * 128 + d] = f2bf(SCALEQ * Pl[i] * bf2f(Qb[i * 136 + d]));
        }
        for (int j8 = 0; j8 < 32; j8 += 8) {
            short8 v8;
#pragma unroll
            for (int e = 0; e < 8; e++) {
                int jj = ih * 32 + j8 + e;
                v8[e] = (short)f2bf(decf[jj] * bf2f(Kb[jj * 136 + d]));
            }
            *(short8*)&KTg[((size_t)bhc * 128 + d) * 64 + ih * 32 + j8] = v8;
        }
    }
    __syncthreads();  // Lm visible; Qb reads done (Yl may alias)

    // ---- blocked forward substitution: (I+L) X = [beta*P*K | beta*V] ----
    int n = tid;
    bool isW = n < 128;
    int cW = n & 127;
    unsigned short* Gout = isW ? Wg : Ug;
    const unsigned short* Vcol = V16 + (size_t)row0 * DIM + col0 + cW;
    for (int bi = 0; bi < 4; ++bi) {
        if (bi > 0) {
            int ib = bi * 16;
#pragma unroll
            for (int t4 = 0; t4 < 4; ++t4) {
                int nt = wv * 4 + t4;
                f32x4 acc = {};
#pragma unroll
                for (int ks = 0; ks < 2; ++ks) {
                    short8 af = *(const short8*)&Lm[(ib + lr) * 72 + ks * 32 + lk8];
                    int nr = nt * 16 + lr;
                    int cj = ks * 4 + (lk8 >> 3);
                    short8 bfr = *(const short8*)(smem + PRE_MT + nr * 128 + (((cj ^ (nr & 7)) & 7) << 4));
                    acc = __builtin_amdgcn_mfma_f32_16x16x32_bf16(af, bfr, acc, 0, 0, 0);
                }
#pragma unroll
                for (int r = 0; r < 4; ++r)
                    Yl[(l4 + r) * 264 + nt * 16 + lr] = f2bf(acc[r]);
            }
        }
        __syncthreads();  // Yl visible (bi=0: Mt zeros + staging settled)
        float xs[16];
#pragma unroll
        for (int ii = 0; ii < 16; ++ii) {
            int i = bi * 16 + ii;
            float a = isW ? betl[i] * Pl[i] * bf2f(Kb[i * 136 + cW])
                          : betl[i] * bf2f(Vcol[(size_t)i * DIM]);
            if (bi > 0) a -= bf2f(Yl[ii * 264 + n]);
#pragma unroll
            for (int j = 0; j < 15; ++j)
                if (j < ii) a = fmaf(-bf2f(Lm[i * 72 + bi * 16 + j]), xs[j], a);
            xs[ii] = a;
        }
        // vectorized swizzled Mt row write (chunks bi*2, bi*2+1)
        {
            short8 m0, m1;
#pragma unroll
            for (int e = 0; e < 8; ++e) { m0[e] = (short)f2bf(xs[e]); m1[e] = (short)f2bf(xs[8 + e]); }
            int cj0 = bi * 2, cj1 = bi * 2 + 1;
            *(short8*)(smem + PRE_MT + n * 128 + (((cj0 ^ (n & 7)) & 7) << 4)) = m0;
            *(short8*)(smem + PRE_MT + n * 128 + (((cj1 ^ (n & 7)) & 7) << 4)) = m1;
        }
#pragma unroll
        for (int ii = 0; ii < 16; ++ii)
            Gout[((size_t)bhc * 64 + bi * 16 + ii) * 128 + cW] = f2bf(xs[ii]);
        __syncthreads();  // Mt visible for next bi corr
    }
}

// Phase 2 (MFMA): sequential over 32 chunks. Grid 256 = dvg*32 + bh, 256 thr (4 waves).
__global__ __launch_bounds__(256) void chunk_scan2_kernel(
    const unsigned short* __restrict__ Wg, const unsigned short* __restrict__ Ug,
    const unsigned short* __restrict__ Qg, const unsigned short* __restrict__ KTg,
    const unsigned short* __restrict__ SMg, const float* __restrict__ Pcs,
    float* __restrict__ O) {
    int blk = blockIdx.x;
    int bh = blk & 31, dvg = blk >> 5;  // same-bh blocks share blk%8 -> one XCD
    int b = bh >> 3, h = bh & 7;
    int col16 = dvg * 16;
    int tid = threadIdx.x;
    int wv = tid >> 6, lane = tid & 63;
    int lr = lane & 15, lk8 = (lane >> 4) * 8, l4 = (lane >> 4) * 4;
    int i0 = wv * 16;

    __shared__ __align__(16) unsigned short Wl[64 * 136];   // [i][d]
    __shared__ __align__(16) unsigned short Ql[64 * 136];   // [i][d]
    __shared__ __align__(16) unsigned short KTl[128 * 72];  // [d][j]
    __shared__ __align__(16) unsigned short SMl[64 * 72];   // [i][j]
    __shared__ __align__(16) unsigned short Ul[64 * 24];    // [i][c16]
    __shared__ __align__(16) unsigned short STl[16 * 136];  // S^T [c][d]
    __shared__ __align__(16) unsigned short DTl[16 * 72];   // Delta^T [c][j]

    for (int e = tid; e < 16 * 136; e += 256) STl[e] = 0;

    f32x4 Sacc[2] = {};

    for (int c = 0; c < 32; c++) {
        int bhc = bh * 32 + c;
        size_t base8k = (size_t)bhc * 8192;
        float pc = Pcs[bhc];
#pragma unroll
        for (int r = 0; r < 4; r++) {
            int v = tid + r * 256;
            *(short8*)&Wl[(v >> 4) * 136 + (v & 15) * 8] = *(const short8*)(Wg + base8k + (size_t)v * 8);
            *(short8*)&Ql[(v >> 4) * 136 + (v & 15) * 8] = *(const short8*)(Qg + base8k + (size_t)v * 8);
            *(short8*)&KTl[(v >> 3) * 72 + (v & 7) * 8] = *(const short8*)(KTg + base8k + (size_t)v * 8);
        }
#pragma unroll
        for (int r = 0; r < 2; r++) {
            int v = tid + r * 256;
            *(short8*)&SMl[(v >> 3) * 72 + (v & 7) * 8] = *(const short8*)(SMg + (size_t)bhc * 4096 + (size_t)v * 8);
        }
        if (tid < 128) {
            int row = tid >> 1, hf = tid & 1;
            *(short8*)&Ul[row * 24 + hf * 8] =
                *(const short8*)(Ug + base8k + (size_t)row * 128 + col16 + hf * 8);
        }
        __syncthreads();

        f32x4 acc0 = {}, acc1 = {};
#pragma unroll
        for (int kd = 0; kd < 4; kd++) {
            short8 bfs = *(const short8*)&STl[lr * 136 + kd * 32 + lk8];
            short8 aw = *(const short8*)&Wl[(i0 + lr) * 136 + kd * 32 + lk8];
            short8 aq = *(const short8*)&Ql[(i0 + lr) * 136 + kd * 32 + lk8];
            acc0 = __builtin_amdgcn_mfma_f32_16x16x32_bf16(aw, bfs, acc0, 0, 0, 0);
            acc1 = __builtin_amdgcn_mfma_f32_16x16x32_bf16(aq, bfs, acc1, 0, 0, 0);
        }
        ushort4 dpk;
        dpk.x = f2bf(bf2f(Ul[(i0 + l4 + 0) * 24 + lr]) - acc0[0]);
        dpk.y = f2bf(bf2f(Ul[(i0 + l4 + 1) * 24 + lr]) - acc0[1]);
        dpk.z = f2bf(bf2f(Ul[(i0 + l4 + 2) * 24 + lr]) - acc0[2]);
        dpk.w = f2bf(bf2f(Ul[(i0 + l4 + 3) * 24 + lr]) - acc0[3]);
        *(ushort4*)&DTl[lr * 72 + i0 + l4] = dpk;
        __syncthreads();

#pragma unroll
        for (int dt = 0; dt < 2; dt++)
#pragma unroll
            for (int r = 0; r < 4; r++) Sacc[dt][r] *= pc;
#pragma unroll
        for (int kj = 0; kj < 2; kj++) {
            short8 bfd = *(const short8*)&DTl[lr * 72 + kj * 32 + lk8];
            short8 as = *(const short8*)&SMl[(i0 + lr) * 72 + kj * 32 + lk8];
            acc1 = __builtin_amdgcn_mfma_f32_16x16x32_bf16(as, bfd, acc1, 0, 0, 0);
#pragma unroll
            for (int dt = 0; dt < 2; dt++) {
                short8 ak = *(const short8*)&KTl[((2 * wv + dt) * 16 + lr) * 72 + kj * 32 + lk8];
                Sacc[dt] = __builtin_amdgcn_mfma_f32_16x16x32_bf16(ak, bfd, Sacc[dt], 0, 0, 0);
            }
        }
        {
            int orow0 = b * 2048 + c * 64 + i0 + l4;
            int ocol = h * 128 + col16 + lr;
#pragma unroll
            for (int r = 0; r < 4; r++)
                O[(size_t)(orow0 + r) * DIM + ocol] = acc1[r];
        }
#pragma unroll
        for (int dt = 0; dt < 2; dt++) {
            ushort4 sp;
            sp.x = f2bf(Sacc[dt][0]);
            sp.y = f2bf(Sacc[dt][1]);
            sp.z = f2bf(Sacc[dt][2]);
            sp.w = f2bf(Sacc[dt][3]);
            *(ushort4*)&STl[lr * 136 + (2 * wv + dt) * 16 + l4] = sp;
        }
        __syncthreads();
    }
}

extern "C" void kernel_launch(void* const* d_in, const int* in_sizes, int n_in,
                              void* d_out, int out_size, void* d_ws, size_t ws_size,
                              hipStream_t stream) {
    const float* x      = (const float*)d_in[0];
    const float* Wq     = (const float*)d_in[1];
    const float* Wk     = (const float*)d_in[2];
    const float* Wv     = (const float*)d_in[3];
    const float* Wb     = (const float*)d_in[4];
    const float* Wa     = (const float*)d_in[5];
    const float* A_log  = (const float*)d_in[6];
    const float* dt_b   = (const float*)d_in[7];
    const float* Wg_in  = (const float*)d_in[8];
    const float* o_norm = (const float*)d_in[9];
    const float* Wo     = (const float*)d_in[10];
    const float* W_fc   = (const float*)d_in[11];
    const float* W_proj = (const float*)d_in[12];
    float* out = (float*)d_out;

    const size_t MATE = (size_t)ROWS * DIM;  // 8M elems
    unsigned short* qb16 = (unsigned short*)d_ws;
    unsigned short* kb16 = qb16 + MATE;
    unsigned short* vb16 = kb16 + MATE;
    unsigned short* gt16 = vb16 + MATE;
    float* o_f = (float*)(gt16 + MATE);
    unsigned short* h_bf = (unsigned short*)(o_f + MATE);
    float* glog = (float*)(h_bf + MATE);
    float* beta = glog + (size_t)ROWS * NH;
    unsigned short* wts = (unsigned short*)(beta + (size_t)ROWS * NH);
    unsigned short* WqT = wts;                     // [4096,1024] concat Wq|Wk|Wv|Wg
    unsigned short* WkT = wts + (1u << 20);
    unsigned short* WvT = wts + 2 * (1u << 20);
    unsigned short* WgT = wts + 3 * (1u << 20);
    unsigned short* WoT = wts + 4 * (1u << 20);
    unsigned short* WfcT = wts + 5 * (1u << 20);
    unsigned short* WprT = wts + 9 * (1u << 20);
    unsigned short* Wgb = wts + 13 * (1u << 20);
    unsigned short* Ugb = Wgb + (8u << 20);
    unsigned short* Qg2 = Ugb + (8u << 20);
    unsigned short* KTg = Qg2 + (8u << 20);
    unsigned short* SMg = KTg + (8u << 20);
    float* pcs = (float*)(SMg + (4u << 20));
    unsigned short* m_bf = h_bf;                   // alias (h dead after smallproj)
    unsigned short* o_bf = vb16;                   // alias (v dead after prep)
    unsigned short* fc_bf = qb16;                  // alias (q..gate dead by step 8)

    // 0. weight transposes -> bf16 [N,K]
    transpose_bf16_kernel<<<dim3(32, 32), 256, 0, stream>>>(Wq, WqT, 1024, 1024);
    transpose_bf16_kernel<<<dim3(32, 32), 256, 0, stream>>>(Wk, WkT, 1024, 1024);
    transpose_bf16_kernel<<<dim3(32, 32), 256, 0, stream>>>(Wv, WvT, 1024, 1024);
    transpose_bf16_kernel<<<dim3(32, 32), 256, 0, stream>>>(Wg_in, WgT, 1024, 1024);
    transpose_bf16_kernel<<<dim3(32, 32), 256, 0, stream>>>(Wo, WoT, 1024, 1024);
    transpose_bf16_kernel<<<dim3(128, 32), 256, 0, stream>>>(W_fc, WfcT, 1024, 4096);
    transpose_bf16_kernel<<<dim3(32, 128), 256, 0, stream>>>(W_proj, WprT, 4096, 1024);

    // 1. h = rms_norm(x) -> bf16
    rmsnorm_bf16_kernel<<<ROWS, 256, 0, stream>>>(x, h_bf);

    // 2. fused QKVG projection + silu + l2norm -> bf16
    mfma_gemm_qkvg<<<dim3(4096 / 128, ROWS / 128), 256, 0, stream>>>(
        h_bf, WqT, qb16, kb16, vb16, gt16, ROWS, DIM);

    // 3. beta/glog
    smallproj_kernel<<<ROWS, 128, 0, stream>>>(h_bf, Wb, Wa, A_log, dt_b, glog, beta);

    // 4. chunked delta rule
    chunk_prep_kernel<<<1024, 256, 0, stream>>>(qb16, kb16, vb16, glog, beta,
                                                Wgb, Ugb, Qg2, KTg, SMg, pcs);
    chunk_scan2_kernel<<<256, 256, 0, stream>>>(Wgb, Ugb, Qg2, KTg, SMg, pcs, o_f);

    // 5. gated RMSNorm -> o_bf
    gating_kernel<<<ROWS, 256, 0, stream>>>(o_f, gt16, o_norm, o_bf);

    // 6. d_out = x + o @ Wo
    dim3 g1(DIM / 128, ROWS / 128);
    mfma_gemm<2, float><<<g1, 256, 0, stream>>>(o_bf, WoT, out, x, ROWS, DIM, DIM);

    // 7. m = rms_norm(d_out) -> m_bf
    rmsnorm_bf16_kernel<<<ROWS, 256, 0, stream>>>(out, m_bf);

    // 8. fc = relu(m @ W_fc)^2 -> bf16
    dim3 g2(DFF_ / 128, ROWS / 128);
    mfma_gemm<3, unsigned short><<<g2, 256, 0, stream>>>(m_bf, WfcT, fc_bf, nullptr, ROWS, DFF_, DIM);

    // 9. d_out += fc @ W_proj
    mfma_gemm<2, float><<<g1, 256, 0, stream>>>(fc_bf, WprT, out, out, ROWS, DIM, DFF_);
}